// Round 1
// 890.807 us; speedup vs baseline: 1.2274x; 1.2274x over previous
//
#include <hip/hip_runtime.h>
#include <hip/hip_bf16.h>
#include <cstdint>

#define SEQ 2048
#define NPAD 12416      // 97*128, padded N for GEMM1
#define NTOT 12352      // qkv(8192) + z(4096) + a(32) + b(32)
#define CONV_INNER 8192

typedef __attribute__((ext_vector_type(8))) short bf16x8;
typedef __attribute__((ext_vector_type(4))) float f32x4;

__device__ __forceinline__ float b2f(unsigned short u) {
  union { unsigned int i; float f; } x; x.i = ((unsigned int)u) << 16; return x.f;
}
__device__ __forceinline__ unsigned short f2b(float f) {
  __hip_bfloat16 h = __float2bfloat16(f);
  return *reinterpret_cast<unsigned short*>(&h);
}
__device__ __forceinline__ void load_lds16(const short* g, short* l) {
  __builtin_amdgcn_global_load_lds(
      (__attribute__((address_space(1))) void*)(g),
      (__attribute__((address_space(3))) void*)(l), 16, 0, 0);
}

// S_all staging: state ENTERING chunk ch of (b,h), bf16 [128 v][128 k].
// Lives in dead workspace columns: qact cols 4096..8191 (v-region, dead after
// chunk_prep) for b=0 cids; g1out cols 4096..8191 (qkv_raw, dead after conv)
// for b=1 cids. One cid = 4 row-slots of 32 v-rows each.
__device__ __forceinline__ unsigned short* sall_ptr(
    unsigned short* qact, unsigned short* g1out, int cid, int vrow) {
  int slot = ((cid & 1023) << 2) + (vrow >> 5);
  if (cid < 1024) return qact + (size_t)slot * 8192 + 4096 + (vrow & 31) * 128;
  return g1out + (size_t)slot * (size_t)NPAD + 4096 + (vrow & 31) * 128;
}

// ---------------- fp32 -> bf16 cast ----------------
__global__ void cast_kernel(const float* __restrict__ in, unsigned short* __restrict__ out, int n4) {
  int i = blockIdx.x * blockDim.x + threadIdx.x;
  if (i >= n4) return;
  float4 v = ((const float4*)in)[i];
  ushort4 o;
  o.x = f2b(v.x); o.y = f2b(v.y); o.z = f2b(v.z); o.w = f2b(v.w);
  ((ushort4*)out)[i] = o;
}

// ---------------- bf16 MFMA GEMM: C[m][n] = sum_k A[m][k]*B[n][k] ----------------
template<bool OUT_BF16>
__global__ __launch_bounds__(256) void gemm_bt(
    const unsigned short* __restrict__ A,   // [M][lda] bf16
    const unsigned short* __restrict__ Bm,  // [Nrows][ldb] bf16
    void* __restrict__ Cout, int K, int lda, int ldb, int ldc, int nmax)
{
  __shared__ __align__(16) short lA[2][128 * 32];
  __shared__ __align__(16) short lB[2][128 * 32];
  const int tid = threadIdx.x;
  const int lane = tid & 63, wid = tid >> 6;
  const int lane16 = lane & 15, quad = lane >> 4;
  const int wm = (wid & 1) * 64, wn = (wid >> 1) * 64;
  const int m0 = blockIdx.y * 128, n0 = blockIdx.x * 128;
  const int srow = wid * 16 + (lane >> 2);                  // staged tile row
  const int scol = (((lane & 3) ^ ((lane >> 3) & 3))) * 8;  // swizzled source chunk
  const int rchunk = (quad ^ ((lane16 >> 1) & 3)) * 8;      // swizzled fragment chunk

  f32x4 acc[4][4];
  #pragma unroll
  for (int i = 0; i < 4; i++)
    #pragma unroll
    for (int j = 0; j < 4; j++)
      acc[i][j] = f32x4{0.f, 0.f, 0.f, 0.f};

  const short* As = (const short*)A;
  const short* Bs = (const short*)Bm;
  short* lA0s[2] = { &lA[0][(wid * 16) * 32], &lA[1][(wid * 16) * 32] };
  short* lA1s[2] = { &lA[0][(64 + wid * 16) * 32], &lA[1][(64 + wid * 16) * 32] };
  short* lB0s[2] = { &lB[0][(wid * 16) * 32], &lB[1][(wid * 16) * 32] };
  short* lB1s[2] = { &lB[0][(64 + wid * 16) * 32], &lB[1][(64 + wid * 16) * 32] };
  const short* ga0 = As + (size_t)(m0 + srow) * lda + scol;
  const short* ga1 = As + (size_t)(m0 + 64 + srow) * lda + scol;
  const short* gb0 = Bs + (size_t)(n0 + srow) * ldb + scol;
  const short* gb1 = Bs + (size_t)(n0 + 64 + srow) * ldb + scol;

  for (int kb = 0; kb < K; kb += 64) {
    #pragma unroll
    for (int st = 0; st < 2; st++) {
      int ko = kb + st * 32;
      load_lds16(ga0 + ko, lA0s[st]);
      load_lds16(ga1 + ko, lA1s[st]);
      load_lds16(gb0 + ko, lB0s[st]);
      load_lds16(gb1 + ko, lB1s[st]);
    }
    __syncthreads();   // drains vmcnt -> both stages complete
    #pragma unroll
    for (int st = 0; st < 2; st++) {
      bf16x8 af[4], bfr[4];
      #pragma unroll
      for (int t = 0; t < 4; t++) af[t]  = *(const bf16x8*)&lA[st][(wm + t * 16 + lane16) * 32 + rchunk];
      #pragma unroll
      for (int t = 0; t < 4; t++) bfr[t] = *(const bf16x8*)&lB[st][(wn + t * 16 + lane16) * 32 + rchunk];
      #pragma unroll
      for (int i = 0; i < 4; i++)
        #pragma unroll
        for (int j = 0; j < 4; j++)
          acc[i][j] = __builtin_amdgcn_mfma_f32_16x16x32_bf16(af[i], bfr[j], acc[i][j], 0, 0, 0);
    }
    __syncthreads();   // all reads done before next overwrite
  }

  #pragma unroll
  for (int i = 0; i < 4; i++) {
    #pragma unroll
    for (int j = 0; j < 4; j++) {
      int n = n0 + wn + j * 16 + lane16;
      if (n >= nmax) continue;
      #pragma unroll
      for (int r = 0; r < 4; r++) {
        int m = m0 + wm + i * 16 + quad * 4 + r;
        float v = acc[i][j][r];
        if (OUT_BF16) ((unsigned short*)Cout)[(size_t)m * ldc + n] = f2b(v);
        else          ((float*)Cout)[(size_t)m * ldc + n] = v;
      }
    }
  }
}

// ---------------- gates: g (log decay) and beta ----------------
__global__ void gebeta_kernel(const unsigned short* __restrict__ g1out,
                              const float* __restrict__ A_log, const float* __restrict__ dt_bias,
                              float* __restrict__ g_out, float* __restrict__ beta)
{
  int idx = blockIdx.x * blockDim.x + threadIdx.x;  // 131072 = 4096*32
  int r = idx >> 5, n = idx & 31;
  float a = b2f(g1out[(size_t)r * NPAD + 12288 + n]) + dt_bias[n];
  float sp = (a > 20.f) ? a : log1pf(expf(a));
  g_out[idx] = -expf(A_log[n]) * sp;
  float bv = b2f(g1out[(size_t)r * NPAD + 12320 + n]);
  beta[idx] = 1.f / (1.f + expf(-bv));
}

// ---------------- conv(4) + silu + l2norm(q,k), 8 ch/thread ----------------
__global__ __launch_bounds__(128) void conv_kernel(
    const unsigned short* __restrict__ g1out, const float* __restrict__ conv_w,
    unsigned short* __restrict__ qkv_act)
{
  const int row = blockIdx.x;            // b*SEQ + s
  const int hg  = blockIdx.y;            // 0..7 (1024 channels each)
  const int tid = threadIdx.x;           // 0..127
  const int c0 = hg * 1024 + tid * 8;
  const int s = row & (SEQ - 1);
  float4 w4[8];
  #pragma unroll
  for (int e = 0; e < 8; e++) w4[e] = *(const float4*)(conv_w + (size_t)(c0 + e) * 4);
  float acc[8] = {0.f,0.f,0.f,0.f,0.f,0.f,0.f,0.f};
  #pragma unroll
  for (int j = 0; j < 4; j++) {
    int sj = s - 3 + j;
    if (sj >= 0) {
      bf16x8 x = *(const bf16x8*)(g1out + (size_t)(row - 3 + j) * NPAD + c0);
      #pragma unroll
      for (int e = 0; e < 8; e++) {
        float wj = (j == 0) ? w4[e].x : (j == 1) ? w4[e].y : (j == 2) ? w4[e].z : w4[e].w;
        acc[e] += wj * b2f((unsigned short)x[e]);
      }
    }
  }
  float sv[8], ssq = 0.f;
  #pragma unroll
  for (int e = 0; e < 8; e++) {
    sv[e] = acc[e] / (1.f + __expf(-acc[e]));
    ssq += sv[e] * sv[e];
  }
  ssq += __shfl_xor(ssq, 1, 64);
  ssq += __shfl_xor(ssq, 2, 64);
  ssq += __shfl_xor(ssq, 4, 64);
  ssq += __shfl_xor(ssq, 8, 64);
  float scale = 1.f;
  if (hg < 4) {
    scale = rsqrtf(ssq + 1e-6f);
    if (hg < 2) scale *= 0.08838834764831845f;  // q: 1/sqrt(128)
  }
  bf16x8 o;
  #pragma unroll
  for (int e = 0; e < 8; e++) o[e] = (short)f2b(sv[e] * scale);
  *(bf16x8*)(qkv_act + (size_t)row * CONV_INNER + c0) = o;
}

// ---------------- conv_state output ----------------
__global__ void convstate_kernel(const unsigned short* __restrict__ g1out, float* __restrict__ out1)
{
  int idx = blockIdx.x * blockDim.x + threadIdx.x;
  int b = idx >> 15, rem = idx & 32767;
  int c = rem >> 2, j = rem & 3;
  out1[idx] = b2f(g1out[(size_t)(b * SEQ + SEQ - 4 + j) * NPAD + c]);
}

// ================= PASS 1: chunk-local W,U (UT transform) =================
__global__ __launch_bounds__(256, 2) void chunk_prep(
    const unsigned short* __restrict__ qact,
    const float* __restrict__ g_arr, const float* __restrict__ beta_arr,
    unsigned short* __restrict__ W_all, unsigned short* __restrict__ U_all)
{
  __shared__ __align__(16) char smem[73472];
  short* sKn = (short*)smem;                  // 64 x stride152; Vt (128x72) aliases
  short* sVt = (short*)smem;
  short* sKt = (short*)(smem + 19456);        // 128 x 72
  float* sA  = (float*)(smem + 37888);        // 64 x 68 fp32; Tb aliases
  short* sTb = (short*)(smem + 37888);        // 64 x 72 bf16
  float* sT  = (float*)(smem + 55296);        // 64 x 68 fp32
  float* sl  = (float*)(smem + 72704);
  float* sel = (float*)(smem + 72960);
  float* sbb = (float*)(smem + 73216);

  const int tid = threadIdx.x, lane = tid & 63, wid = tid >> 6;
  const int lane16 = lane & 15, quad = lane >> 4;
  const int cid = blockIdx.x;
  const int ch = cid & 31, h = (cid >> 5) & 31, b = cid >> 10;
  const int qh = h >> 1;
  const int row0 = b * SEQ + ch * 64;

  float gv = g_arr[(size_t)(row0 + lane) * 32 + h];
  float bb = beta_arr[(size_t)(row0 + lane) * 32 + h];
  float l = gv;
  #pragma unroll
  for (int off = 1; off < 64; off <<= 1) {
    float p = __shfl_up(l, off, 64);
    if (lane >= off) l += p;
  }
  float el = expf(l);
  if (wid == 0) { sl[lane] = l; sel[lane] = el; sbb[lane] = bb; }

  {
    int j = tid >> 2, kc = (tid & 3) * 32;
    const unsigned short* src = qact + (size_t)(row0 + j) * CONV_INNER + 2048 + qh * 128 + kc;
    #pragma unroll
    for (int u = 0; u < 4; u++) {
      bf16x8 r = *(const bf16x8*)(src + u * 8);
      *(bf16x8*)&sKn[j * 152 + kc + u * 8] = r;
    }
  }
  {
    const unsigned short* src = qact + (size_t)(row0 + lane) * CONV_INNER + 2048 + qh * 128 + wid * 32;
    float cj = bb * el;
    #pragma unroll
    for (int u = 0; u < 4; u++) {
      bf16x8 r = *(const bf16x8*)(src + u * 8);
      #pragma unroll
      for (int e = 0; e < 8; e++)
        sKt[(wid * 32 + u * 8 + e) * 72 + lane] = (short)f2b(b2f((unsigned short)r[e]) * cj);
    }
  }
  __syncthreads();

  {
    f32x4 accA[4];
    #pragma unroll
    for (int t = 0; t < 4; t++) accA[t] = f32x4{0.f, 0.f, 0.f, 0.f};
    #pragma unroll
    for (int ks = 0; ks < 4; ks++) {
      bf16x8 a = *(const bf16x8*)&sKn[(wid * 16 + lane16) * 152 + ks * 32 + quad * 8];
      #pragma unroll
      for (int jt = 0; jt < 4; jt++) {
        bf16x8 bfr = *(const bf16x8*)&sKn[(jt * 16 + lane16) * 152 + ks * 32 + quad * 8];
        accA[jt] = __builtin_amdgcn_mfma_f32_16x16x32_bf16(a, bfr, accA[jt], 0, 0, 0);
      }
    }
    #pragma unroll
    for (int jt = 0; jt < 4; jt++) {
      int j = jt * 16 + lane16;
      float lj = sl[j];
      #pragma unroll
      for (int r = 0; r < 4; r++) {
        int i = wid * 16 + quad * 4 + r;
        float v = (j < i) ? sbb[i] * expf(sl[i] - lj) * accA[jt][r] : 0.f;
        sA[i * 68 + j] = v;
      }
    }
  }
  __syncthreads();

  {
    const unsigned short* src = qact + (size_t)(row0 + lane) * CONV_INNER + 4096 + h * 128 + wid * 32;
    #pragma unroll
    for (int u = 0; u < 4; u++) {
      bf16x8 r = *(const bf16x8*)(src + u * 8);
      #pragma unroll
      for (int e = 0; e < 8; e++)
        sVt[(wid * 32 + u * 8 + e) * 72 + lane] = (short)f2b(b2f((unsigned short)r[e]) * bb);
    }
  }
  __syncthreads();

  if (wid == 0 && lane < 32) {
    int c = lane;
    float treg[32];
    treg[0] = (c == 0) ? 1.f : 0.f;
    #pragma unroll
    for (int i = 1; i < 32; i++) {
      float s = 0.f;
      #pragma unroll
      for (int j = 0; j < i; j++) s += sA[i * 68 + j] * treg[j];
      treg[i] = ((i == c) ? 1.f : 0.f) - s;
    }
    #pragma unroll
    for (int i = 0; i < 32; i++) sT[i * 68 + c] = treg[i];
  } else if (wid == 1 && lane < 32) {
    int c = lane;
    float treg[32];
    treg[0] = (c == 0) ? 1.f : 0.f;
    #pragma unroll
    for (int i = 1; i < 32; i++) {
      float s = 0.f;
      #pragma unroll
      for (int j = 0; j < i; j++) s += sA[(32 + i) * 68 + 32 + j] * treg[j];
      treg[i] = ((i == c) ? 1.f : 0.f) - s;
    }
    #pragma unroll
    for (int i = 0; i < 32; i++) sT[(32 + i) * 68 + 32 + c] = treg[i];
  } else if (wid == 2) {
    for (int e = lane; e < 1024; e += 64) sT[(e >> 5) * 68 + 32 + (e & 31)] = 0.f;
  }
  __syncthreads();

  {
    int i = tid & 31, c0 = (tid >> 5) * 4;
    float x[4] = {0.f, 0.f, 0.f, 0.f};
    #pragma unroll
    for (int j = 0; j < 32; j++) {
      float a = sA[(32 + i) * 68 + j];
      #pragma unroll
      for (int cc = 0; cc < 4; cc++) x[cc] += a * sT[j * 68 + c0 + cc];
    }
    #pragma unroll
    for (int cc = 0; cc < 4; cc++) sA[i * 68 + c0 + cc] = x[cc];
  }
  __syncthreads();
  {
    int i = tid & 31, c0 = (tid >> 5) * 4;
    float x[4] = {0.f, 0.f, 0.f, 0.f};
    #pragma unroll
    for (int j = 0; j < 32; j++) {
      float t2 = sT[(32 + i) * 68 + 32 + j];
      #pragma unroll
      for (int cc = 0; cc < 4; cc++) x[cc] += t2 * sA[j * 68 + c0 + cc];
    }
    #pragma unroll
    for (int cc = 0; cc < 4; cc++) sT[(32 + i) * 68 + c0 + cc] = -x[cc];
  }
  __syncthreads();
  #pragma unroll
  for (int ii = 0; ii < 16; ii++) {
    int e = tid + 256 * ii;
    int r = e >> 6, cc = e & 63;
    sTb[r * 72 + cc] = (short)f2b(sT[r * 68 + cc]);
  }
  __syncthreads();

  {
    f32x4 accW[8], accU[8];
    #pragma unroll
    for (int nt = 0; nt < 8; nt++) { accW[nt] = f32x4{0.f,0.f,0.f,0.f}; accU[nt] = f32x4{0.f,0.f,0.f,0.f}; }
    bf16x8 ta[2];
    #pragma unroll
    for (int ks = 0; ks < 2; ks++)
      ta[ks] = *(const bf16x8*)&sTb[(wid * 16 + lane16) * 72 + ks * 32 + quad * 8];
    #pragma unroll
    for (int nt = 0; nt < 8; nt++) {
      #pragma unroll
      for (int ks = 0; ks < 2; ks++) {
        bf16x8 bk = *(const bf16x8*)&sKt[(nt * 16 + lane16) * 72 + ks * 32 + quad * 8];
        accW[nt] = __builtin_amdgcn_mfma_f32_16x16x32_bf16(ta[ks], bk, accW[nt], 0, 0, 0);
        bf16x8 bv = *(const bf16x8*)&sVt[(nt * 16 + lane16) * 72 + ks * 32 + quad * 8];
        accU[nt] = __builtin_amdgcn_mfma_f32_16x16x32_bf16(ta[ks], bv, accU[nt], 0, 0, 0);
      }
    }
    unsigned short* Wg = W_all + (size_t)cid * 8192;
    unsigned short* Ug = U_all + (size_t)cid * 8192;
    #pragma unroll
    for (int nt = 0; nt < 8; nt++)
      #pragma unroll
      for (int r = 0; r < 4; r++) {
        int i = wid * 16 + quad * 4 + r, k = nt * 16 + lane16;
        Wg[i * 128 + k] = f2b(accW[nt][r]);
        Ug[i * 128 + k] = f2b(accU[nt][r]);
      }
  }
}

// ================= PASS 2a: sequential state recurrence only =================
// S_{c+1} = elC*S_c + (U_c - W_c S_c^T)^T-style update; v-rows independent ->
// 128 blocks = 64 (b,h) x 2 v-halves, 512 threads (8 waves, 2/SIMD).
// lgkmcnt-only barriers (no vmcnt drain) + cross-chunk register prefetch.
__global__ __launch_bounds__(512) void state_scan(
    unsigned short* qact, unsigned short* g1out,
    const float* __restrict__ g_arr,
    const unsigned short* __restrict__ W_all, const unsigned short* __restrict__ U_all,
    float* __restrict__ state_out)
{
  __shared__ __align__(16) short sS[64 * 136];    // S half-tile [64v][128k] bf16
  __shared__ __align__(16) short sDt[64 * 72];    // Dt [64v][64t] bf16
  __shared__ __align__(16) short sK2[128 * 72];   // K2^T [128k'][64t] bf16
  const int tid = threadIdx.x, lane = tid & 63, w = tid >> 6;
  const int lane16 = lane & 15, quad = lane >> 4;
  const int bid = blockIdx.x;
  const int bh = bid >> 1, vs = bid & 1;
  const int h = bh & 31, b = bh >> 5, qh = h >> 1;
  const int V0 = vs * 64;
  const int tt = w >> 1, vhl = (w & 1) * 32;      // aD work split
  const int avt = w & 3, kt0 = (w >> 2) * 4;      // aS work split

  for (int e = tid; e < 64 * 136 / 2; e += 512) ((unsigned int*)sS)[e] = 0u;
  float Sreg[4][4];
  #pragma unroll
  for (int n = 0; n < 4; n++)
    #pragma unroll
    for (int r = 0; r < 4; r++) Sreg[n][r] = 0.f;

  // ---- prefetch chunk 0 ----
  float gvn;
  bf16x8 kn[2], wn[4];
  unsigned short un[8];
  {
    const int r0_ = b * SEQ, cid_ = bh << 5;
    gvn = g_arr[(size_t)(r0_ + lane) * 32 + h];
    const unsigned short* ks_ = qact + (size_t)(r0_ + lane) * 8192 + 2048 + qh * 128 + w * 16;
    kn[0] = *(const bf16x8*)ks_; kn[1] = *(const bf16x8*)(ks_ + 8);
    const unsigned short* ws_ = W_all + (size_t)cid_ * 8192 + (tt * 16 + lane16) * 128 + quad * 8;
    #pragma unroll
    for (int ks = 0; ks < 4; ks++) wn[ks] = *(const bf16x8*)(ws_ + ks * 32);
    const unsigned short* us_ = U_all + (size_t)cid_ * 8192 + (tt * 16 + quad * 4) * 128 + V0 + vhl + lane16;
    #pragma unroll
    for (int vt = 0; vt < 2; vt++)
      #pragma unroll
      for (int r = 0; r < 4; r++) un[vt * 4 + r] = us_[r * 128 + vt * 16];
  }

  for (int ch = 0; ch < 32; ch++) {
    const int cid = (bh << 5) + ch;
    // consume prefetched g/K; copy W,U before overwrite
    float l = gvn;
    #pragma unroll
    for (int off = 1; off < 64; off <<= 1) {
      float p = __shfl_up(l, off, 64);
      if (lane >= off) l += p;
    }
    float lC = __shfl(l, 63, 64);
    float elC = expf(lC);
    float s2 = expf(lC - l);
    #pragma unroll
    for (int e = 0; e < 8; e++)
      sK2[(w * 16 + e) * 72 + lane] = (short)f2b(b2f((unsigned short)kn[0][e]) * s2);
    #pragma unroll
    for (int e = 0; e < 8; e++)
      sK2[(w * 16 + 8 + e) * 72 + lane] = (short)f2b(b2f((unsigned short)kn[1][e]) * s2);
    bf16x8 wc[4];
    #pragma unroll
    for (int ks = 0; ks < 4; ks++) wc[ks] = wn[ks];
    unsigned short uc[8];
    #pragma unroll
    for (int i = 0; i < 8; i++) uc[i] = un[i];

    // issue next-chunk prefetch (stays in flight across lgkm-only barriers)
    if (ch < 31) {
      const int r0_ = b * SEQ + (ch + 1) * 64, cid_ = cid + 1;
      gvn = g_arr[(size_t)(r0_ + lane) * 32 + h];
      const unsigned short* ks_ = qact + (size_t)(r0_ + lane) * 8192 + 2048 + qh * 128 + w * 16;
      kn[0] = *(const bf16x8*)ks_; kn[1] = *(const bf16x8*)(ks_ + 8);
      const unsigned short* ws_ = W_all + (size_t)cid_ * 8192 + (tt * 16 + lane16) * 128 + quad * 8;
      #pragma unroll
      for (int ks = 0; ks < 4; ks++) wn[ks] = *(const bf16x8*)(ws_ + ks * 32);
      const unsigned short* us_ = U_all + (size_t)cid_ * 8192 + (tt * 16 + quad * 4) * 128 + V0 + vhl + lane16;
      #pragma unroll
      for (int vt = 0; vt < 2; vt++)
        #pragma unroll
        for (int r = 0; r < 4; r++) un[vt * 4 + r] = us_[r * 128 + vt * 16];
    }
    asm volatile("s_waitcnt lgkmcnt(0)" ::: "memory");
    __builtin_amdgcn_s_barrier();      // bar1: sS(entering) + sK2 ready

    // Dt = U - W.S^T  -> out[t][v]
    f32x4 aD[2];
    aD[0] = f32x4{0.f,0.f,0.f,0.f}; aD[1] = f32x4{0.f,0.f,0.f,0.f};
    #pragma unroll
    for (int ks = 0; ks < 4; ks++)
      #pragma unroll
      for (int vt = 0; vt < 2; vt++) {
        bf16x8 bfr = *(const bf16x8*)&sS[(vhl + vt * 16 + lane16) * 136 + ks * 32 + quad * 8];
        aD[vt] = __builtin_amdgcn_mfma_f32_16x16x32_bf16(wc[ks], bfr, aD[vt], 0, 0, 0);
      }
    #pragma unroll
    for (int vt = 0; vt < 2; vt++)
      #pragma unroll
      for (int r = 0; r < 4; r++)
        sDt[(vhl + vt * 16 + lane16) * 72 + tt * 16 + quad * 4 + r] =
            (short)f2b(b2f(uc[vt * 4 + r]) - aD[vt][r]);
    asm volatile("s_waitcnt lgkmcnt(0)" ::: "memory");
    __builtin_amdgcn_s_barrier();      // bar2: sDt ready

    // S <- elC*S + Dt.K2
    bf16x8 a2[2];
    #pragma unroll
    for (int ks2 = 0; ks2 < 2; ks2++)
      a2[ks2] = *(const bf16x8*)&sDt[(avt * 16 + lane16) * 72 + ks2 * 32 + quad * 8];
    f32x4 aS[4];
    #pragma unroll
    for (int n = 0; n < 4; n++) aS[n] = f32x4{0.f,0.f,0.f,0.f};
    #pragma unroll
    for (int n = 0; n < 4; n++)
      #pragma unroll
      for (int ks2 = 0; ks2 < 2; ks2++) {
        bf16x8 bfr = *(const bf16x8*)&sK2[((kt0 + n) * 16 + lane16) * 72 + ks2 * 32 + quad * 8];
        aS[n] = __builtin_amdgcn_mfma_f32_16x16x32_bf16(a2[ks2], bfr, aS[n], 0, 0, 0);
      }
    #pragma unroll
    for (int r = 0; r < 4; r++) {
      int vg = V0 + avt * 16 + quad * 4 + r;
      unsigned short* sp = nullptr;
      if (ch < 31) sp = sall_ptr(qact, g1out, cid + 1, vg);  // entering-state for chunk ch+1
      #pragma unroll
      for (int n = 0; n < 4; n++) {
        float v = elC * Sreg[n][r] + aS[n][r];
        Sreg[n][r] = v;
        unsigned short bv = f2b(v);
        sS[(avt * 16 + quad * 4 + r) * 136 + (kt0 + n) * 16 + lane16] = (short)bv;
        if (ch < 31) sp[(kt0 + n) * 16 + lane16] = bv;
      }
    }
    asm volatile("s_waitcnt lgkmcnt(0)" ::: "memory");
    __builtin_amdgcn_s_barrier();      // bar3: sS(new) written; sDt/sK2 reads done
  }

  float* so = state_out + (size_t)bh * 16384;
  #pragma unroll
  for (int r = 0; r < 4; r++)
    #pragma unroll
    for (int n = 0; n < 4; n++)
      so[(size_t)(V0 + avt * 16 + quad * 4 + r) * 128 + (kt0 + n) * 16 + lane16] = Sreg[n][r];
}

// ================= PASS 2b: per-chunk output (fully parallel) =================
// One block per (b,h,chunk) = 2048 blocks; recomputes Dt from staged S_c.
__global__ __launch_bounds__(256) void chunk_out(
    unsigned short* qact, unsigned short* g1out,
    const float* __restrict__ g_arr, const float* __restrict__ norm_w,
    const unsigned short* __restrict__ W_all, const unsigned short* __restrict__ U_all)
{
  __shared__ __align__(16) short sS[128 * 136];   // 34816 B
  __shared__ __align__(16) short sKn[64 * 136];   // 17408 B ; sM aliases
  __shared__ __align__(16) short sDt[128 * 72];   // 18432 B
  __shared__ float sl[64];
  __shared__ float sel[64];
  __shared__ float snw[128];
  short* sM = sKn;
  const int tid = threadIdx.x, lane = tid & 63, wid = tid >> 6;
  const int lane16 = lane & 15, quad = lane >> 4;
  const int cid = blockIdx.x;
  const int ch = cid & 31, h = (cid >> 5) & 31, b = cid >> 10, qh = h >> 1;
  const int row0 = b * SEQ + ch * 64;

  float l = g_arr[(size_t)(row0 + lane) * 32 + h];
  #pragma unroll
  for (int off = 1; off < 64; off <<= 1) {
    float p = __shfl_up(l, off, 64);
    if (lane >= off) l += p;
  }
  if (wid == 0) { sl[lane] = l; sel[lane] = expf(l); }
  if (tid < 128) snw[tid] = norm_w[tid];

  // stage K tile
  {
    int j4 = tid >> 2, kc = (tid & 3) * 32;
    const unsigned short* sk = qact + (size_t)(row0 + j4) * 8192 + 2048 + qh * 128 + kc;
    #pragma unroll
    for (int u = 0; u < 4; u++)
      *(bf16x8*)&sKn[j4 * 136 + kc + u * 8] = *(const bf16x8*)(sk + u * 8);
  }
  // stage entering-state S_c
  if (ch == 0) {
    for (int e = tid; e < 128 * 136 / 2; e += 256) ((unsigned int*)sS)[e] = 0u;
  } else {
    int vr = tid >> 1, hf = (tid & 1) * 64;
    const unsigned short* sp = sall_ptr(qact, g1out, cid, vr) + hf;
    #pragma unroll
    for (int u = 0; u < 8; u++)
      *(bf16x8*)&sS[vr * 136 + hf + u * 8] = *(const bf16x8*)(sp + u * 8);
  }
  // register operands: Q, W fragments; U, z scalars
  bf16x8 qf[4], wf[4];
  {
    const unsigned short* qsrc = qact + (size_t)(row0 + wid * 16 + lane16) * 8192 + qh * 128 + quad * 8;
    #pragma unroll
    for (int ks = 0; ks < 4; ks++) qf[ks] = *(const bf16x8*)(qsrc + ks * 32);
    const unsigned short* wsrc = W_all + (size_t)cid * 8192 + (wid * 16 + lane16) * 128 + quad * 8;
    #pragma unroll
    for (int ks = 0; ks < 4; ks++) wf[ks] = *(const bf16x8*)(wsrc + ks * 32);
  }
  unsigned short uvr[8][4], zr[8][4];
  {
    const unsigned short* usrc = U_all + (size_t)cid * 8192 + (wid * 16 + quad * 4) * 128 + lane16;
    const unsigned short* zsrc = g1out + (size_t)(row0 + wid * 16 + quad * 4) * NPAD + 8192 + h * 128 + lane16;
    #pragma unroll
    for (int nt = 0; nt < 8; nt++)
      #pragma unroll
      for (int r = 0; r < 4; r++) {
        uvr[nt][r] = usrc[r * 128 + nt * 16];
        zr[nt][r]  = zsrc[(size_t)r * NPAD + nt * 16];
      }
  }
  __syncthreads();   // B1

  // Dt = U - W.S^T
  {
    f32x4 aD[8];
    #pragma unroll
    for (int nt = 0; nt < 8; nt++) aD[nt] = f32x4{0.f,0.f,0.f,0.f};
    #pragma unroll
    for (int ks = 0; ks < 4; ks++)
      #pragma unroll
      for (int nt = 0; nt < 8; nt++) {
        bf16x8 bfr = *(const bf16x8*)&sS[(nt * 16 + lane16) * 136 + ks * 32 + quad * 8];
        aD[nt] = __builtin_amdgcn_mfma_f32_16x16x32_bf16(wf[ks], bfr, aD[nt], 0, 0, 0);
      }
    #pragma unroll
    for (int nt = 0; nt < 8; nt++)
      #pragma unroll
      for (int r = 0; r < 4; r++)
        sDt[(nt * 16 + lane16) * 72 + wid * 16 + quad * 4 + r] =
            (short)f2b(b2f(uvr[nt][r]) - aD[nt][r]);
  }
  // QK^T
  f32x4 aM[4];
  #pragma unroll
  for (int jt = 0; jt < 4; jt++) aM[jt] = f32x4{0.f,0.f,0.f,0.f};
  #pragma unroll
  for (int ks = 0; ks < 4; ks++)
    #pragma unroll
    for (int jt = 0; jt < 4; jt++) {
      bf16x8 bfr = *(const bf16x8*)&sKn[(jt * 16 + lane16) * 136 + ks * 32 + quad * 8];
      aM[jt] = __builtin_amdgcn_mfma_f32_16x16x32_bf16(qf[ks], bfr, aM[jt], 0, 0, 0);
    }
  __syncthreads();   // B2: sKn reads done (sM aliases), sDt written

  #pragma unroll
  for (int jt = 0; jt < 4; jt++) {
    int j = jt * 16 + lane16;
    float lj = sl[j];
    #pragma unroll
    for (int r = 0; r < 4; r++) {
      int i = wid * 16 + quad * 4 + r;
      float m = (j <= i) ? expf(sl[i] - lj) * aM[jt][r] : 0.f;
      sM[i * 72 + j] = (short)f2b(m);
    }
  }
  // O(inter) = diag(el) . (Q.S^T)
  f32x4 aO[8];
  #pragma unroll
  for (int nt = 0; nt < 8; nt++) aO[nt] = f32x4{0.f,0.f,0.f,0.f};
  #pragma unroll
  for (int ks = 0; ks < 4; ks++)
    #pragma unroll
    for (int nt = 0; nt < 8; nt++) {
      bf16x8 bfr = *(const bf16x8*)&sS[(nt * 16 + lane16) * 136 + ks * 32 + quad * 8];
      aO[nt] = __builtin_amdgcn_mfma_f32_16x16x32_bf16(qf[ks], bfr, aO[nt], 0, 0, 0);
    }
  #pragma unroll
  for (int r = 0; r < 4; r++) {
    float eli = sel[wid * 16 + quad * 4 + r];
    #pragma unroll
    for (int nt = 0; nt < 8; nt++) aO[nt][r] *= eli;
  }
  __syncthreads();   // B3: sM written

  // O += M.Dt
  {
    bf16x8 a2[2];
    #pragma unroll
    for (int ks2 = 0; ks2 < 2; ks2++)
      a2[ks2] = *(const bf16x8*)&sM[(wid * 16 + lane16) * 72 + ks2 * 32 + quad * 8];
    #pragma unroll
    for (int ks2 = 0; ks2 < 2; ks2++)
      #pragma unroll
      for (int nt = 0; nt < 8; nt++) {
        bf16x8 bfr = *(const bf16x8*)&sDt[(nt * 16 + lane16) * 72 + ks2 * 32 + quad * 8];
        aO[nt] = __builtin_amdgcn_mfma_f32_16x16x32_bf16(a2[ks2], bfr, aO[nt], 0, 0, 0);
      }
  }
  // epilogue: RMSNorm + z-gate, write y into g1out cols h*128..
  #pragma unroll
  for (int r = 0; r < 4; r++) {
    float ss = 0.f;
    #pragma unroll
    for (int nt = 0; nt < 8; nt++) ss += aO[nt][r] * aO[nt][r];
    ss += __shfl_xor(ss, 1, 64);
    ss += __shfl_xor(ss, 2, 64);
    ss += __shfl_xor(ss, 4, 64);
    ss += __shfl_xor(ss, 8, 64);
    float rinv = rsqrtf(ss * (1.f / 128.f) + 1e-6f);
    int i = wid * 16 + quad * 4 + r;
    size_t grow = (size_t)(row0 + i) * NPAD + h * 128;
    #pragma unroll
    for (int nt = 0; nt < 8; nt++) {
      int v = nt * 16 + lane16;
      float zv = b2f(zr[nt][r]);
      float zg = zv / (1.f + __expf(-zv));
      float y = snw[v] * (aO[nt][r] * rinv) * zg;
      g1out[grow + v] = f2b(y);
    }
  }
}

extern "C" void kernel_launch(void* const* d_in, const int* in_sizes, int n_in,
                              void* d_out, int out_size, void* d_ws, size_t ws_size,
                              hipStream_t stream)
{
  const float* hidden  = (const float*)d_in[0];
  const float* W_qkv   = (const float*)d_in[1];
  const float* W_z     = (const float*)d_in[2];
  const float* W_a     = (const float*)d_in[3];
  const float* W_b     = (const float*)d_in[4];
  const float* conv_w  = (const float*)d_in[5];
  const float* A_log   = (const float*)d_in[6];
  const float* dt_bias = (const float*)d_in[7];
  const float* norm_w  = (const float*)d_in[8];
  const float* W_out   = (const float*)d_in[9];

  char* ws = (char*)d_ws;
  unsigned short* hbf   = (unsigned short*)(ws);                 // [4096][2048] bf16
  unsigned short* Wcat  = (unsigned short*)(ws + 16777216ull);   // [12416][2048] bf16
  unsigned short* Woutb = (unsigned short*)(ws + 67633152ull);   // [2048][4096] bf16
  unsigned short* g1out = (unsigned short*)(ws + 84410368ull);   // [4096][12416] bf16
  unsigned short* qact  = (unsigned short*)(ws + 186122240ull);  // [4096][8192] bf16
  float* g_arr          = (float*)(ws + 253231104ull);           // [4096][32]
  float* beta           = (float*)(ws + 253755392ull);           // [4096][32]
  unsigned short* W_all = (unsigned short*)(ws);                 // aliases hbf (dead after GEMM1)
  unsigned short* U_all = (unsigned short*)(ws + 33554432ull);   // aliases Wcat tail

  float* out0 = (float*)d_out;          // (2,2048,2048) fp32
  float* out1 = out0 + 8388608;         // conv_state (2,8192,4)
  float* out2 = out0 + 8454144;         // state (2,32,128,128)

  cast_kernel<<<8192,  256, 0, stream>>>(hidden, hbf, 2097152);
  cast_kernel<<<16384, 256, 0, stream>>>(W_qkv, Wcat, 4194304);
  cast_kernel<<<8192,  256, 0, stream>>>(W_z,   Wcat + 8192ull  * 2048, 2097152);
  cast_kernel<<<64,    256, 0, stream>>>(W_a,   Wcat + 12288ull * 2048, 16384);
  cast_kernel<<<64,    256, 0, stream>>>(W_b,   Wcat + 12320ull * 2048, 16384);
  cast_kernel<<<8192,  256, 0, stream>>>(W_out, Woutb, 2097152);

  gemm_bt<true><<<dim3(97, 32), 256, 0, stream>>>(hbf, Wcat, g1out, 2048, 2048, 2048, NPAD, NTOT);
  gebeta_kernel<<<512, 256, 0, stream>>>(g1out, A_log, dt_bias, g_arr, beta);
  conv_kernel<<<dim3(4096, 8), 128, 0, stream>>>(g1out, conv_w, qact);
  convstate_kernel<<<256, 256, 0, stream>>>(g1out, out1);

  chunk_prep<<<2048, 256, 0, stream>>>(qact, g_arr, beta, W_all, U_all);
  state_scan<<<128, 512, 0, stream>>>(qact, g1out, g_arr, W_all, U_all, out2);
  chunk_out<<<2048, 256, 0, stream>>>(qact, g1out, g_arr, norm_w, W_all, U_all);

  gemm_bt<false><<<dim3(16, 32), 256, 0, stream>>>(g1out, Woutb, out0, 4096, NPAD, 4096, 2048, 2048);
}

// Round 2
// 857.043 us; speedup vs baseline: 1.2757x; 1.0394x over previous
//
#include <hip/hip_runtime.h>
#include <hip/hip_bf16.h>
#include <cstdint>

#define SEQ 2048
#define NPAD 12416      // 97*128, padded N for GEMM1
#define NTOT 12352      // qkv(8192) + z(4096) + a(32) + b(32)
#define CONV_INNER 8192

typedef __attribute__((ext_vector_type(8))) short bf16x8;
typedef __attribute__((ext_vector_type(4))) float f32x4;

__device__ __forceinline__ float b2f(unsigned short u) {
  union { unsigned int i; float f; } x; x.i = ((unsigned int)u) << 16; return x.f;
}
__device__ __forceinline__ unsigned short f2b(float f) {
  __hip_bfloat16 h = __float2bfloat16(f);
  return *reinterpret_cast<unsigned short*>(&h);
}
__device__ __forceinline__ void load_lds16(const short* g, short* l) {
  __builtin_amdgcn_global_load_lds(
      (__attribute__((address_space(1))) void*)(g),
      (__attribute__((address_space(3))) void*)(l), 16, 0, 0);
}

// S_all staging: state ENTERING chunk ch of (b,h), bf16 [128 v][128 k].
// Lives in dead workspace columns: qact cols 4096..8191 (v-region, dead after
// chunk_prep) for b=0 cids; g1out cols 4096..8191 (qkv_raw, dead after conv)
// for b=1 cids. One cid = 4 row-slots of 32 v-rows each.
__device__ __forceinline__ unsigned short* sall_ptr(
    unsigned short* qact, unsigned short* g1out, int cid, int vrow) {
  int slot = ((cid & 1023) << 2) + (vrow >> 5);
  if (cid < 1024) return qact + (size_t)slot * 8192 + 4096 + (vrow & 31) * 128;
  return g1out + (size_t)slot * (size_t)NPAD + 4096 + (vrow & 31) * 128;
}

// ---------------- fp32 -> bf16 cast ----------------
__global__ void cast_kernel(const float* __restrict__ in, unsigned short* __restrict__ out, int n4) {
  int i = blockIdx.x * blockDim.x + threadIdx.x;
  if (i >= n4) return;
  float4 v = ((const float4*)in)[i];
  ushort4 o;
  o.x = f2b(v.x); o.y = f2b(v.y); o.z = f2b(v.z); o.w = f2b(v.w);
  ((ushort4*)out)[i] = o;
}

// ---------------- bf16 MFMA GEMM (128^2, 2-barrier): C[m][n] = sum_k A[m][k]*B[n][k] ----
template<bool OUT_BF16>
__global__ __launch_bounds__(256) void gemm_bt(
    const unsigned short* __restrict__ A,   // [M][lda] bf16
    const unsigned short* __restrict__ Bm,  // [Nrows][ldb] bf16
    void* __restrict__ Cout, int K, int lda, int ldb, int ldc, int nmax)
{
  __shared__ __align__(16) short lA[2][128 * 32];
  __shared__ __align__(16) short lB[2][128 * 32];
  const int tid = threadIdx.x;
  const int lane = tid & 63, wid = tid >> 6;
  const int lane16 = lane & 15, quad = lane >> 4;
  const int wm = (wid & 1) * 64, wn = (wid >> 1) * 64;
  const int m0 = blockIdx.y * 128, n0 = blockIdx.x * 128;
  const int srow = wid * 16 + (lane >> 2);                  // staged tile row
  const int scol = (((lane & 3) ^ ((lane >> 3) & 3))) * 8;  // swizzled source chunk
  const int rchunk = (quad ^ ((lane16 >> 1) & 3)) * 8;      // swizzled fragment chunk

  f32x4 acc[4][4];
  #pragma unroll
  for (int i = 0; i < 4; i++)
    #pragma unroll
    for (int j = 0; j < 4; j++)
      acc[i][j] = f32x4{0.f, 0.f, 0.f, 0.f};

  const short* As = (const short*)A;
  const short* Bs = (const short*)Bm;
  short* lA0s[2] = { &lA[0][(wid * 16) * 32], &lA[1][(wid * 16) * 32] };
  short* lA1s[2] = { &lA[0][(64 + wid * 16) * 32], &lA[1][(64 + wid * 16) * 32] };
  short* lB0s[2] = { &lB[0][(wid * 16) * 32], &lB[1][(wid * 16) * 32] };
  short* lB1s[2] = { &lB[0][(64 + wid * 16) * 32], &lB[1][(64 + wid * 16) * 32] };
  const short* ga0 = As + (size_t)(m0 + srow) * lda + scol;
  const short* ga1 = As + (size_t)(m0 + 64 + srow) * lda + scol;
  const short* gb0 = Bs + (size_t)(n0 + srow) * ldb + scol;
  const short* gb1 = Bs + (size_t)(n0 + 64 + srow) * ldb + scol;

  for (int kb = 0; kb < K; kb += 64) {
    #pragma unroll
    for (int st = 0; st < 2; st++) {
      int ko = kb + st * 32;
      load_lds16(ga0 + ko, lA0s[st]);
      load_lds16(ga1 + ko, lA1s[st]);
      load_lds16(gb0 + ko, lB0s[st]);
      load_lds16(gb1 + ko, lB1s[st]);
    }
    __syncthreads();   // drains vmcnt -> both stages complete
    #pragma unroll
    for (int st = 0; st < 2; st++) {
      bf16x8 af[4], bfr[4];
      #pragma unroll
      for (int t = 0; t < 4; t++) af[t]  = *(const bf16x8*)&lA[st][(wm + t * 16 + lane16) * 32 + rchunk];
      #pragma unroll
      for (int t = 0; t < 4; t++) bfr[t] = *(const bf16x8*)&lB[st][(wn + t * 16 + lane16) * 32 + rchunk];
      #pragma unroll
      for (int i = 0; i < 4; i++)
        #pragma unroll
        for (int j = 0; j < 4; j++)
          acc[i][j] = __builtin_amdgcn_mfma_f32_16x16x32_bf16(af[i], bfr[j], acc[i][j], 0, 0, 0);
    }
    __syncthreads();   // all reads done before next overwrite
  }

  #pragma unroll
  for (int i = 0; i < 4; i++) {
    #pragma unroll
    for (int j = 0; j < 4; j++) {
      int n = n0 + wn + j * 16 + lane16;
      if (n >= nmax) continue;
      #pragma unroll
      for (int r = 0; r < 4; r++) {
        int m = m0 + wm + i * 16 + quad * 4 + r;
        float v = acc[i][j][r];
        if (OUT_BF16) ((unsigned short*)Cout)[(size_t)m * ldc + n] = f2b(v);
        else          ((float*)Cout)[(size_t)m * ldc + n] = v;
      }
    }
  }
}

// ======== 256x256 8-phase GEMM (T2+T3+T4+T5), bf16 out, B-row clamp ========
// 512 threads = 8 waves (2M x 4N); BK=64 double-buffered; per-wave C = 128x64.
// LDS [buf][hk 2][row 256][32 shorts], staged as K-half units (2 loads each).
// Steady state: every odd phase gates vmcnt(8) (8 loads always in flight).
__global__ __launch_bounds__(512, 2) void gemm1_256(
    const unsigned short* __restrict__ A,
    const unsigned short* __restrict__ Bm,
    unsigned short* __restrict__ Cout,
    int K, int lda, int ldb, int ldc, int nmax, int brmax, int tnc)
{
  __shared__ __align__(16) short lA[2][16384];
  __shared__ __align__(16) short lB[2][16384];
  const int tid = threadIdx.x;
  const int lane = tid & 63, wid = tid >> 6;
  const int lane16 = lane & 15, quad = lane >> 4;
  const int wm = (wid >> 2) * 128, wn = (wid & 3) * 64;
  const int cpx = gridDim.x >> 3;                 // grid % 8 == 0 (bijective)
  const int swz = ((int)blockIdx.x & 7) * cpx + ((int)blockIdx.x >> 3);
  const int tn = swz % tnc, tm = swz / tnc;
  const int m0 = tm * 256, n0 = tn * 256;
  const int srow = tid >> 2;                                // 0..127
  const int scol = ((tid & 3) ^ ((tid >> 3) & 3)) * 8;      // swizzled src chunk
  const int rchunk = (quad ^ ((lane16 >> 1) & 3)) * 8;      // swizzled read chunk
  const int NK = K >> 6;

  const short* As = (const short*)A;
  const short* Bs = (const short*)Bm;
  const size_t arow0 = (size_t)(m0 + srow) * lda;
  const size_t arow1 = (size_t)(m0 + 128 + srow) * lda;
  int br0i = n0 + srow;       if (br0i > brmax) br0i = brmax;
  int br1i = n0 + 128 + srow; if (br1i > brmax) br1i = brmax;
  const size_t brow0 = (size_t)br0i * ldb;
  const size_t brow1 = (size_t)br1i * ldb;
  short* dA[2] = { &lA[0][wid * 512], &lA[1][wid * 512] };
  short* dB[2] = { &lB[0][wid * 512], &lB[1][wid * 512] };

  f32x4 acc[8][4];
  #pragma unroll
  for (int i = 0; i < 8; i++)
    #pragma unroll
    for (int j = 0; j < 4; j++) acc[i][j] = f32x4{0.f, 0.f, 0.f, 0.f};

  auto stgA = [&](int buf, int hk, int kt) {
    int co = kt * 64 + hk * 32 + scol;
    load_lds16(As + arow0 + co, dA[buf] + hk * 8192);
    load_lds16(As + arow1 + co, dA[buf] + hk * 8192 + 4096);
  };
  auto stgB = [&](int buf, int hk, int kt) {
    int co = kt * 64 + hk * 32 + scol;
    load_lds16(Bs + brow0 + co, dB[buf] + hk * 8192);
    load_lds16(Bs + brow1 + co, dB[buf] + hk * 8192 + 4096);
  };

#define G1_BAR()   __builtin_amdgcn_s_barrier()
#define G1_LGKM0() { asm volatile("s_waitcnt lgkmcnt(0)" ::: "memory"); \
                     __builtin_amdgcn_sched_barrier(0); }
#define G1_VM8()   asm volatile("s_waitcnt vmcnt(8)" ::: "memory")
#define G1_VM0()   asm volatile("s_waitcnt vmcnt(0)" ::: "memory")
#define G1_MFMA4(mbase) \
  { __builtin_amdgcn_s_setprio(1); \
    _Pragma("unroll") \
    for (int mt = 0; mt < 4; mt++) \
      _Pragma("unroll") \
      for (int jt = 0; jt < 4; jt++) \
        acc[(mbase) + mt][jt] = __builtin_amdgcn_mfma_f32_16x16x32_bf16( \
            af[mt], bfr[jt], acc[(mbase) + mt][jt], 0, 0, 0); \
    __builtin_amdgcn_s_setprio(0); }

  // prologue: T0 (buf0) fully + T1.hk0 (buf1) = 6 units, 12 loads in order
  stgA(0, 0, 0); stgB(0, 0, 0); stgA(0, 1, 0); stgB(0, 1, 0);
  stgA(1, 0, 1); stgB(1, 0, 1);
  G1_VM8();          // first 4 loads (T0.hk0 A+B) landed
  G1_BAR();

  for (int it = 0; it < (NK >> 1); it++) {
    const int t0 = 2 * it, t1 = 2 * it + 1;
    const bool s2 = (t0 + 2) < NK;   // prefetch tile t0+2 -> buf0
    const bool s3 = (t1 + 2) < NK;   // prefetch tile t1+2 -> buf1
    bf16x8 af[4], bfr[4];

    // ---- p0: T0 ks0, m0-3 (+B ks0); stage T1.A.hk1 -> buf1 ----
    #pragma unroll
    for (int jt = 0; jt < 4; jt++)
      bfr[jt] = *(const bf16x8*)&lB[0][(wn + jt * 16 + lane16) * 32 + rchunk];
    #pragma unroll
    for (int mt = 0; mt < 4; mt++)
      af[mt] = *(const bf16x8*)&lA[0][(wm + mt * 16 + lane16) * 32 + rchunk];
    stgA(1, 1, t1);
    G1_BAR(); G1_LGKM0(); G1_MFMA4(0); G1_BAR();

    // ---- p1: T0 ks0, m4-7; stage T1.B.hk1 -> buf1; vmcnt(8) ----
    #pragma unroll
    for (int mt = 0; mt < 4; mt++)
      af[mt] = *(const bf16x8*)&lA[0][(wm + 64 + mt * 16 + lane16) * 32 + rchunk];
    stgB(1, 1, t1);
    G1_BAR(); G1_LGKM0(); G1_MFMA4(4); G1_VM8(); G1_BAR();

    // ---- p2: T0 ks1, m0-3 (+B ks1); stage T2.A.hk0 -> buf0 ----
    #pragma unroll
    for (int jt = 0; jt < 4; jt++)
      bfr[jt] = *(const bf16x8*)&lB[0][8192 + (wn + jt * 16 + lane16) * 32 + rchunk];
    #pragma unroll
    for (int mt = 0; mt < 4; mt++)
      af[mt] = *(const bf16x8*)&lA[0][8192 + (wm + mt * 16 + lane16) * 32 + rchunk];
    if (s2) stgA(0, 0, t0 + 2);
    G1_BAR(); G1_LGKM0(); G1_MFMA4(0); G1_BAR();

    // ---- p3: T0 ks1, m4-7; stage T2.B.hk0 -> buf0; vmcnt ----
    #pragma unroll
    for (int mt = 0; mt < 4; mt++)
      af[mt] = *(const bf16x8*)&lA[0][8192 + (wm + 64 + mt * 16 + lane16) * 32 + rchunk];
    if (s2) stgB(0, 0, t0 + 2);
    G1_BAR(); G1_LGKM0(); G1_MFMA4(4);
    if (s2) { G1_VM8(); } else { G1_VM0(); }
    G1_BAR();

    // ---- p4: T1 ks0, m0-3 (+B ks0); stage T2.A.hk1 -> buf0 ----
    #pragma unroll
    for (int jt = 0; jt < 4; jt++)
      bfr[jt] = *(const bf16x8*)&lB[1][(wn + jt * 16 + lane16) * 32 + rchunk];
    #pragma unroll
    for (int mt = 0; mt < 4; mt++)
      af[mt] = *(const bf16x8*)&lA[1][(wm + mt * 16 + lane16) * 32 + rchunk];
    if (s2) stgA(0, 1, t0 + 2);
    G1_BAR(); G1_LGKM0(); G1_MFMA4(0); G1_BAR();

    // ---- p5: T1 ks0, m4-7; stage T2.B.hk1 -> buf0; vmcnt ----
    #pragma unroll
    for (int mt = 0; mt < 4; mt++)
      af[mt] = *(const bf16x8*)&lA[1][(wm + 64 + mt * 16 + lane16) * 32 + rchunk];
    if (s2) stgB(0, 1, t0 + 2);
    G1_BAR(); G1_LGKM0(); G1_MFMA4(4);
    if (s2) { G1_VM8(); } else { G1_VM0(); }
    G1_BAR();

    // ---- p6: T1 ks1, m0-3 (+B ks1); stage T3.A.hk0 -> buf1 ----
    #pragma unroll
    for (int jt = 0; jt < 4; jt++)
      bfr[jt] = *(const bf16x8*)&lB[1][8192 + (wn + jt * 16 + lane16) * 32 + rchunk];
    #pragma unroll
    for (int mt = 0; mt < 4; mt++)
      af[mt] = *(const bf16x8*)&lA[1][8192 + (wm + mt * 16 + lane16) * 32 + rchunk];
    if (s3) stgA(1, 0, t1 + 2);
    G1_BAR(); G1_LGKM0(); G1_MFMA4(0); G1_BAR();

    // ---- p7: T1 ks1, m4-7; stage T3.B.hk0 -> buf1; vmcnt(8) ----
    #pragma unroll
    for (int mt = 0; mt < 4; mt++)
      af[mt] = *(const bf16x8*)&lA[1][8192 + (wm + 64 + mt * 16 + lane16) * 32 + rchunk];
    if (s3) stgB(1, 0, t1 + 2);
    G1_BAR(); G1_LGKM0(); G1_MFMA4(4); G1_VM8(); G1_BAR();
  }

  #pragma unroll
  for (int mt = 0; mt < 8; mt++)
    #pragma unroll
    for (int jt = 0; jt < 4; jt++) {
      int n = n0 + wn + jt * 16 + lane16;
      if (n >= nmax) continue;
      #pragma unroll
      for (int r = 0; r < 4; r++) {
        int m = m0 + wm + mt * 16 + quad * 4 + r;
        Cout[(size_t)m * ldc + n] = f2b(acc[mt][jt][r]);
      }
    }
#undef G1_BAR
#undef G1_LGKM0
#undef G1_VM8
#undef G1_VM0
#undef G1_MFMA4
}

// ---------------- gates: g (log decay) and beta ----------------
__global__ void gebeta_kernel(const unsigned short* __restrict__ g1out,
                              const float* __restrict__ A_log, const float* __restrict__ dt_bias,
                              float* __restrict__ g_out, float* __restrict__ beta)
{
  int idx = blockIdx.x * blockDim.x + threadIdx.x;  // 131072 = 4096*32
  int r = idx >> 5, n = idx & 31;
  float a = b2f(g1out[(size_t)r * NPAD + 12288 + n]) + dt_bias[n];
  float sp = (a > 20.f) ? a : log1pf(expf(a));
  g_out[idx] = -expf(A_log[n]) * sp;
  float bv = b2f(g1out[(size_t)r * NPAD + 12320 + n]);
  beta[idx] = 1.f / (1.f + expf(-bv));
}

// ---------------- conv(4) + silu + l2norm(q,k), 8 ch/thread ----------------
__global__ __launch_bounds__(128) void conv_kernel(
    const unsigned short* __restrict__ g1out, const float* __restrict__ conv_w,
    unsigned short* __restrict__ qkv_act)
{
  const int row = blockIdx.x;            // b*SEQ + s
  const int hg  = blockIdx.y;            // 0..7 (1024 channels each)
  const int tid = threadIdx.x;           // 0..127
  const int c0 = hg * 1024 + tid * 8;
  const int s = row & (SEQ - 1);
  float4 w4[8];
  #pragma unroll
  for (int e = 0; e < 8; e++) w4[e] = *(const float4*)(conv_w + (size_t)(c0 + e) * 4);
  float acc[8] = {0.f,0.f,0.f,0.f,0.f,0.f,0.f,0.f};
  #pragma unroll
  for (int j = 0; j < 4; j++) {
    int sj = s - 3 + j;
    if (sj >= 0) {
      bf16x8 x = *(const bf16x8*)(g1out + (size_t)(row - 3 + j) * NPAD + c0);
      #pragma unroll
      for (int e = 0; e < 8; e++) {
        float wj = (j == 0) ? w4[e].x : (j == 1) ? w4[e].y : (j == 2) ? w4[e].z : w4[e].w;
        acc[e] += wj * b2f((unsigned short)x[e]);
      }
    }
  }
  float sv[8], ssq = 0.f;
  #pragma unroll
  for (int e = 0; e < 8; e++) {
    sv[e] = acc[e] / (1.f + __expf(-acc[e]));
    ssq += sv[e] * sv[e];
  }
  ssq += __shfl_xor(ssq, 1, 64);
  ssq += __shfl_xor(ssq, 2, 64);
  ssq += __shfl_xor(ssq, 4, 64);
  ssq += __shfl_xor(ssq, 8, 64);
  float scale = 1.f;
  if (hg < 4) {
    scale = rsqrtf(ssq + 1e-6f);
    if (hg < 2) scale *= 0.08838834764831845f;  // q: 1/sqrt(128)
  }
  bf16x8 o;
  #pragma unroll
  for (int e = 0; e < 8; e++) o[e] = (short)f2b(sv[e] * scale);
  *(bf16x8*)(qkv_act + (size_t)row * CONV_INNER + c0) = o;
}

// ---------------- conv_state output ----------------
__global__ void convstate_kernel(const unsigned short* __restrict__ g1out, float* __restrict__ out1)
{
  int idx = blockIdx.x * blockDim.x + threadIdx.x;
  int b = idx >> 15, rem = idx & 32767;
  int c = rem >> 2, j = rem & 3;
  out1[idx] = b2f(g1out[(size_t)(b * SEQ + SEQ - 4 + j) * NPAD + c]);
}

// ================= PASS 1: chunk-local W,U (UT transform) =================
__global__ __launch_bounds__(256, 2) void chunk_prep(
    const unsigned short* __restrict__ qact,
    const float* __restrict__ g_arr, const float* __restrict__ beta_arr,
    unsigned short* __restrict__ W_all, unsigned short* __restrict__ U_all)
{
  __shared__ __align__(16) char smem[73472];
  short* sKn = (short*)smem;                  // 64 x stride152; Vt (128x72) aliases
  short* sVt = (short*)smem;
  short* sKt = (short*)(smem + 19456);        // 128 x 72
  float* sA  = (float*)(smem + 37888);        // 64 x 68 fp32; Tb aliases
  short* sTb = (short*)(smem + 37888);        // 64 x 72 bf16
  float* sT  = (float*)(smem + 55296);        // 64 x 68 fp32
  float* sl  = (float*)(smem + 72704);
  float* sel = (float*)(smem + 72960);
  float* sbb = (float*)(smem + 73216);

  const int tid = threadIdx.x, lane = tid & 63, wid = tid >> 6;
  const int lane16 = lane & 15, quad = lane >> 4;
  const int cid = blockIdx.x;
  const int ch = cid & 31, h = (cid >> 5) & 31, b = cid >> 10;
  const int qh = h >> 1;
  const int row0 = b * SEQ + ch * 64;

  float gv = g_arr[(size_t)(row0 + lane) * 32 + h];
  float bb = beta_arr[(size_t)(row0 + lane) * 32 + h];
  float l = gv;
  #pragma unroll
  for (int off = 1; off < 64; off <<= 1) {
    float p = __shfl_up(l, off, 64);
    if (lane >= off) l += p;
  }
  float el = expf(l);
  if (wid == 0) { sl[lane] = l; sel[lane] = el; sbb[lane] = bb; }

  {
    int j = tid >> 2, kc = (tid & 3) * 32;
    const unsigned short* src = qact + (size_t)(row0 + j) * CONV_INNER + 2048 + qh * 128 + kc;
    #pragma unroll
    for (int u = 0; u < 4; u++) {
      bf16x8 r = *(const bf16x8*)(src + u * 8);
      *(bf16x8*)&sKn[j * 152 + kc + u * 8] = r;
    }
  }
  {
    const unsigned short* src = qact + (size_t)(row0 + lane) * CONV_INNER + 2048 + qh * 128 + wid * 32;
    float cj = bb * el;
    #pragma unroll
    for (int u = 0; u < 4; u++) {
      bf16x8 r = *(const bf16x8*)(src + u * 8);
      #pragma unroll
      for (int e = 0; e < 8; e++)
        sKt[(wid * 32 + u * 8 + e) * 72 + lane] = (short)f2b(b2f((unsigned short)r[e]) * cj);
    }
  }
  __syncthreads();

  {
    f32x4 accA[4];
    #pragma unroll
    for (int t = 0; t < 4; t++) accA[t] = f32x4{0.f, 0.f, 0.f, 0.f};
    #pragma unroll
    for (int ks = 0; ks < 4; ks++) {
      bf16x8 a = *(const bf16x8*)&sKn[(wid * 16 + lane16) * 152 + ks * 32 + quad * 8];
      #pragma unroll
      for (int jt = 0; jt < 4; jt++) {
        bf16x8 bfr = *(const bf16x8*)&sKn[(jt * 16 + lane16) * 152 + ks * 32 + quad * 8];
        accA[jt] = __builtin_amdgcn_mfma_f32_16x16x32_bf16(a, bfr, accA[jt], 0, 0, 0);
      }
    }
    #pragma unroll
    for (int jt = 0; jt < 4; jt++) {
      int j = jt * 16 + lane16;
      float lj = sl[j];
      #pragma unroll
      for (int r = 0; r < 4; r++) {
        int i = wid * 16 + quad * 4 + r;
        float v = (j < i) ? sbb[i] * expf(sl[i] - lj) * accA[jt][r] : 0.f;
        sA[i * 68 + j] = v;
      }
    }
  }
  __syncthreads();

  {
    const unsigned short* src = qact + (size_t)(row0 + lane) * CONV_INNER + 4096 + h * 128 + wid * 32;
    #pragma unroll
    for (int u = 0; u < 4; u++) {
      bf16x8 r = *(const bf16x8*)(src + u * 8);
      #pragma unroll
      for (int e = 0; e < 8; e++)
        sVt[(wid * 32 + u * 8 + e) * 72 + lane] = (short)f2b(b2f((unsigned short)r[e]) * bb);
    }
  }
  __syncthreads();

  if (wid == 0 && lane < 32) {
    int c = lane;
    float treg[32];
    treg[0] = (c == 0) ? 1.f : 0.f;
    #pragma unroll
    for (int i = 1; i < 32; i++) {
      float s = 0.f;
      #pragma unroll
      for (int j = 0; j < i; j++) s += sA[i * 68 + j] * treg[j];
      treg[i] = ((i == c) ? 1.f : 0.f) - s;
    }
    #pragma unroll
    for (int i = 0; i < 32; i++) sT[i * 68 + c] = treg[i];
  } else if (wid == 1 && lane < 32) {
    int c = lane;
    float treg[32];
    treg[0] = (c == 0) ? 1.f : 0.f;
    #pragma unroll
    for (int i = 1; i < 32; i++) {
      float s = 0.f;
      #pragma unroll
      for (int j = 0; j < i; j++) s += sA[(32 + i) * 68 + 32 + j] * treg[j];
      treg[i] = ((i == c) ? 1.f : 0.f) - s;
    }
    #pragma unroll
    for (int i = 0; i < 32; i++) sT[(32 + i) * 68 + 32 + c] = treg[i];
  } else if (wid == 2) {
    for (int e = lane; e < 1024; e += 64) sT[(e >> 5) * 68 + 32 + (e & 31)] = 0.f;
  }
  __syncthreads();

  {
    int i = tid & 31, c0 = (tid >> 5) * 4;
    float x[4] = {0.f, 0.f, 0.f, 0.f};
    #pragma unroll
    for (int j = 0; j < 32; j++) {
      float a = sA[(32 + i) * 68 + j];
      #pragma unroll
      for (int cc = 0; cc < 4; cc++) x[cc] += a * sT[j * 68 + c0 + cc];
    }
    #pragma unroll
    for (int cc = 0; cc < 4; cc++) sA[i * 68 + c0 + cc] = x[cc];
  }
  __syncthreads();
  {
    int i = tid & 31, c0 = (tid >> 5) * 4;
    float x[4] = {0.f, 0.f, 0.f, 0.f};
    #pragma unroll
    for (int j = 0; j < 32; j++) {
      float t2 = sT[(32 + i) * 68 + 32 + j];
      #pragma unroll
      for (int cc = 0; cc < 4; cc++) x[cc] += t2 * sA[j * 68 + c0 + cc];
    }
    #pragma unroll
    for (int cc = 0; cc < 4; cc++) sT[(32 + i) * 68 + c0 + cc] = -x[cc];
  }
  __syncthreads();
  #pragma unroll
  for (int ii = 0; ii < 16; ii++) {
    int e = tid + 256 * ii;
    int r = e >> 6, cc = e & 63;
    sTb[r * 72 + cc] = (short)f2b(sT[r * 68 + cc]);
  }
  __syncthreads();

  {
    f32x4 accW[8], accU[8];
    #pragma unroll
    for (int nt = 0; nt < 8; nt++) { accW[nt] = f32x4{0.f,0.f,0.f,0.f}; accU[nt] = f32x4{0.f,0.f,0.f,0.f}; }
    bf16x8 ta[2];
    #pragma unroll
    for (int ks = 0; ks < 2; ks++)
      ta[ks] = *(const bf16x8*)&sTb[(wid * 16 + lane16) * 72 + ks * 32 + quad * 8];
    #pragma unroll
    for (int nt = 0; nt < 8; nt++) {
      #pragma unroll
      for (int ks = 0; ks < 2; ks++) {
        bf16x8 bk = *(const bf16x8*)&sKt[(nt * 16 + lane16) * 72 + ks * 32 + quad * 8];
        accW[nt] = __builtin_amdgcn_mfma_f32_16x16x32_bf16(ta[ks], bk, accW[nt], 0, 0, 0);
        bf16x8 bv = *(const bf16x8*)&sVt[(nt * 16 + lane16) * 72 + ks * 32 + quad * 8];
        accU[nt] = __builtin_amdgcn_mfma_f32_16x16x32_bf16(ta[ks], bv, accU[nt], 0, 0, 0);
      }
    }
    unsigned short* Wg = W_all + (size_t)cid * 8192;
    unsigned short* Ug = U_all + (size_t)cid * 8192;
    #pragma unroll
    for (int nt = 0; nt < 8; nt++)
      #pragma unroll
      for (int r = 0; r < 4; r++) {
        int i = wid * 16 + quad * 4 + r, k = nt * 16 + lane16;
        Wg[i * 128 + k] = f2b(accW[nt][r]);
        Ug[i * 128 + k] = f2b(accU[nt][r]);
      }
  }
}

// ================= PASS 2a: sequential state recurrence only =================
__global__ __launch_bounds__(512) void state_scan(
    unsigned short* qact, unsigned short* g1out,
    const float* __restrict__ g_arr,
    const unsigned short* __restrict__ W_all, const unsigned short* __restrict__ U_all,
    float* __restrict__ state_out)
{
  __shared__ __align__(16) short sS[64 * 136];    // S half-tile [64v][128k] bf16
  __shared__ __align__(16) short sDt[64 * 72];    // Dt [64v][64t] bf16
  __shared__ __align__(16) short sK2[128 * 72];   // K2^T [128k'][64t] bf16
  const int tid = threadIdx.x, lane = tid & 63, w = tid >> 6;
  const int lane16 = lane & 15, quad = lane >> 4;
  const int bid = blockIdx.x;
  const int bh = bid >> 1, vs = bid & 1;
  const int h = bh & 31, b = bh >> 5, qh = h >> 1;
  const int V0 = vs * 64;
  const int tt = w >> 1, vhl = (w & 1) * 32;      // aD work split
  const int avt = w & 3, kt0 = (w >> 2) * 4;      // aS work split

  for (int e = tid; e < 64 * 136 / 2; e += 512) ((unsigned int*)sS)[e] = 0u;
  float Sreg[4][4];
  #pragma unroll
  for (int n = 0; n < 4; n++)
    #pragma unroll
    for (int r = 0; r < 4; r++) Sreg[n][r] = 0.f;

  // ---- prefetch chunk 0 ----
  float gvn;
  bf16x8 kn[2], wn[4];
  unsigned short un[8];
  {
    const int r0_ = b * SEQ, cid_ = bh << 5;
    gvn = g_arr[(size_t)(r0_ + lane) * 32 + h];
    const unsigned short* ks_ = qact + (size_t)(r0_ + lane) * 8192 + 2048 + qh * 128 + w * 16;
    kn[0] = *(const bf16x8*)ks_; kn[1] = *(const bf16x8*)(ks_ + 8);
    const unsigned short* ws_ = W_all + (size_t)cid_ * 8192 + (tt * 16 + lane16) * 128 + quad * 8;
    #pragma unroll
    for (int ks = 0; ks < 4; ks++) wn[ks] = *(const bf16x8*)(ws_ + ks * 32);
    const unsigned short* us_ = U_all + (size_t)cid_ * 8192 + (tt * 16 + quad * 4) * 128 + V0 + vhl + lane16;
    #pragma unroll
    for (int vt = 0; vt < 2; vt++)
      #pragma unroll
      for (int r = 0; r < 4; r++) un[vt * 4 + r] = us_[r * 128 + vt * 16];
  }

  for (int ch = 0; ch < 32; ch++) {
    const int cid = (bh << 5) + ch;
    float l = gvn;
    #pragma unroll
    for (int off = 1; off < 64; off <<= 1) {
      float p = __shfl_up(l, off, 64);
      if (lane >= off) l += p;
    }
    float lC = __shfl(l, 63, 64);
    float elC = expf(lC);
    float s2 = expf(lC - l);
    #pragma unroll
    for (int e = 0; e < 8; e++)
      sK2[(w * 16 + e) * 72 + lane] = (short)f2b(b2f((unsigned short)kn[0][e]) * s2);
    #pragma unroll
    for (int e = 0; e < 8; e++)
      sK2[(w * 16 + 8 + e) * 72 + lane] = (short)f2b(b2f((unsigned short)kn[1][e]) * s2);
    bf16x8 wc[4];
    #pragma unroll
    for (int ks = 0; ks < 4; ks++) wc[ks] = wn[ks];
    unsigned short uc[8];
    #pragma unroll
    for (int i = 0; i < 8; i++) uc[i] = un[i];

    if (ch < 31) {
      const int r0_ = b * SEQ + (ch + 1) * 64, cid_ = cid + 1;
      gvn = g_arr[(size_t)(r0_ + lane) * 32 + h];
      const unsigned short* ks_ = qact + (size_t)(r0_ + lane) * 8192 + 2048 + qh * 128 + w * 16;
      kn[0] = *(const bf16x8*)ks_; kn[1] = *(const bf16x8*)(ks_ + 8);
      const unsigned short* ws_ = W_all + (size_t)cid_ * 8192 + (tt * 16 + lane16) * 128 + quad * 8;
      #pragma unroll
      for (int ks = 0; ks < 4; ks++) wn[ks] = *(const bf16x8*)(ws_ + ks * 32);
      const unsigned short* us_ = U_all + (size_t)cid_ * 8192 + (tt * 16 + quad * 4) * 128 + V0 + vhl + lane16;
      #pragma unroll
      for (int vt = 0; vt < 2; vt++)
        #pragma unroll
        for (int r = 0; r < 4; r++) un[vt * 4 + r] = us_[r * 128 + vt * 16];
    }
    asm volatile("s_waitcnt lgkmcnt(0)" ::: "memory");
    __builtin_amdgcn_s_barrier();      // bar1: sS(entering) + sK2 ready

    // Dt = U - W.S^T  -> out[t][v]
    f32x4 aD[2];
    aD[0] = f32x4{0.f,0.f,0.f,0.f}; aD[1] = f32x4{0.f,0.f,0.f,0.f};
    #pragma unroll
    for (int ks = 0; ks < 4; ks++)
      #pragma unroll
      for (int vt = 0; vt < 2; vt++) {
        bf16x8 bfr = *(const bf16x8*)&sS[(vhl + vt * 16 + lane16) * 136 + ks * 32 + quad * 8];
        aD[vt] = __builtin_amdgcn_mfma_f32_16x16x32_bf16(wc[ks], bfr, aD[vt], 0, 0, 0);
      }
    #pragma unroll
    for (int vt = 0; vt < 2; vt++)
      #pragma unroll
      for (int r = 0; r < 4; r++)
        sDt[(vhl + vt * 16 + lane16) * 72 + tt * 16 + quad * 4 + r] =
            (short)f2b(b2f(uc[vt * 4 + r]) - aD[vt][r]);
    asm volatile("s_waitcnt lgkmcnt(0)" ::: "memory");
    __builtin_amdgcn_s_barrier();      // bar2: sDt ready

    // S <- elC*S + Dt.K2
    bf16x8 a2[2];
    #pragma unroll
    for (int ks2 = 0; ks2 < 2; ks2++)
      a2[ks2] = *(const bf16x8*)&sDt[(avt * 16 + lane16) * 72 + ks2 * 32 + quad * 8];
    f32x4 aS[4];
    #pragma unroll
    for (int n = 0; n < 4; n++) aS[n] = f32x4{0.f,0.f,0.f,0.f};
    #pragma unroll
    for (int n = 0; n < 4; n++)
      #pragma unroll
      for (int ks2 = 0; ks2 < 2; ks2++) {
        bf16x8 bfr = *(const bf16x8*)&sK2[((kt0 + n) * 16 + lane16) * 72 + ks2 * 32 + quad * 8];
        aS[n] = __builtin_amdgcn_mfma_f32_16x16x32_bf16(a2[ks2], bfr, aS[n], 0, 0, 0);
      }
    #pragma unroll
    for (int r = 0; r < 4; r++) {
      int vg = V0 + avt * 16 + quad * 4 + r;
      unsigned short* sp = nullptr;
      if (ch < 31) sp = sall_ptr(qact, g1out, cid + 1, vg);
      #pragma unroll
      for (int n = 0; n < 4; n++) {
        float v = elC * Sreg[n][r] + aS[n][r];
        Sreg[n][r] = v;
        unsigned short bv = f2b(v);
        sS[(avt * 16 + quad * 4 + r) * 136 + (kt0 + n) * 16 + lane16] = (short)bv;
        if (ch < 31) sp[(kt0 + n) * 16 + lane16] = bv;
      }
    }
    asm volatile("s_waitcnt lgkmcnt(0)" ::: "memory");
    __builtin_amdgcn_s_barrier();      // bar3: sS(new) written; sDt/sK2 reads done
  }

  float* so = state_out + (size_t)bh * 16384;
  #pragma unroll
  for (int r = 0; r < 4; r++)
    #pragma unroll
    for (int n = 0; n < 4; n++)
      so[(size_t)(V0 + avt * 16 + quad * 4 + r) * 128 + (kt0 + n) * 16 + lane16] = Sreg[n][r];
}

// ================= PASS 2b: per-chunk output (fully parallel) =================
__global__ __launch_bounds__(256) void chunk_out(
    unsigned short* qact, unsigned short* g1out,
    const float* __restrict__ g_arr, const float* __restrict__ norm_w,
    const unsigned short* __restrict__ W_all, const unsigned short* __restrict__ U_all)
{
  __shared__ __align__(16) short sS[128 * 136];   // 34816 B
  __shared__ __align__(16) short sKn[64 * 136];   // 17408 B ; sM aliases
  __shared__ __align__(16) short sDt[128 * 72];   // 18432 B
  __shared__ float sl[64];
  __shared__ float sel[64];
  __shared__ float snw[128];
  short* sM = sKn;
  const int tid = threadIdx.x, lane = tid & 63, wid = tid >> 6;
  const int lane16 = lane & 15, quad = lane >> 4;
  const int cid = blockIdx.x;
  const int ch = cid & 31, h = (cid >> 5) & 31, b = cid >> 10, qh = h >> 1;
  const int row0 = b * SEQ + ch * 64;

  float l = g_arr[(size_t)(row0 + lane) * 32 + h];
  #pragma unroll
  for (int off = 1; off < 64; off <<= 1) {
    float p = __shfl_up(l, off, 64);
    if (lane >= off) l += p;
  }
  if (wid == 0) { sl[lane] = l; sel[lane] = expf(l); }
  if (tid < 128) snw[tid] = norm_w[tid];

  {
    int j4 = tid >> 2, kc = (tid & 3) * 32;
    const unsigned short* sk = qact + (size_t)(row0 + j4) * 8192 + 2048 + qh * 128 + kc;
    #pragma unroll
    for (int u = 0; u < 4; u++)
      *(bf16x8*)&sKn[j4 * 136 + kc + u * 8] = *(const bf16x8*)(sk + u * 8);
  }
  if (ch == 0) {
    for (int e = tid; e < 128 * 136 / 2; e += 256) ((unsigned int*)sS)[e] = 0u;
  } else {
    int vr = tid >> 1, hf = (tid & 1) * 64;
    const unsigned short* sp = sall_ptr(qact, g1out, cid, vr) + hf;
    #pragma unroll
    for (int u = 0; u < 8; u++)
      *(bf16x8*)&sS[vr * 136 + hf + u * 8] = *(const bf16x8*)(sp + u * 8);
  }
  bf16x8 qf[4], wf[4];
  {
    const unsigned short* qsrc = qact + (size_t)(row0 + wid * 16 + lane16) * 8192 + qh * 128 + quad * 8;
    #pragma unroll
    for (int ks = 0; ks < 4; ks++) qf[ks] = *(const bf16x8*)(qsrc + ks * 32);
    const unsigned short* wsrc = W_all + (size_t)cid * 8192 + (wid * 16 + lane16) * 128 + quad * 8;
    #pragma unroll
    for (int ks = 0; ks < 4; ks++) wf[ks] = *(const bf16x8*)(wsrc + ks * 32);
  }
  unsigned short uvr[8][4], zr[8][4];
  {
    const unsigned short* usrc = U_all + (size_t)cid * 8192 + (wid * 16 + quad * 4) * 128 + lane16;
    const unsigned short* zsrc = g1out + (size_t)(row0 + wid * 16 + quad * 4) * NPAD + 8192 + h * 128 + lane16;
    #pragma unroll
    for (int nt = 0; nt < 8; nt++)
      #pragma unroll
      for (int r = 0; r < 4; r++) {
        uvr[nt][r] = usrc[r * 128 + nt * 16];
        zr[nt][r]  = zsrc[(size_t)r * NPAD + nt * 16];
      }
  }
  __syncthreads();   // B1

  {
    f32x4 aD[8];
    #pragma unroll
    for (int nt = 0; nt < 8; nt++) aD[nt] = f32x4{0.f,0.f,0.f,0.f};
    #pragma unroll
    for (int ks = 0; ks < 4; ks++)
      #pragma unroll
      for (int nt = 0; nt < 8; nt++) {
        bf16x8 bfr = *(const bf16x8*)&sS[(nt * 16 + lane16) * 136 + ks * 32 + quad * 8];
        aD[nt] = __builtin_amdgcn_mfma_f32_16x16x32_bf16(wf[ks], bfr, aD[nt], 0, 0, 0);
      }
    #pragma unroll
    for (int nt = 0; nt < 8; nt++)
      #pragma unroll
      for (int r = 0; r < 4; r++)
        sDt[(nt * 16 + lane16) * 72 + wid * 16 + quad * 4 + r] =
            (short)f2b(b2f(uvr[nt][r]) - aD[nt][r]);
  }
  f32x4 aM[4];
  #pragma unroll
  for (int jt = 0; jt < 4; jt++) aM[jt] = f32x4{0.f,0.f,0.f,0.f};
  #pragma unroll
  for (int ks = 0; ks < 4; ks++)
    #pragma unroll
    for (int jt = 0; jt < 4; jt++) {
      bf16x8 bfr = *(const bf16x8*)&sKn[(jt * 16 + lane16) * 136 + ks * 32 + quad * 8];
      aM[jt] = __builtin_amdgcn_mfma_f32_16x16x32_bf16(qf[ks], bfr, aM[jt], 0, 0, 0);
    }
  __syncthreads();   // B2

  #pragma unroll
  for (int jt = 0; jt < 4; jt++) {
    int j = jt * 16 + lane16;
    float lj = sl[j];
    #pragma unroll
    for (int r = 0; r < 4; r++) {
      int i = wid * 16 + quad * 4 + r;
      float m = (j <= i) ? expf(sl[i] - lj) * aM[jt][r] : 0.f;
      sM[i * 72 + j] = (short)f2b(m);
    }
  }
  f32x4 aO[8];
  #pragma unroll
  for (int nt = 0; nt < 8; nt++) aO[nt] = f32x4{0.f,0.f,0.f,0.f};
  #pragma unroll
  for (int ks = 0; ks < 4; ks++)
    #pragma unroll
    for (int nt = 0; nt < 8; nt++) {
      bf16x8 bfr = *(const bf16x8*)&sS[(nt * 16 + lane16) * 136 + ks * 32 + quad * 8];
      aO[nt] = __builtin_amdgcn_mfma_f32_16x16x32_bf16(qf[ks], bfr, aO[nt], 0, 0, 0);
    }
  #pragma unroll
  for (int r = 0; r < 4; r++) {
    float eli = sel[wid * 16 + quad * 4 + r];
    #pragma unroll
    for (int nt = 0; nt < 8; nt++) aO[nt][r] *= eli;
  }
  __syncthreads();   // B3

  {
    bf16x8 a2[2];
    #pragma unroll
    for (int ks2 = 0; ks2 < 2; ks2++)
      a2[ks2] = *(const bf16x8*)&sM[(wid * 16 + lane16) * 72 + ks2 * 32 + quad * 8];
    #pragma unroll
    for (int ks2 = 0; ks2 < 2; ks2++)
      #pragma unroll
      for (int nt = 0; nt < 8; nt++) {
        bf16x8 bfr = *(const bf16x8*)&sDt[(nt * 16 + lane16) * 72 + ks2 * 32 + quad * 8];
        aO[nt] = __builtin_amdgcn_mfma_f32_16x16x32_bf16(a2[ks2], bfr, aO[nt], 0, 0, 0);
      }
  }
  #pragma unroll
  for (int r = 0; r < 4; r++) {
    float ss = 0.f;
    #pragma unroll
    for (int nt = 0; nt < 8; nt++) ss += aO[nt][r] * aO[nt][r];
    ss += __shfl_xor(ss, 1, 64);
    ss += __shfl_xor(ss, 2, 64);
    ss += __shfl_xor(ss, 4, 64);
    ss += __shfl_xor(ss, 8, 64);
    float rinv = rsqrtf(ss * (1.f / 128.f) + 1e-6f);
    int i = wid * 16 + quad * 4 + r;
    size_t grow = (size_t)(row0 + i) * NPAD + h * 128;
    #pragma unroll
    for (int nt = 0; nt < 8; nt++) {
      int v = nt * 16 + lane16;
      float zv = b2f(zr[nt][r]);
      float zg = zv / (1.f + __expf(-zv));
      float y = snw[v] * (aO[nt][r] * rinv) * zg;
      g1out[grow + v] = f2b(y);
    }
  }
}

extern "C" void kernel_launch(void* const* d_in, const int* in_sizes, int n_in,
                              void* d_out, int out_size, void* d_ws, size_t ws_size,
                              hipStream_t stream)
{
  const float* hidden  = (const float*)d_in[0];
  const float* W_qkv   = (const float*)d_in[1];
  const float* W_z     = (const float*)d_in[2];
  const float* W_a     = (const float*)d_in[3];
  const float* W_b     = (const float*)d_in[4];
  const float* conv_w  = (const float*)d_in[5];
  const float* A_log   = (const float*)d_in[6];
  const float* dt_bias = (const float*)d_in[7];
  const float* norm_w  = (const float*)d_in[8];
  const float* W_out   = (const float*)d_in[9];

  char* ws = (char*)d_ws;
  unsigned short* hbf   = (unsigned short*)(ws);                 // [4096][2048] bf16
  unsigned short* Wcat  = (unsigned short*)(ws + 16777216ull);   // [12416][2048] bf16
  unsigned short* Woutb = (unsigned short*)(ws + 67633152ull);   // [2048][4096] bf16
  unsigned short* g1out = (unsigned short*)(ws + 84410368ull);   // [4096][12416] bf16
  unsigned short* qact  = (unsigned short*)(ws + 186122240ull);  // [4096][8192] bf16
  float* g_arr          = (float*)(ws + 253231104ull);           // [4096][32]
  float* beta           = (float*)(ws + 253755392ull);           // [4096][32]
  unsigned short* W_all = (unsigned short*)(ws);                 // aliases hbf (dead after GEMM1)
  unsigned short* U_all = (unsigned short*)(ws + 33554432ull);   // aliases Wcat tail

  float* out0 = (float*)d_out;          // (2,2048,2048) fp32
  float* out1 = out0 + 8388608;         // conv_state (2,8192,4)
  float* out2 = out0 + 8454144;         // state (2,32,128,128)

  cast_kernel<<<8192,  256, 0, stream>>>(hidden, hbf, 2097152);
  cast_kernel<<<16384, 256, 0, stream>>>(W_qkv, Wcat, 4194304);
  cast_kernel<<<8192,  256, 0, stream>>>(W_z,   Wcat + 8192ull  * 2048, 2097152);
  cast_kernel<<<64,    256, 0, stream>>>(W_a,   Wcat + 12288ull * 2048, 16384);
  cast_kernel<<<64,    256, 0, stream>>>(W_b,   Wcat + 12320ull * 2048, 16384);
  cast_kernel<<<8192,  256, 0, stream>>>(W_out, Woutb, 2097152);

  // GEMM1: 256^2 8-phase; 49 n-tiles (last clamped), 16 m-tiles; 784 % 8 == 0
  gemm1_256<<<784, 512, 0, stream>>>(hbf, Wcat, g1out, 2048, 2048, 2048,
                                     NPAD, NTOT, NPAD - 1, 49);
  gebeta_kernel<<<512, 256, 0, stream>>>(g1out, A_log, dt_bias, g_arr, beta);
  conv_kernel<<<dim3(4096, 8), 128, 0, stream>>>(g1out, conv_w, qact);
  convstate_kernel<<<256, 256, 0, stream>>>(g1out, out1);

  chunk_prep<<<2048, 256, 0, stream>>>(qact, g_arr, beta, W_all, U_all);
  state_scan<<<128, 512, 0, stream>>>(qact, g1out, g_arr, W_all, U_all, out2);
  chunk_out<<<2048, 256, 0, stream>>>(qact, g1out, g_arr, norm_w, W_all, U_all);

  gemm_bt<false><<<dim3(16, 32), 256, 0, stream>>>(g1out, Woutb, out0, 4096, NPAD, 4096, 2048, 2048);
}

// Round 3
// 856.235 us; speedup vs baseline: 1.2769x; 1.0009x over previous
//
#include <hip/hip_runtime.h>
#include <hip/hip_bf16.h>
#include <cstdint>

#define SEQ 2048
#define NPAD 12416      // 97*128, padded N for GEMM1 output rows
#define NTOT 12352      // qkv(8192) + z(4096) + a(32) + b(32)
#define CONV_INNER 8192

typedef __attribute__((ext_vector_type(8))) short bf16x8;
typedef __attribute__((ext_vector_type(4))) float f32x4;

__device__ __forceinline__ float b2f(unsigned short u) {
  union { unsigned int i; float f; } x; x.i = ((unsigned int)u) << 16; return x.f;
}
__device__ __forceinline__ unsigned short f2b(float f) {
  __hip_bfloat16 h = __float2bfloat16(f);
  return *reinterpret_cast<unsigned short*>(&h);
}
__device__ __forceinline__ void load_lds16(const short* g, short* l) {
  __builtin_amdgcn_global_load_lds(
      (__attribute__((address_space(1))) void*)(g),
      (__attribute__((address_space(3))) void*)(l), 16, 0, 0);
}

// S_all staging: state ENTERING chunk ch of (b,h), bf16 [128 v][128 k].
// Lives in dead workspace columns: qact cols 4096..8191 (v-region, dead after
// chunk_prep) for b=0 cids; g1out cols 4096..8191 (qkv_raw, dead after conv)
// for b=1 cids. One cid = 4 row-slots of 32 v-rows each.
__device__ __forceinline__ unsigned short* sall_ptr(
    unsigned short* qact, unsigned short* g1out, int cid, int vrow) {
  int slot = ((cid & 1023) << 2) + (vrow >> 5);
  if (cid < 1024) return qact + (size_t)slot * 8192 + 4096 + (vrow & 31) * 128;
  return g1out + (size_t)slot * (size_t)NPAD + 4096 + (vrow & 31) * 128;
}

// ---------------- fp32 -> bf16 cast ----------------
__global__ void cast_kernel(const float* __restrict__ in, unsigned short* __restrict__ out, int n4) {
  int i = blockIdx.x * blockDim.x + threadIdx.x;
  if (i >= n4) return;
  float4 v = ((const float4*)in)[i];
  ushort4 o;
  o.x = f2b(v.x); o.y = f2b(v.y); o.z = f2b(v.z); o.w = f2b(v.w);
  ((ushort4*)out)[i] = o;
}

// ---------------- bf16 MFMA GEMM (128^2, 2-barrier): C[m][n] = sum_k A[m][k]*B[n][k] ----
template<bool OUT_BF16>
__global__ __launch_bounds__(256) void gemm_bt(
    const unsigned short* __restrict__ A,   // [M][lda] bf16
    const unsigned short* __restrict__ Bm,  // [Nrows][ldb] bf16
    void* __restrict__ Cout, int K, int lda, int ldb, int ldc, int nmax)
{
  __shared__ __align__(16) short lA[2][128 * 32];
  __shared__ __align__(16) short lB[2][128 * 32];
  const int tid = threadIdx.x;
  const int lane = tid & 63, wid = tid >> 6;
  const int lane16 = lane & 15, quad = lane >> 4;
  const int wm = (wid & 1) * 64, wn = (wid >> 1) * 64;
  const int m0 = blockIdx.y * 128, n0 = blockIdx.x * 128;
  const int srow = wid * 16 + (lane >> 2);                  // staged tile row
  const int scol = (((lane & 3) ^ ((lane >> 3) & 3))) * 8;  // swizzled source chunk
  const int rchunk = (quad ^ ((lane16 >> 1) & 3)) * 8;      // swizzled fragment chunk

  f32x4 acc[4][4];
  #pragma unroll
  for (int i = 0; i < 4; i++)
    #pragma unroll
    for (int j = 0; j < 4; j++)
      acc[i][j] = f32x4{0.f, 0.f, 0.f, 0.f};

  const short* As = (const short*)A;
  const short* Bs = (const short*)Bm;
  short* lA0s[2] = { &lA[0][(wid * 16) * 32], &lA[1][(wid * 16) * 32] };
  short* lA1s[2] = { &lA[0][(64 + wid * 16) * 32], &lA[1][(64 + wid * 16) * 32] };
  short* lB0s[2] = { &lB[0][(wid * 16) * 32], &lB[1][(wid * 16) * 32] };
  short* lB1s[2] = { &lB[0][(64 + wid * 16) * 32], &lB[1][(64 + wid * 16) * 32] };
  const short* ga0 = As + (size_t)(m0 + srow) * lda + scol;
  const short* ga1 = As + (size_t)(m0 + 64 + srow) * lda + scol;
  const short* gb0 = Bs + (size_t)(n0 + srow) * ldb + scol;
  const short* gb1 = Bs + (size_t)(n0 + 64 + srow) * ldb + scol;

  for (int kb = 0; kb < K; kb += 64) {
    #pragma unroll
    for (int st = 0; st < 2; st++) {
      int ko = kb + st * 32;
      load_lds16(ga0 + ko, lA0s[st]);
      load_lds16(ga1 + ko, lA1s[st]);
      load_lds16(gb0 + ko, lB0s[st]);
      load_lds16(gb1 + ko, lB1s[st]);
    }
    __syncthreads();   // drains vmcnt -> both stages complete
    #pragma unroll
    for (int st = 0; st < 2; st++) {
      bf16x8 af[4], bfr[4];
      #pragma unroll
      for (int t = 0; t < 4; t++) af[t]  = *(const bf16x8*)&lA[st][(wm + t * 16 + lane16) * 32 + rchunk];
      #pragma unroll
      for (int t = 0; t < 4; t++) bfr[t] = *(const bf16x8*)&lB[st][(wn + t * 16 + lane16) * 32 + rchunk];
      #pragma unroll
      for (int i = 0; i < 4; i++)
        #pragma unroll
        for (int j = 0; j < 4; j++)
          acc[i][j] = __builtin_amdgcn_mfma_f32_16x16x32_bf16(af[i], bfr[j], acc[i][j], 0, 0, 0);
    }
    __syncthreads();   // all reads done before next overwrite
  }

  #pragma unroll
  for (int i = 0; i < 4; i++) {
    #pragma unroll
    for (int j = 0; j < 4; j++) {
      int n = n0 + wn + j * 16 + lane16;
      if (n >= nmax) continue;
      #pragma unroll
      for (int r = 0; r < 4; r++) {
        int m = m0 + wm + i * 16 + quad * 4 + r;
        float v = acc[i][j][r];
        if (OUT_BF16) ((unsigned short*)Cout)[(size_t)m * ldc + n] = f2b(v);
        else          ((float*)Cout)[(size_t)m * ldc + n] = v;
      }
    }
  }
}

// ======== 256x256 8-phase GEMM (T2+T3+T4+T5), bf16 out ========
// 512 threads = 8 waves (2M x 4N); BK=64 double-buffered; per-wave C = 128x64.
// LDS [buf][hk 2][row 256][32 shorts], staged as K-half units (2 loads each).
// Consumption is 6 phases after issue; gates: p1 vmcnt(8) [active iter0 only],
// p3 vmcnt(4) [vmcnt(0) on drain iter], p7 vmcnt(4).
__global__ __launch_bounds__(512, 2) void gemm1_256(
    const unsigned short* __restrict__ A,
    const unsigned short* __restrict__ Bm,
    unsigned short* __restrict__ Cout,
    int K, int lda, int ldb, int ldc, int nmax, int brmax, int tnc)
{
  __shared__ __align__(16) short lA[2][16384];
  __shared__ __align__(16) short lB[2][16384];
  const int tid = threadIdx.x;
  const int lane = tid & 63, wid = tid >> 6;
  const int lane16 = lane & 15, quad = lane >> 4;
  const int wm = (wid >> 2) * 128, wn = (wid & 3) * 64;
  const int cpx = gridDim.x >> 3;                 // grid % 8 == 0 (bijective)
  const int swz = ((int)blockIdx.x & 7) * cpx + ((int)blockIdx.x >> 3);
  const int tn = swz % tnc, tm = swz / tnc;
  const int m0 = tm * 256, n0 = tn * 256;
  const int srow = tid >> 2;                                // 0..127
  const int scol = ((tid & 3) ^ ((tid >> 3) & 3)) * 8;      // swizzled src chunk
  const int rchunk = (quad ^ ((lane16 >> 1) & 3)) * 8;      // swizzled read chunk
  const int NK = K >> 6;

  const short* As = (const short*)A;
  const short* Bs = (const short*)Bm;
  const size_t arow0 = (size_t)(m0 + srow) * lda;
  const size_t arow1 = (size_t)(m0 + 128 + srow) * lda;
  int br0i = n0 + srow;       if (br0i > brmax) br0i = brmax;
  int br1i = n0 + 128 + srow; if (br1i > brmax) br1i = brmax;
  const size_t brow0 = (size_t)br0i * ldb;
  const size_t brow1 = (size_t)br1i * ldb;
  short* dA[2] = { &lA[0][wid * 512], &lA[1][wid * 512] };
  short* dB[2] = { &lB[0][wid * 512], &lB[1][wid * 512] };

  f32x4 acc[8][4];
  #pragma unroll
  for (int i = 0; i < 8; i++)
    #pragma unroll
    for (int j = 0; j < 4; j++) acc[i][j] = f32x4{0.f, 0.f, 0.f, 0.f};

  auto stgA = [&](int buf, int hk, int kt) {
    int co = kt * 64 + hk * 32 + scol;
    load_lds16(As + arow0 + co, dA[buf] + hk * 8192);
    load_lds16(As + arow1 + co, dA[buf] + hk * 8192 + 4096);
  };
  auto stgB = [&](int buf, int hk, int kt) {
    int co = kt * 64 + hk * 32 + scol;
    load_lds16(Bs + brow0 + co, dB[buf] + hk * 8192);
    load_lds16(Bs + brow1 + co, dB[buf] + hk * 8192 + 4096);
  };

#define G1_BAR()   __builtin_amdgcn_s_barrier()
#define G1_LGKM0() { asm volatile("s_waitcnt lgkmcnt(0)" ::: "memory"); \
                     __builtin_amdgcn_sched_barrier(0); }
#define G1_VM8()   asm volatile("s_waitcnt vmcnt(8)" ::: "memory")
#define G1_VM4()   asm volatile("s_waitcnt vmcnt(4)" ::: "memory")
#define G1_VM0()   asm volatile("s_waitcnt vmcnt(0)" ::: "memory")
#define G1_MFMA4(mbase) \
  { __builtin_amdgcn_s_setprio(1); \
    _Pragma("unroll") \
    for (int mt = 0; mt < 4; mt++) \
      _Pragma("unroll") \
      for (int jt = 0; jt < 4; jt++) \
        acc[(mbase) + mt][jt] = __builtin_amdgcn_mfma_f32_16x16x32_bf16( \
            af[mt], bfr[jt], acc[(mbase) + mt][jt], 0, 0, 0); \
    __builtin_amdgcn_s_setprio(0); }

  // prologue: T0 (buf0) fully + T1.hk0 (buf1) = 6 units, 12 loads in order
  stgA(0, 0, 0); stgB(0, 0, 0); stgA(0, 1, 0); stgB(0, 1, 0);
  stgA(1, 0, 1); stgB(1, 0, 1);
  G1_VM8();          // first 4 loads (T0.hk0 A+B) landed
  G1_BAR();

  for (int it = 0; it < (NK >> 1); it++) {
    const int t0 = 2 * it, t1 = 2 * it + 1;
    const bool s2 = (t0 + 2) < NK;   // prefetch tile t0+2 -> buf0
    const bool s3 = (t1 + 2) < NK;   // prefetch tile t1+2 -> buf1
    bf16x8 af[4], bfr[4];

    // ---- p0: T0 ks0, m0-3 (+B ks0); stage T1.A.hk1 -> buf1 ----
    #pragma unroll
    for (int jt = 0; jt < 4; jt++)
      bfr[jt] = *(const bf16x8*)&lB[0][(wn + jt * 16 + lane16) * 32 + rchunk];
    #pragma unroll
    for (int mt = 0; mt < 4; mt++)
      af[mt] = *(const bf16x8*)&lA[0][(wm + mt * 16 + lane16) * 32 + rchunk];
    stgA(1, 1, t1);
    G1_BAR(); G1_LGKM0(); G1_MFMA4(0); G1_BAR();

    // ---- p1: T0 ks0, m4-7; stage T1.B.hk1 -> buf1; vmcnt(8) (iter0 guard) ----
    #pragma unroll
    for (int mt = 0; mt < 4; mt++)
      af[mt] = *(const bf16x8*)&lA[0][(wm + 64 + mt * 16 + lane16) * 32 + rchunk];
    stgB(1, 1, t1);
    G1_BAR(); G1_LGKM0(); G1_MFMA4(4); G1_VM8(); G1_BAR();

    // ---- p2: T0 ks1, m0-3 (+B ks1); stage T2.A.hk0 -> buf0 ----
    #pragma unroll
    for (int jt = 0; jt < 4; jt++)
      bfr[jt] = *(const bf16x8*)&lB[0][8192 + (wn + jt * 16 + lane16) * 32 + rchunk];
    #pragma unroll
    for (int mt = 0; mt < 4; mt++)
      af[mt] = *(const bf16x8*)&lA[0][8192 + (wm + mt * 16 + lane16) * 32 + rchunk];
    if (s2) stgA(0, 0, t0 + 2);
    G1_BAR(); G1_LGKM0(); G1_MFMA4(0); G1_BAR();

    // ---- p3: T0 ks1, m4-7; stage T2.B.hk0 -> buf0; vmcnt(4) ----
    #pragma unroll
    for (int mt = 0; mt < 4; mt++)
      af[mt] = *(const bf16x8*)&lA[0][8192 + (wm + 64 + mt * 16 + lane16) * 32 + rchunk];
    if (s2) stgB(0, 0, t0 + 2);
    G1_BAR(); G1_LGKM0(); G1_MFMA4(4);
    if (s2) { G1_VM4(); } else { G1_VM0(); }
    G1_BAR();

    // ---- p4: T1 ks0, m0-3 (+B ks0); stage T2.A.hk1 -> buf0 ----
    #pragma unroll
    for (int jt = 0; jt < 4; jt++)
      bfr[jt] = *(const bf16x8*)&lB[1][(wn + jt * 16 + lane16) * 32 + rchunk];
    #pragma unroll
    for (int mt = 0; mt < 4; mt++)
      af[mt] = *(const bf16x8*)&lA[1][(wm + mt * 16 + lane16) * 32 + rchunk];
    if (s2) stgA(0, 1, t0 + 2);
    G1_BAR(); G1_LGKM0(); G1_MFMA4(0); G1_BAR();

    // ---- p5: T1 ks0, m4-7; stage T2.B.hk1 -> buf0; (no gate) ----
    #pragma unroll
    for (int mt = 0; mt < 4; mt++)
      af[mt] = *(const bf16x8*)&lA[1][(wm + 64 + mt * 16 + lane16) * 32 + rchunk];
    if (s2) stgB(0, 1, t0 + 2);
    G1_BAR(); G1_LGKM0(); G1_MFMA4(4); G1_BAR();

    // ---- p6: T1 ks1, m0-3 (+B ks1); stage T3.A.hk0 -> buf1 ----
    #pragma unroll
    for (int jt = 0; jt < 4; jt++)
      bfr[jt] = *(const bf16x8*)&lB[1][8192 + (wn + jt * 16 + lane16) * 32 + rchunk];
    #pragma unroll
    for (int mt = 0; mt < 4; mt++)
      af[mt] = *(const bf16x8*)&lA[1][8192 + (wm + mt * 16 + lane16) * 32 + rchunk];
    if (s3) stgA(1, 0, t1 + 2);
    G1_BAR(); G1_LGKM0(); G1_MFMA4(0); G1_BAR();

    // ---- p7: T1 ks1, m4-7; stage T3.B.hk0 -> buf1; vmcnt(4) ----
    #pragma unroll
    for (int mt = 0; mt < 4; mt++)
      af[mt] = *(const bf16x8*)&lA[1][8192 + (wm + 64 + mt * 16 + lane16) * 32 + rchunk];
    if (s3) stgB(1, 0, t1 + 2);
    G1_BAR(); G1_LGKM0(); G1_MFMA4(4); G1_VM4(); G1_BAR();
  }

  #pragma unroll
  for (int mt = 0; mt < 8; mt++)
    #pragma unroll
    for (int jt = 0; jt < 4; jt++) {
      int n = n0 + wn + jt * 16 + lane16;
      if (n >= nmax) continue;
      #pragma unroll
      for (int r = 0; r < 4; r++) {
        int m = m0 + wm + mt * 16 + quad * 4 + r;
        Cout[(size_t)m * ldc + n] = f2b(acc[mt][jt][r]);
      }
    }
#undef G1_BAR
#undef G1_LGKM0
#undef G1_VM8
#undef G1_VM4
#undef G1_VM0
#undef G1_MFMA4
}

// ---------------- gates: g (log decay) and beta ----------------
__global__ void gebeta_kernel(const unsigned short* __restrict__ g1out,
                              const float* __restrict__ A_log, const float* __restrict__ dt_bias,
                              float* __restrict__ g_out, float* __restrict__ beta)
{
  int idx = blockIdx.x * blockDim.x + threadIdx.x;  // 131072 = 4096*32
  int r = idx >> 5, n = idx & 31;
  float a = b2f(g1out[(size_t)r * NPAD + 12288 + n]) + dt_bias[n];
  float sp = (a > 20.f) ? a : log1pf(expf(a));
  g_out[idx] = -expf(A_log[n]) * sp;
  float bv = b2f(g1out[(size_t)r * NPAD + 12320 + n]);
  beta[idx] = 1.f / (1.f + expf(-bv));
}

// ---------------- conv(4) + silu + l2norm(q,k), 8 ch/thread ----------------
__global__ __launch_bounds__(128) void conv_kernel(
    const unsigned short* __restrict__ g1out, const float* __restrict__ conv_w,
    unsigned short* __restrict__ qkv_act)
{
  const int row = blockIdx.x;            // b*SEQ + s
  const int hg  = blockIdx.y;            // 0..7 (1024 channels each)
  const int tid = threadIdx.x;           // 0..127
  const int c0 = hg * 1024 + tid * 8;
  const int s = row & (SEQ - 1);
  float4 w4[8];
  #pragma unroll
  for (int e = 0; e < 8; e++) w4[e] = *(const float4*)(conv_w + (size_t)(c0 + e) * 4);
  float acc[8] = {0.f,0.f,0.f,0.f,0.f,0.f,0.f,0.f};
  #pragma unroll
  for (int j = 0; j < 4; j++) {
    int sj = s - 3 + j;
    if (sj >= 0) {
      bf16x8 x = *(const bf16x8*)(g1out + (size_t)(row - 3 + j) * NPAD + c0);
      #pragma unroll
      for (int e = 0; e < 8; e++) {
        float wj = (j == 0) ? w4[e].x : (j == 1) ? w4[e].y : (j == 2) ? w4[e].z : w4[e].w;
        acc[e] += wj * b2f((unsigned short)x[e]);
      }
    }
  }
  float sv[8], ssq = 0.f;
  #pragma unroll
  for (int e = 0; e < 8; e++) {
    sv[e] = acc[e] / (1.f + __expf(-acc[e]));
    ssq += sv[e] * sv[e];
  }
  ssq += __shfl_xor(ssq, 1, 64);
  ssq += __shfl_xor(ssq, 2, 64);
  ssq += __shfl_xor(ssq, 4, 64);
  ssq += __shfl_xor(ssq, 8, 64);
  float scale = 1.f;
  if (hg < 4) {
    scale = rsqrtf(ssq + 1e-6f);
    if (hg < 2) scale *= 0.08838834764831845f;  // q: 1/sqrt(128)
  }
  bf16x8 o;
  #pragma unroll
  for (int e = 0; e < 8; e++) o[e] = (short)f2b(sv[e] * scale);
  *(bf16x8*)(qkv_act + (size_t)row * CONV_INNER + c0) = o;
}

// ---------------- conv_state output ----------------
__global__ void convstate_kernel(const unsigned short* __restrict__ g1out, float* __restrict__ out1)
{
  int idx = blockIdx.x * blockDim.x + threadIdx.x;
  int b = idx >> 15, rem = idx & 32767;
  int c = rem >> 2, j = rem & 3;
  out1[idx] = b2f(g1out[(size_t)(b * SEQ + SEQ - 4 + j) * NPAD + c]);
}

// ================= PASS 1: chunk-local W,U (UT transform) =================
__global__ __launch_bounds__(256, 2) void chunk_prep(
    const unsigned short* __restrict__ qact,
    const float* __restrict__ g_arr, const float* __restrict__ beta_arr,
    unsigned short* __restrict__ W_all, unsigned short* __restrict__ U_all)
{
  __shared__ __align__(16) char smem[73472];
  short* sKn = (short*)smem;                  // 64 x stride152; Vt (128x72) aliases
  short* sVt = (short*)smem;
  short* sKt = (short*)(smem + 19456);        // 128 x 72
  float* sA  = (float*)(smem + 37888);        // 64 x 68 fp32; Tb aliases
  short* sTb = (short*)(smem + 37888);        // 64 x 72 bf16
  float* sT  = (float*)(smem + 55296);        // 64 x 68 fp32
  float* sl  = (float*)(smem + 72704);
  float* sel = (float*)(smem + 72960);
  float* sbb = (float*)(smem + 73216);

  const int tid = threadIdx.x, lane = tid & 63, wid = tid >> 6;
  const int lane16 = lane & 15, quad = lane >> 4;
  const int cid = blockIdx.x;
  const int ch = cid & 31, h = (cid >> 5) & 31, b = cid >> 10;
  const int qh = h >> 1;
  const int row0 = b * SEQ + ch * 64;

  float gv = g_arr[(size_t)(row0 + lane) * 32 + h];
  float bb = beta_arr[(size_t)(row0 + lane) * 32 + h];
  float l = gv;
  #pragma unroll
  for (int off = 1; off < 64; off <<= 1) {
    float p = __shfl_up(l, off, 64);
    if (lane >= off) l += p;
  }
  float el = expf(l);
  if (wid == 0) { sl[lane] = l; sel[lane] = el; sbb[lane] = bb; }

  {
    int j = tid >> 2, kc = (tid & 3) * 32;
    const unsigned short* src = qact + (size_t)(row0 + j) * CONV_INNER + 2048 + qh * 128 + kc;
    #pragma unroll
    for (int u = 0; u < 4; u++) {
      bf16x8 r = *(const bf16x8*)(src + u * 8);
      *(bf16x8*)&sKn[j * 152 + kc + u * 8] = r;
    }
  }
  {
    const unsigned short* src = qact + (size_t)(row0 + lane) * CONV_INNER + 2048 + qh * 128 + wid * 32;
    float cj = bb * el;
    #pragma unroll
    for (int u = 0; u < 4; u++) {
      bf16x8 r = *(const bf16x8*)(src + u * 8);
      #pragma unroll
      for (int e = 0; e < 8; e++)
        sKt[(wid * 32 + u * 8 + e) * 72 + lane] = (short)f2b(b2f((unsigned short)r[e]) * cj);
    }
  }
  __syncthreads();

  {
    f32x4 accA[4];
    #pragma unroll
    for (int t = 0; t < 4; t++) accA[t] = f32x4{0.f, 0.f, 0.f, 0.f};
    #pragma unroll
    for (int ks = 0; ks < 4; ks++) {
      bf16x8 a = *(const bf16x8*)&sKn[(wid * 16 + lane16) * 152 + ks * 32 + quad * 8];
      #pragma unroll
      for (int jt = 0; jt < 4; jt++) {
        bf16x8 bfr = *(const bf16x8*)&sKn[(jt * 16 + lane16) * 152 + ks * 32 + quad * 8];
        accA[jt] = __builtin_amdgcn_mfma_f32_16x16x32_bf16(a, bfr, accA[jt], 0, 0, 0);
      }
    }
    #pragma unroll
    for (int jt = 0; jt < 4; jt++) {
      int j = jt * 16 + lane16;
      float lj = sl[j];
      #pragma unroll
      for (int r = 0; r < 4; r++) {
        int i = wid * 16 + quad * 4 + r;
        float v = (j < i) ? sbb[i] * expf(sl[i] - lj) * accA[jt][r] : 0.f;
        sA[i * 68 + j] = v;
      }
    }
  }
  __syncthreads();

  {
    const unsigned short* src = qact + (size_t)(row0 + lane) * CONV_INNER + 4096 + h * 128 + wid * 32;
    #pragma unroll
    for (int u = 0; u < 4; u++) {
      bf16x8 r = *(const bf16x8*)(src + u * 8);
      #pragma unroll
      for (int e = 0; e < 8; e++)
        sVt[(wid * 32 + u * 8 + e) * 72 + lane] = (short)f2b(b2f((unsigned short)r[e]) * bb);
    }
  }
  __syncthreads();

  if (wid == 0 && lane < 32) {
    int c = lane;
    float treg[32];
    treg[0] = (c == 0) ? 1.f : 0.f;
    #pragma unroll
    for (int i = 1; i < 32; i++) {
      float s = 0.f;
      #pragma unroll
      for (int j = 0; j < i; j++) s += sA[i * 68 + j] * treg[j];
      treg[i] = ((i == c) ? 1.f : 0.f) - s;
    }
    #pragma unroll
    for (int i = 0; i < 32; i++) sT[i * 68 + c] = treg[i];
  } else if (wid == 1 && lane < 32) {
    int c = lane;
    float treg[32];
    treg[0] = (c == 0) ? 1.f : 0.f;
    #pragma unroll
    for (int i = 1; i < 32; i++) {
      float s = 0.f;
      #pragma unroll
      for (int j = 0; j < i; j++) s += sA[(32 + i) * 68 + 32 + j] * treg[j];
      treg[i] = ((i == c) ? 1.f : 0.f) - s;
    }
    #pragma unroll
    for (int i = 0; i < 32; i++) sT[(32 + i) * 68 + 32 + c] = treg[i];
  } else if (wid == 2) {
    for (int e = lane; e < 1024; e += 64) sT[(e >> 5) * 68 + 32 + (e & 31)] = 0.f;
  }
  __syncthreads();

  {
    int i = tid & 31, c0 = (tid >> 5) * 4;
    float x[4] = {0.f, 0.f, 0.f, 0.f};
    #pragma unroll
    for (int j = 0; j < 32; j++) {
      float a = sA[(32 + i) * 68 + j];
      #pragma unroll
      for (int cc = 0; cc < 4; cc++) x[cc] += a * sT[j * 68 + c0 + cc];
    }
    #pragma unroll
    for (int cc = 0; cc < 4; cc++) sA[i * 68 + c0 + cc] = x[cc];
  }
  __syncthreads();
  {
    int i = tid & 31, c0 = (tid >> 5) * 4;
    float x[4] = {0.f, 0.f, 0.f, 0.f};
    #pragma unroll
    for (int j = 0; j < 32; j++) {
      float t2 = sT[(32 + i) * 68 + 32 + j];
      #pragma unroll
      for (int cc = 0; cc < 4; cc++) x[cc] += t2 * sA[j * 68 + c0 + cc];
    }
    #pragma unroll
    for (int cc = 0; cc < 4; cc++) sT[(32 + i) * 68 + c0 + cc] = -x[cc];
  }
  __syncthreads();
  #pragma unroll
  for (int ii = 0; ii < 16; ii++) {
    int e = tid + 256 * ii;
    int r = e >> 6, cc = e & 63;
    sTb[r * 72 + cc] = (short)f2b(sT[r * 68 + cc]);
  }
  __syncthreads();

  {
    f32x4 accW[8], accU[8];
    #pragma unroll
    for (int nt = 0; nt < 8; nt++) { accW[nt] = f32x4{0.f,0.f,0.f,0.f}; accU[nt] = f32x4{0.f,0.f,0.f,0.f}; }
    bf16x8 ta[2];
    #pragma unroll
    for (int ks = 0; ks < 2; ks++)
      ta[ks] = *(const bf16x8*)&sTb[(wid * 16 + lane16) * 72 + ks * 32 + quad * 8];
    #pragma unroll
    for (int nt = 0; nt < 8; nt++) {
      #pragma unroll
      for (int ks = 0; ks < 2; ks++) {
        bf16x8 bk = *(const bf16x8*)&sKt[(nt * 16 + lane16) * 72 + ks * 32 + quad * 8];
        accW[nt] = __builtin_amdgcn_mfma_f32_16x16x32_bf16(ta[ks], bk, accW[nt], 0, 0, 0);
        bf16x8 bv = *(const bf16x8*)&sVt[(nt * 16 + lane16) * 72 + ks * 32 + quad * 8];
        accU[nt] = __builtin_amdgcn_mfma_f32_16x16x32_bf16(ta[ks], bv, accU[nt], 0, 0, 0);
      }
    }
    unsigned short* Wg = W_all + (size_t)cid * 8192;
    unsigned short* Ug = U_all + (size_t)cid * 8192;
    #pragma unroll
    for (int nt = 0; nt < 8; nt++)
      #pragma unroll
      for (int r = 0; r < 4; r++) {
        int i = wid * 16 + quad * 4 + r, k = nt * 16 + lane16;
        Wg[i * 128 + k] = f2b(accW[nt][r]);
        Ug[i * 128 + k] = f2b(accU[nt][r]);
      }
  }
}

// ================= PASS 2a: sequential state recurrence only =================
__global__ __launch_bounds__(512) void state_scan(
    unsigned short* qact, unsigned short* g1out,
    const float* __restrict__ g_arr,
    const unsigned short* __restrict__ W_all, const unsigned short* __restrict__ U_all,
    float* __restrict__ state_out)
{
  __shared__ __align__(16) short sS[64 * 136];    // S half-tile [64v][128k] bf16
  __shared__ __align__(16) short sDt[64 * 72];    // Dt [64v][64t] bf16
  __shared__ __align__(16) short sK2[128 * 72];   // K2^T [128k'][64t] bf16
  const int tid = threadIdx.x, lane = tid & 63, w = tid >> 6;
  const int lane16 = lane & 15, quad = lane >> 4;
  const int bid = blockIdx.x;
  const int bh = bid >> 1, vs = bid & 1;
  const int h = bh & 31, b = bh >> 5, qh = h >> 1;
  const int V0 = vs * 64;
  const int tt = w >> 1, vhl = (w & 1) * 32;      // aD work split
  const int avt = w & 3, kt0 = (w >> 2) * 4;      // aS work split

  for (int e = tid; e < 64 * 136 / 2; e += 512) ((unsigned int*)sS)[e] = 0u;
  float Sreg[4][4];
  #pragma unroll
  for (int n = 0; n < 4; n++)
    #pragma unroll
    for (int r = 0; r < 4; r++) Sreg[n][r] = 0.f;

  // ---- prefetch chunk 0 ----
  float gvn;
  bf16x8 kn[2], wn[4];
  unsigned short un[8];
  {
    const int r0_ = b * SEQ, cid_ = bh << 5;
    gvn = g_arr[(size_t)(r0_ + lane) * 32 + h];
    const unsigned short* ks_ = qact + (size_t)(r0_ + lane) * 8192 + 2048 + qh * 128 + w * 16;
    kn[0] = *(const bf16x8*)ks_; kn[1] = *(const bf16x8*)(ks_ + 8);
    const unsigned short* ws_ = W_all + (size_t)cid_ * 8192 + (tt * 16 + lane16) * 128 + quad * 8;
    #pragma unroll
    for (int ks = 0; ks < 4; ks++) wn[ks] = *(const bf16x8*)(ws_ + ks * 32);
    const unsigned short* us_ = U_all + (size_t)cid_ * 8192 + (tt * 16 + quad * 4) * 128 + V0 + vhl + lane16;
    #pragma unroll
    for (int vt = 0; vt < 2; vt++)
      #pragma unroll
      for (int r = 0; r < 4; r++) un[vt * 4 + r] = us_[r * 128 + vt * 16];
  }

  for (int ch = 0; ch < 32; ch++) {
    const int cid = (bh << 5) + ch;
    float l = gvn;
    #pragma unroll
    for (int off = 1; off < 64; off <<= 1) {
      float p = __shfl_up(l, off, 64);
      if (lane >= off) l += p;
    }
    float lC = __shfl(l, 63, 64);
    float elC = expf(lC);
    float s2 = expf(lC - l);
    #pragma unroll
    for (int e = 0; e < 8; e++)
      sK2[(w * 16 + e) * 72 + lane] = (short)f2b(b2f((unsigned short)kn[0][e]) * s2);
    #pragma unroll
    for (int e = 0; e < 8; e++)
      sK2[(w * 16 + 8 + e) * 72 + lane] = (short)f2b(b2f((unsigned short)kn[1][e]) * s2);
    bf16x8 wc[4];
    #pragma unroll
    for (int ks = 0; ks < 4; ks++) wc[ks] = wn[ks];
    unsigned short uc[8];
    #pragma unroll
    for (int i = 0; i < 8; i++) uc[i] = un[i];

    if (ch < 31) {
      const int r0_ = b * SEQ + (ch + 1) * 64, cid_ = cid + 1;
      gvn = g_arr[(size_t)(r0_ + lane) * 32 + h];
      const unsigned short* ks_ = qact + (size_t)(r0_ + lane) * 8192 + 2048 + qh * 128 + w * 16;
      kn[0] = *(const bf16x8*)ks_; kn[1] = *(const bf16x8*)(ks_ + 8);
      const unsigned short* ws_ = W_all + (size_t)cid_ * 8192 + (tt * 16 + lane16) * 128 + quad * 8;
      #pragma unroll
      for (int ks = 0; ks < 4; ks++) wn[ks] = *(const bf16x8*)(ws_ + ks * 32);
      const unsigned short* us_ = U_all + (size_t)cid_ * 8192 + (tt * 16 + quad * 4) * 128 + V0 + vhl + lane16;
      #pragma unroll
      for (int vt = 0; vt < 2; vt++)
        #pragma unroll
        for (int r = 0; r < 4; r++) un[vt * 4 + r] = us_[r * 128 + vt * 16];
    }
    asm volatile("s_waitcnt lgkmcnt(0)" ::: "memory");
    __builtin_amdgcn_s_barrier();      // bar1: sS(entering) + sK2 ready

    // Dt = U - W.S^T  -> out[t][v]
    f32x4 aD[2];
    aD[0] = f32x4{0.f,0.f,0.f,0.f}; aD[1] = f32x4{0.f,0.f,0.f,0.f};
    #pragma unroll
    for (int ks = 0; ks < 4; ks++)
      #pragma unroll
      for (int vt = 0; vt < 2; vt++) {
        bf16x8 bfr = *(const bf16x8*)&sS[(vhl + vt * 16 + lane16) * 136 + ks * 32 + quad * 8];
        aD[vt] = __builtin_amdgcn_mfma_f32_16x16x32_bf16(wc[ks], bfr, aD[vt], 0, 0, 0);
      }
    #pragma unroll
    for (int vt = 0; vt < 2; vt++)
      #pragma unroll
      for (int r = 0; r < 4; r++)
        sDt[(vhl + vt * 16 + lane16) * 72 + tt * 16 + quad * 4 + r] =
            (short)f2b(b2f(uc[vt * 4 + r]) - aD[vt][r]);
    asm volatile("s_waitcnt lgkmcnt(0)" ::: "memory");
    __builtin_amdgcn_s_barrier();      // bar2: sDt ready

    // S <- elC*S + Dt.K2
    bf16x8 a2[2];
    #pragma unroll
    for (int ks2 = 0; ks2 < 2; ks2++)
      a2[ks2] = *(const bf16x8*)&sDt[(avt * 16 + lane16) * 72 + ks2 * 32 + quad * 8];
    f32x4 aS[4];
    #pragma unroll
    for (int n = 0; n < 4; n++) aS[n] = f32x4{0.f,0.f,0.f,0.f};
    #pragma unroll
    for (int n = 0; n < 4; n++)
      #pragma unroll
      for (int ks2 = 0; ks2 < 2; ks2++) {
        bf16x8 bfr = *(const bf16x8*)&sK2[((kt0 + n) * 16 + lane16) * 72 + ks2 * 32 + quad * 8];
        aS[n] = __builtin_amdgcn_mfma_f32_16x16x32_bf16(a2[ks2], bfr, aS[n], 0, 0, 0);
      }
    #pragma unroll
    for (int r = 0; r < 4; r++) {
      int vg = V0 + avt * 16 + quad * 4 + r;
      unsigned short* sp = nullptr;
      if (ch < 31) sp = sall_ptr(qact, g1out, cid + 1, vg);
      #pragma unroll
      for (int n = 0; n < 4; n++) {
        float v = elC * Sreg[n][r] + aS[n][r];
        Sreg[n][r] = v;
        unsigned short bv = f2b(v);
        sS[(avt * 16 + quad * 4 + r) * 136 + (kt0 + n) * 16 + lane16] = (short)bv;
        if (ch < 31) sp[(kt0 + n) * 16 + lane16] = bv;
      }
    }
    asm volatile("s_waitcnt lgkmcnt(0)" ::: "memory");
    __builtin_amdgcn_s_barrier();      // bar3: sS(new) written; sDt/sK2 reads done
  }

  float* so = state_out + (size_t)bh * 16384;
  #pragma unroll
  for (int r = 0; r < 4; r++)
    #pragma unroll
    for (int n = 0; n < 4; n++)
      so[(size_t)(V0 + avt * 16 + quad * 4 + r) * 128 + (kt0 + n) * 16 + lane16] = Sreg[n][r];
}

// ================= PASS 2b: per-chunk output (fully parallel) =================
__global__ __launch_bounds__(256) void chunk_out(
    unsigned short* qact, unsigned short* g1out,
    const float* __restrict__ g_arr, const float* __restrict__ norm_w,
    const unsigned short* __restrict__ W_all, const unsigned short* __restrict__ U_all)
{
  __shared__ __align__(16) short sS[128 * 136];   // 34816 B
  __shared__ __align__(16) short sKn[64 * 136];   // 17408 B ; sM aliases
  __shared__ __align__(16) short sDt[128 * 72];   // 18432 B
  __shared__ float sl[64];
  __shared__ float sel[64];
  __shared__ float snw[128];
  short* sM = sKn;
  const int tid = threadIdx.x, lane = tid & 63, wid = tid >> 6;
  const int lane16 = lane & 15, quad = lane >> 4;
  const int cid = blockIdx.x;
  const int ch = cid & 31, h = (cid >> 5) & 31, b = cid >> 10, qh = h >> 1;
  const int row0 = b * SEQ + ch * 64;

  float l = g_arr[(size_t)(row0 + lane) * 32 + h];
  #pragma unroll
  for (int off = 1; off < 64; off <<= 1) {
    float p = __shfl_up(l, off, 64);
    if (lane >= off) l += p;
  }
  if (wid == 0) { sl[lane] = l; sel[lane] = expf(l); }
  if (tid < 128) snw[tid] = norm_w[tid];

  {
    int j4 = tid >> 2, kc = (tid & 3) * 32;
    const unsigned short* sk = qact + (size_t)(row0 + j4) * 8192 + 2048 + qh * 128 + kc;
    #pragma unroll
    for (int u = 0; u < 4; u++)
      *(bf16x8*)&sKn[j4 * 136 + kc + u * 8] = *(const bf16x8*)(sk + u * 8);
  }
  if (ch == 0) {
    for (int e = tid; e < 128 * 136 / 2; e += 256) ((unsigned int*)sS)[e] = 0u;
  } else {
    int vr = tid >> 1, hf = (tid & 1) * 64;
    const unsigned short* sp = sall_ptr(qact, g1out, cid, vr) + hf;
    #pragma unroll
    for (int u = 0; u < 8; u++)
      *(bf16x8*)&sS[vr * 136 + hf + u * 8] = *(const bf16x8*)(sp + u * 8);
  }
  bf16x8 qf[4], wf[4];
  {
    const unsigned short* qsrc = qact + (size_t)(row0 + wid * 16 + lane16) * 8192 + qh * 128 + quad * 8;
    #pragma unroll
    for (int ks = 0; ks < 4; ks++) qf[ks] = *(const bf16x8*)(qsrc + ks * 32);
    const unsigned short* wsrc = W_all + (size_t)cid * 8192 + (wid * 16 + lane16) * 128 + quad * 8;
    #pragma unroll
    for (int ks = 0; ks < 4; ks++) wf[ks] = *(const bf16x8*)(wsrc + ks * 32);
  }
  unsigned short uvr[8][4], zr[8][4];
  {
    const unsigned short* usrc = U_all + (size_t)cid * 8192 + (wid * 16 + quad * 4) * 128 + lane16;
    const unsigned short* zsrc = g1out + (size_t)(row0 + wid * 16 + quad * 4) * NPAD + 8192 + h * 128 + lane16;
    #pragma unroll
    for (int nt = 0; nt < 8; nt++)
      #pragma unroll
      for (int r = 0; r < 4; r++) {
        uvr[nt][r] = usrc[r * 128 + nt * 16];
        zr[nt][r]  = zsrc[(size_t)r * NPAD + nt * 16];
      }
  }
  __syncthreads();   // B1

  {
    f32x4 aD[8];
    #pragma unroll
    for (int nt = 0; nt < 8; nt++) aD[nt] = f32x4{0.f,0.f,0.f,0.f};
    #pragma unroll
    for (int ks = 0; ks < 4; ks++)
      #pragma unroll
      for (int nt = 0; nt < 8; nt++) {
        bf16x8 bfr = *(const bf16x8*)&sS[(nt * 16 + lane16) * 136 + ks * 32 + quad * 8];
        aD[nt] = __builtin_amdgcn_mfma_f32_16x16x32_bf16(wf[ks], bfr, aD[nt], 0, 0, 0);
      }
    #pragma unroll
    for (int nt = 0; nt < 8; nt++)
      #pragma unroll
      for (int r = 0; r < 4; r++)
        sDt[(nt * 16 + lane16) * 72 + wid * 16 + quad * 4 + r] =
            (short)f2b(b2f(uvr[nt][r]) - aD[nt][r]);
  }
  f32x4 aM[4];
  #pragma unroll
  for (int jt = 0; jt < 4; jt++) aM[jt] = f32x4{0.f,0.f,0.f,0.f};
  #pragma unroll
  for (int ks = 0; ks < 4; ks++)
    #pragma unroll
    for (int jt = 0; jt < 4; jt++) {
      bf16x8 bfr = *(const bf16x8*)&sKn[(jt * 16 + lane16) * 136 + ks * 32 + quad * 8];
      aM[jt] = __builtin_amdgcn_mfma_f32_16x16x32_bf16(qf[ks], bfr, aM[jt], 0, 0, 0);
    }
  __syncthreads();   // B2

  #pragma unroll
  for (int jt = 0; jt < 4; jt++) {
    int j = jt * 16 + lane16;
    float lj = sl[j];
    #pragma unroll
    for (int r = 0; r < 4; r++) {
      int i = wid * 16 + quad * 4 + r;
      float m = (j <= i) ? expf(sl[i] - lj) * aM[jt][r] : 0.f;
      sM[i * 72 + j] = (short)f2b(m);
    }
  }
  f32x4 aO[8];
  #pragma unroll
  for (int nt = 0; nt < 8; nt++) aO[nt] = f32x4{0.f,0.f,0.f,0.f};
  #pragma unroll
  for (int ks = 0; ks < 4; ks++)
    #pragma unroll
    for (int nt = 0; nt < 8; nt++) {
      bf16x8 bfr = *(const bf16x8*)&sS[(nt * 16 + lane16) * 136 + ks * 32 + quad * 8];
      aO[nt] = __builtin_amdgcn_mfma_f32_16x16x32_bf16(qf[ks], bfr, aO[nt], 0, 0, 0);
    }
  #pragma unroll
  for (int r = 0; r < 4; r++) {
    float eli = sel[wid * 16 + quad * 4 + r];
    #pragma unroll
    for (int nt = 0; nt < 8; nt++) aO[nt][r] *= eli;
  }
  __syncthreads();   // B3

  {
    bf16x8 a2[2];
    #pragma unroll
    for (int ks2 = 0; ks2 < 2; ks2++)
      a2[ks2] = *(const bf16x8*)&sM[(wid * 16 + lane16) * 72 + ks2 * 32 + quad * 8];
    #pragma unroll
    for (int ks2 = 0; ks2 < 2; ks2++)
      #pragma unroll
      for (int nt = 0; nt < 8; nt++) {
        bf16x8 bfr = *(const bf16x8*)&sDt[(nt * 16 + lane16) * 72 + ks2 * 32 + quad * 8];
        aO[nt] = __builtin_amdgcn_mfma_f32_16x16x32_bf16(a2[ks2], bfr, aO[nt], 0, 0, 0);
      }
  }
  #pragma unroll
  for (int r = 0; r < 4; r++) {
    float ss = 0.f;
    #pragma unroll
    for (int nt = 0; nt < 8; nt++) ss += aO[nt][r] * aO[nt][r];
    ss += __shfl_xor(ss, 1, 64);
    ss += __shfl_xor(ss, 2, 64);
    ss += __shfl_xor(ss, 4, 64);
    ss += __shfl_xor(ss, 8, 64);
    float rinv = rsqrtf(ss * (1.f / 128.f) + 1e-6f);
    int i = wid * 16 + quad * 4 + r;
    size_t grow = (size_t)(row0 + i) * NPAD + h * 128;
    #pragma unroll
    for (int nt = 0; nt < 8; nt++) {
      int v = nt * 16 + lane16;
      float zv = b2f(zr[nt][r]);
      float zg = zv / (1.f + __expf(-zv));
      float y = snw[v] * (aO[nt][r] * rinv) * zg;
      g1out[grow + v] = f2b(y);
    }
  }
}

extern "C" void kernel_launch(void* const* d_in, const int* in_sizes, int n_in,
                              void* d_out, int out_size, void* d_ws, size_t ws_size,
                              hipStream_t stream)
{
  const float* hidden  = (const float*)d_in[0];
  const float* W_qkv   = (const float*)d_in[1];
  const float* W_z     = (const float*)d_in[2];
  const float* W_a     = (const float*)d_in[3];
  const float* W_b     = (const float*)d_in[4];
  const float* conv_w  = (const float*)d_in[5];
  const float* A_log   = (const float*)d_in[6];
  const float* dt_bias = (const float*)d_in[7];
  const float* norm_w  = (const float*)d_in[8];
  const float* W_out   = (const float*)d_in[9];

  char* ws = (char*)d_ws;
  unsigned short* hbf   = (unsigned short*)(ws);                 // [4096][2048] bf16
  unsigned short* Wcat  = (unsigned short*)(ws + 16777216ull);   // [12416][2048] bf16
  unsigned short* Woutb = (unsigned short*)(ws + 67633152ull);   // [2048][4096] bf16
  unsigned short* g1out = (unsigned short*)(ws + 84410368ull);   // [4096][12416] bf16
  unsigned short* qact  = (unsigned short*)(ws + 186122240ull);  // [4096][8192] bf16
  float* g_arr          = (float*)(ws + 253231104ull);           // [4096][32]
  float* beta           = (float*)(ws + 253755392ull);           // [4096][32]
  unsigned short* W_all = (unsigned short*)(ws);                 // aliases hbf (dead after GEMM1)
  unsigned short* U_all = (unsigned short*)(ws + 33554432ull);   // aliases Wcat tail

  float* out0 = (float*)d_out;          // (2,2048,2048) fp32
  float* out1 = out0 + 8388608;         // conv_state (2,8192,4)
  float* out2 = out0 + 8454144;         // state (2,32,128,128)

  cast_kernel<<<8192,  256, 0, stream>>>(hidden, hbf, 2097152);
  cast_kernel<<<16384, 256, 0, stream>>>(W_qkv, Wcat, 4194304);
  cast_kernel<<<8192,  256, 0, stream>>>(W_z,   Wcat + 8192ull  * 2048, 2097152);
  cast_kernel<<<64,    256, 0, stream>>>(W_a,   Wcat + 12288ull * 2048, 16384);
  cast_kernel<<<64,    256, 0, stream>>>(W_b,   Wcat + 12320ull * 2048, 16384);
  cast_kernel<<<8192,  256, 0, stream>>>(W_out, Woutb, 2097152);

  // a/b gate columns (M=4096, N=64, K=2048) -> g1out cols 12288..12351
  gemm_bt<true><<<dim3(1, 32), 256, 0, stream>>>(
      hbf, Wcat + 12288ull * 2048, g1out + 12288, 2048, 2048, 2048, NPAD, 64);
  // GEMM1: 256^2 8-phase over q,k,v,z; 48 n-tiles x 16 m-tiles = 768 = 3x256
  gemm1_256<<<768, 512, 0, stream>>>(hbf, Wcat, g1out, 2048, 2048, 2048,
                                     NPAD, 12288, NPAD - 1, 48);
  gebeta_kernel<<<512, 256, 0, stream>>>(g1out, A_log, dt_bias, g_arr, beta);
  conv_kernel<<<dim3(4096, 8), 128, 0, stream>>>(g1out, conv_w, qact);
  convstate_kernel<<<256, 256, 0, stream>>>(g1out, out1);

  chunk_prep<<<2048, 256, 0, stream>>>(qact, g_arr, beta, W_all, U_all);
  state_scan<<<128, 512, 0, stream>>>(qact, g1out, g_arr, W_all, U_all, out2);
  chunk_out<<<2048, 256, 0, stream>>>(qact, g1out, g_arr, norm_w, W_all, U_all);

  gemm_bt<false><<<dim3(16, 32), 256, 0, stream>>>(g1out, Woutb, out0, 4096, NPAD, 4096, 2048, 2048);
}

// Round 4
// 839.090 us; speedup vs baseline: 1.3030x; 1.0204x over previous
//
#include <hip/hip_runtime.h>
#include <hip/hip_bf16.h>
#include <cstdint>

#define SEQ 2048
#define NPAD 12416      // 97*128, padded N for GEMM1 output rows
#define NTOT 12352      // qkv(8192) + z(4096) + a(32) + b(32)
#define CONV_INNER 8192

typedef __attribute__((ext_vector_type(8))) short bf16x8;
typedef __attribute__((ext_vector_type(4))) float f32x4;

__device__ __forceinline__ float b2f(unsigned short u) {
  union { unsigned int i; float f; } x; x.i = ((unsigned int)u) << 16; return x.f;
}
__device__ __forceinline__ unsigned short f2b(float f) {
  __hip_bfloat16 h = __float2bfloat16(f);
  return *reinterpret_cast<unsigned short*>(&h);
}
__device__ __forceinline__ void load_lds16(const short* g, short* l) {
  __builtin_amdgcn_global_load_lds(
      (__attribute__((address_space(1))) void*)(g),
      (__attribute__((address_space(3))) void*)(l), 16, 0, 0);
}

// S_all staging: state ENTERING chunk ch of (b,h), bf16 [128 v][128 k].
// Lives in dead workspace columns: qact cols 4096..8191 (v-region, dead after
// chunk_prep) for b=0 cids; g1out cols 4096..8191 (qkv_raw, dead after conv)
// for b=1 cids. One cid = 4 row-slots of 32 v-rows each.
__device__ __forceinline__ unsigned short* sall_ptr(
    unsigned short* qact, unsigned short* g1out, int cid, int vrow) {
  int slot = ((cid & 1023) << 2) + (vrow >> 5);
  if (cid < 1024) return qact + (size_t)slot * 8192 + 4096 + (vrow & 31) * 128;
  return g1out + (size_t)slot * (size_t)NPAD + 4096 + (vrow & 31) * 128;
}

// ---------------- fp32 -> bf16 cast ----------------
__global__ void cast_kernel(const float* __restrict__ in, unsigned short* __restrict__ out, int n4) {
  int i = blockIdx.x * blockDim.x + threadIdx.x;
  if (i >= n4) return;
  float4 v = ((const float4*)in)[i];
  ushort4 o;
  o.x = f2b(v.x); o.y = f2b(v.y); o.z = f2b(v.z); o.w = f2b(v.w);
  ((ushort4*)out)[i] = o;
}

// ---------------- bf16 MFMA GEMM (128^2, 2-barrier): C[m][n] = sum_k A[m][k]*B[n][k] ----
template<bool OUT_BF16>
__global__ __launch_bounds__(256) void gemm_bt(
    const unsigned short* __restrict__ A,   // [M][lda] bf16
    const unsigned short* __restrict__ Bm,  // [Nrows][ldb] bf16
    void* __restrict__ Cout, int K, int lda, int ldb, int ldc, int nmax)
{
  __shared__ __align__(16) short lA[2][128 * 32];
  __shared__ __align__(16) short lB[2][128 * 32];
  const int tid = threadIdx.x;
  const int lane = tid & 63, wid = tid >> 6;
  const int lane16 = lane & 15, quad = lane >> 4;
  const int wm = (wid & 1) * 64, wn = (wid >> 1) * 64;
  const int m0 = blockIdx.y * 128, n0 = blockIdx.x * 128;
  const int srow = wid * 16 + (lane >> 2);                  // staged tile row
  const int scol = (((lane & 3) ^ ((lane >> 3) & 3))) * 8;  // swizzled source chunk
  const int rchunk = (quad ^ ((lane16 >> 1) & 3)) * 8;      // swizzled fragment chunk

  f32x4 acc[4][4];
  #pragma unroll
  for (int i = 0; i < 4; i++)
    #pragma unroll
    for (int j = 0; j < 4; j++)
      acc[i][j] = f32x4{0.f, 0.f, 0.f, 0.f};

  const short* As = (const short*)A;
  const short* Bs = (const short*)Bm;
  short* lA0s[2] = { &lA[0][(wid * 16) * 32], &lA[1][(wid * 16) * 32] };
  short* lA1s[2] = { &lA[0][(64 + wid * 16) * 32], &lA[1][(64 + wid * 16) * 32] };
  short* lB0s[2] = { &lB[0][(wid * 16) * 32], &lB[1][(wid * 16) * 32] };
  short* lB1s[2] = { &lB[0][(64 + wid * 16) * 32], &lB[1][(64 + wid * 16) * 32] };
  const short* ga0 = As + (size_t)(m0 + srow) * lda + scol;
  const short* ga1 = As + (size_t)(m0 + 64 + srow) * lda + scol;
  const short* gb0 = Bs + (size_t)(n0 + srow) * ldb + scol;
  const short* gb1 = Bs + (size_t)(n0 + 64 + srow) * ldb + scol;

  for (int kb = 0; kb < K; kb += 64) {
    #pragma unroll
    for (int st = 0; st < 2; st++) {
      int ko = kb + st * 32;
      load_lds16(ga0 + ko, lA0s[st]);
      load_lds16(ga1 + ko, lA1s[st]);
      load_lds16(gb0 + ko, lB0s[st]);
      load_lds16(gb1 + ko, lB1s[st]);
    }
    __syncthreads();   // drains vmcnt -> both stages complete
    #pragma unroll
    for (int st = 0; st < 2; st++) {
      bf16x8 af[4], bfr[4];
      #pragma unroll
      for (int t = 0; t < 4; t++) af[t]  = *(const bf16x8*)&lA[st][(wm + t * 16 + lane16) * 32 + rchunk];
      #pragma unroll
      for (int t = 0; t < 4; t++) bfr[t] = *(const bf16x8*)&lB[st][(wn + t * 16 + lane16) * 32 + rchunk];
      #pragma unroll
      for (int i = 0; i < 4; i++)
        #pragma unroll
        for (int j = 0; j < 4; j++)
          acc[i][j] = __builtin_amdgcn_mfma_f32_16x16x32_bf16(af[i], bfr[j], acc[i][j], 0, 0, 0);
    }
    __syncthreads();   // all reads done before next overwrite
  }

  #pragma unroll
  for (int i = 0; i < 4; i++) {
    #pragma unroll
    for (int j = 0; j < 4; j++) {
      int n = n0 + wn + j * 16 + lane16;
      if (n >= nmax) continue;
      #pragma unroll
      for (int r = 0; r < 4; r++) {
        int m = m0 + wm + i * 16 + quad * 4 + r;
        float v = acc[i][j][r];
        if (OUT_BF16) ((unsigned short*)Cout)[(size_t)m * ldc + n] = f2b(v);
        else          ((float*)Cout)[(size_t)m * ldc + n] = v;
      }
    }
  }
}

// ---------- split-K a/b gate GEMM: P[ks][m][64] = A[m][k0:k0+256] . Bab[n][k0:k0+256]^T ----------
// 256 blocks = 8 K-segments x 32 m-tiles; full-chip; fp32 partials.
__global__ __launch_bounds__(256) void gemm_ab(
    const unsigned short* __restrict__ A,     // hbf [4096][2048]
    const unsigned short* __restrict__ Bm,    // Wcat rows 12288.. (64 rows: a then b)
    float* __restrict__ Pout)                 // [8][4096][64] fp32
{
  __shared__ __align__(16) short lA[2][128 * 32];
  __shared__ __align__(16) short lB[2][128 * 32];
  const int tid = threadIdx.x;
  const int lane = tid & 63, wid = tid >> 6;
  const int lane16 = lane & 15, quad = lane >> 4;
  const int wm = (wid & 1) * 64, wn = (wid >> 1) * 64;
  const int m0 = blockIdx.y * 128;
  const int k0 = blockIdx.x * 256;
  const int srow = wid * 16 + (lane >> 2);
  const int scol = (((lane & 3) ^ ((lane >> 3) & 3))) * 8;
  const int rchunk = (quad ^ ((lane16 >> 1) & 3)) * 8;

  f32x4 acc[4][4];
  #pragma unroll
  for (int i = 0; i < 4; i++)
    #pragma unroll
    for (int j = 0; j < 4; j++)
      acc[i][j] = f32x4{0.f, 0.f, 0.f, 0.f};

  const short* As = (const short*)A;
  const short* Bs = (const short*)Bm;
  short* lA0s[2] = { &lA[0][(wid * 16) * 32], &lA[1][(wid * 16) * 32] };
  short* lA1s[2] = { &lA[0][(64 + wid * 16) * 32], &lA[1][(64 + wid * 16) * 32] };
  short* lB0s[2] = { &lB[0][(wid * 16) * 32], &lB[1][(wid * 16) * 32] };
  short* lB1s[2] = { &lB[0][(64 + wid * 16) * 32], &lB[1][(64 + wid * 16) * 32] };
  const short* ga0 = As + (size_t)(m0 + srow) * 2048 + k0 + scol;
  const short* ga1 = As + (size_t)(m0 + 64 + srow) * 2048 + k0 + scol;
  int br0 = srow > 63 ? 63 : srow;                 // only 64 B rows exist
  const short* gb0 = Bs + (size_t)br0 * 2048 + k0 + scol;
  const short* gb1 = Bs + (size_t)63  * 2048 + k0 + scol;   // rows 64.. all clamp

  for (int kb = 0; kb < 256; kb += 64) {
    #pragma unroll
    for (int st = 0; st < 2; st++) {
      int ko = kb + st * 32;
      load_lds16(ga0 + ko, lA0s[st]);
      load_lds16(ga1 + ko, lA1s[st]);
      load_lds16(gb0 + ko, lB0s[st]);
      load_lds16(gb1 + ko, lB1s[st]);
    }
    __syncthreads();
    #pragma unroll
    for (int st = 0; st < 2; st++) {
      bf16x8 af[4], bfr[4];
      #pragma unroll
      for (int t = 0; t < 4; t++) af[t]  = *(const bf16x8*)&lA[st][(wm + t * 16 + lane16) * 32 + rchunk];
      #pragma unroll
      for (int t = 0; t < 4; t++) bfr[t] = *(const bf16x8*)&lB[st][(wn + t * 16 + lane16) * 32 + rchunk];
      #pragma unroll
      for (int i = 0; i < 4; i++)
        #pragma unroll
        for (int j = 0; j < 4; j++)
          acc[i][j] = __builtin_amdgcn_mfma_f32_16x16x32_bf16(af[i], bfr[j], acc[i][j], 0, 0, 0);
    }
    __syncthreads();
  }

  #pragma unroll
  for (int i = 0; i < 4; i++) {
    #pragma unroll
    for (int j = 0; j < 4; j++) {
      int n = wn + j * 16 + lane16;
      if (n >= 64) continue;
      #pragma unroll
      for (int r = 0; r < 4; r++) {
        int m = m0 + wm + i * 16 + quad * 4 + r;
        Pout[((size_t)blockIdx.x * 4096 + m) * 64 + n] = acc[i][j][r];
      }
    }
  }
}

// ======== 256x256 8-phase GEMM (T2+T3+T4+T5), bf16 out ========
// 512 threads = 8 waves (2M x 4N); BK=64 double-buffered; per-wave C = 128x64.
// LDS [buf][hk 2][row 256][32 shorts], staged as K-half units (2 loads each).
// Gates: p1 vmcnt(8) [active iter0 only], p3 vmcnt(4) [vmcnt(0) on drain], p7 vmcnt(4).
// Tile map is m-fastest (column-major): each XCD's resident blocks share 2 B-panels
// (L2-resident) and stream A, instead of every XCD streaming the whole 48MB B.
__global__ __launch_bounds__(512, 2) void gemm1_256(
    const unsigned short* __restrict__ A,
    const unsigned short* __restrict__ Bm,
    unsigned short* __restrict__ Cout,
    int K, int lda, int ldb, int ldc, int nmax, int brmax, int tmc)
{
  __shared__ __align__(16) short lA[2][16384];
  __shared__ __align__(16) short lB[2][16384];
  const int tid = threadIdx.x;
  const int lane = tid & 63, wid = tid >> 6;
  const int lane16 = lane & 15, quad = lane >> 4;
  const int wm = (wid >> 2) * 128, wn = (wid & 3) * 64;
  const int cpx = gridDim.x >> 3;                 // grid % 8 == 0 (bijective)
  const int swz = ((int)blockIdx.x & 7) * cpx + ((int)blockIdx.x >> 3);
  const int tm = swz % tmc, tn = swz / tmc;       // m-fastest
  const int m0 = tm * 256, n0 = tn * 256;
  const int srow = tid >> 2;                                // 0..127
  const int scol = ((tid & 3) ^ ((tid >> 3) & 3)) * 8;      // swizzled src chunk
  const int rchunk = (quad ^ ((lane16 >> 1) & 3)) * 8;      // swizzled read chunk
  const int NK = K >> 6;

  const short* As = (const short*)A;
  const short* Bs = (const short*)Bm;
  const size_t arow0 = (size_t)(m0 + srow) * lda;
  const size_t arow1 = (size_t)(m0 + 128 + srow) * lda;
  int br0i = n0 + srow;       if (br0i > brmax) br0i = brmax;
  int br1i = n0 + 128 + srow; if (br1i > brmax) br1i = brmax;
  const size_t brow0 = (size_t)br0i * ldb;
  const size_t brow1 = (size_t)br1i * ldb;
  short* dA[2] = { &lA[0][wid * 512], &lA[1][wid * 512] };
  short* dB[2] = { &lB[0][wid * 512], &lB[1][wid * 512] };

  f32x4 acc[8][4];
  #pragma unroll
  for (int i = 0; i < 8; i++)
    #pragma unroll
    for (int j = 0; j < 4; j++) acc[i][j] = f32x4{0.f, 0.f, 0.f, 0.f};

  auto stgA = [&](int buf, int hk, int kt) {
    int co = kt * 64 + hk * 32 + scol;
    load_lds16(As + arow0 + co, dA[buf] + hk * 8192);
    load_lds16(As + arow1 + co, dA[buf] + hk * 8192 + 4096);
  };
  auto stgB = [&](int buf, int hk, int kt) {
    int co = kt * 64 + hk * 32 + scol;
    load_lds16(Bs + brow0 + co, dB[buf] + hk * 8192);
    load_lds16(Bs + brow1 + co, dB[buf] + hk * 8192 + 4096);
  };

#define G1_BAR()   __builtin_amdgcn_s_barrier()
#define G1_LGKM0() { asm volatile("s_waitcnt lgkmcnt(0)" ::: "memory"); \
                     __builtin_amdgcn_sched_barrier(0); }
#define G1_VM8()   asm volatile("s_waitcnt vmcnt(8)" ::: "memory")
#define G1_VM4()   asm volatile("s_waitcnt vmcnt(4)" ::: "memory")
#define G1_VM0()   asm volatile("s_waitcnt vmcnt(0)" ::: "memory")
#define G1_MFMA4(mbase) \
  { __builtin_amdgcn_s_setprio(1); \
    _Pragma("unroll") \
    for (int mt = 0; mt < 4; mt++) \
      _Pragma("unroll") \
      for (int jt = 0; jt < 4; jt++) \
        acc[(mbase) + mt][jt] = __builtin_amdgcn_mfma_f32_16x16x32_bf16( \
            af[mt], bfr[jt], acc[(mbase) + mt][jt], 0, 0, 0); \
    __builtin_amdgcn_s_setprio(0); }

  // prologue: T0 (buf0) fully + T1.hk0 (buf1) = 6 units, 12 loads in order
  stgA(0, 0, 0); stgB(0, 0, 0); stgA(0, 1, 0); stgB(0, 1, 0);
  stgA(1, 0, 1); stgB(1, 0, 1);
  G1_VM8();          // first 4 loads (T0.hk0 A+B) landed
  G1_BAR();

  for (int it = 0; it < (NK >> 1); it++) {
    const int t0 = 2 * it, t1 = 2 * it + 1;
    const bool s2 = (t0 + 2) < NK;   // prefetch tile t0+2 -> buf0
    const bool s3 = (t1 + 2) < NK;   // prefetch tile t1+2 -> buf1
    bf16x8 af[4], bfr[4];

    // ---- p0: T0 ks0, m0-3 (+B ks0); stage T1.A.hk1 -> buf1 ----
    #pragma unroll
    for (int jt = 0; jt < 4; jt++)
      bfr[jt] = *(const bf16x8*)&lB[0][(wn + jt * 16 + lane16) * 32 + rchunk];
    #pragma unroll
    for (int mt = 0; mt < 4; mt++)
      af[mt] = *(const bf16x8*)&lA[0][(wm + mt * 16 + lane16) * 32 + rchunk];
    stgA(1, 1, t1);
    G1_BAR(); G1_LGKM0(); G1_MFMA4(0); G1_BAR();

    // ---- p1: T0 ks0, m4-7; stage T1.B.hk1 -> buf1; vmcnt(8) (iter0 guard) ----
    #pragma unroll
    for (int mt = 0; mt < 4; mt++)
      af[mt] = *(const bf16x8*)&lA[0][(wm + 64 + mt * 16 + lane16) * 32 + rchunk];
    stgB(1, 1, t1);
    G1_BAR(); G1_LGKM0(); G1_MFMA4(4); G1_VM8(); G1_BAR();

    // ---- p2: T0 ks1, m0-3 (+B ks1); stage T2.A.hk0 -> buf0 ----
    #pragma unroll
    for (int jt = 0; jt < 4; jt++)
      bfr[jt] = *(const bf16x8*)&lB[0][8192 + (wn + jt * 16 + lane16) * 32 + rchunk];
    #pragma unroll
    for (int mt = 0; mt < 4; mt++)
      af[mt] = *(const bf16x8*)&lA[0][8192 + (wm + mt * 16 + lane16) * 32 + rchunk];
    if (s2) stgA(0, 0, t0 + 2);
    G1_BAR(); G1_LGKM0(); G1_MFMA4(0); G1_BAR();

    // ---- p3: T0 ks1, m4-7; stage T2.B.hk0 -> buf0; vmcnt(4) ----
    #pragma unroll
    for (int mt = 0; mt < 4; mt++)
      af[mt] = *(const bf16x8*)&lA[0][8192 + (wm + 64 + mt * 16 + lane16) * 32 + rchunk];
    if (s2) stgB(0, 0, t0 + 2);
    G1_BAR(); G1_LGKM0(); G1_MFMA4(4);
    if (s2) { G1_VM4(); } else { G1_VM0(); }
    G1_BAR();

    // ---- p4: T1 ks0, m0-3 (+B ks0); stage T2.A.hk1 -> buf0 ----
    #pragma unroll
    for (int jt = 0; jt < 4; jt++)
      bfr[jt] = *(const bf16x8*)&lB[1][(wn + jt * 16 + lane16) * 32 + rchunk];
    #pragma unroll
    for (int mt = 0; mt < 4; mt++)
      af[mt] = *(const bf16x8*)&lA[1][(wm + mt * 16 + lane16) * 32 + rchunk];
    if (s2) stgA(0, 1, t0 + 2);
    G1_BAR(); G1_LGKM0(); G1_MFMA4(0); G1_BAR();

    // ---- p5: T1 ks0, m4-7; stage T2.B.hk1 -> buf0; (no gate) ----
    #pragma unroll
    for (int mt = 0; mt < 4; mt++)
      af[mt] = *(const bf16x8*)&lA[1][(wm + 64 + mt * 16 + lane16) * 32 + rchunk];
    if (s2) stgB(0, 1, t0 + 2);
    G1_BAR(); G1_LGKM0(); G1_MFMA4(4); G1_BAR();

    // ---- p6: T1 ks1, m0-3 (+B ks1); stage T3.A.hk0 -> buf1 ----
    #pragma unroll
    for (int jt = 0; jt < 4; jt++)
      bfr[jt] = *(const bf16x8*)&lB[1][8192 + (wn + jt * 16 + lane16) * 32 + rchunk];
    #pragma unroll
    for (int mt = 0; mt < 4; mt++)
      af[mt] = *(const bf16x8*)&lA[1][8192 + (wm + mt * 16 + lane16) * 32 + rchunk];
    if (s3) stgA(1, 0, t1 + 2);
    G1_BAR(); G1_LGKM0(); G1_MFMA4(0); G1_BAR();

    // ---- p7: T1 ks1, m4-7; stage T3.B.hk0 -> buf1; vmcnt(4) ----
    #pragma unroll
    for (int mt = 0; mt < 4; mt++)
      af[mt] = *(const bf16x8*)&lA[1][8192 + (wm + 64 + mt * 16 + lane16) * 32 + rchunk];
    if (s3) stgB(1, 0, t1 + 2);
    G1_BAR(); G1_LGKM0(); G1_MFMA4(4); G1_VM4(); G1_BAR();
  }

  #pragma unroll
  for (int mt = 0; mt < 8; mt++)
    #pragma unroll
    for (int jt = 0; jt < 4; jt++) {
      int n = n0 + wn + jt * 16 + lane16;
      if (n >= nmax) continue;
      #pragma unroll
      for (int r = 0; r < 4; r++) {
        int m = m0 + wm + mt * 16 + quad * 4 + r;
        Cout[(size_t)m * ldc + n] = f2b(acc[mt][jt][r]);
      }
    }
#undef G1_BAR
#undef G1_LGKM0
#undef G1_VM8
#undef G1_VM4
#undef G1_VM0
#undef G1_MFMA4
}

// ---------------- gates: g (log decay) and beta, from split-K fp32 partials ----------------
__global__ void gebeta_kernel(const float* __restrict__ P,   // [8][4096][64]
                              const float* __restrict__ A_log, const float* __restrict__ dt_bias,
                              float* __restrict__ g_out, float* __restrict__ beta)
{
  int idx = blockIdx.x * blockDim.x + threadIdx.x;  // 131072 = 4096*32
  int r = idx >> 5, n = idx & 31;
  float av = 0.f, bvv = 0.f;
  #pragma unroll
  for (int ks = 0; ks < 8; ks++) {
    const float* p = P + ((size_t)ks * 4096 + r) * 64;
    av  += p[n];
    bvv += p[32 + n];
  }
  float a = av + dt_bias[n];
  float sp = (a > 20.f) ? a : log1pf(expf(a));
  g_out[idx] = -expf(A_log[n]) * sp;
  beta[idx] = 1.f / (1.f + expf(-bvv));
}

// ---------------- conv(4) + silu + l2norm(q,k), 8 ch/thread ----------------
__global__ __launch_bounds__(128) void conv_kernel(
    const unsigned short* __restrict__ g1out, const float* __restrict__ conv_w,
    unsigned short* __restrict__ qkv_act)
{
  const int row = blockIdx.x;            // b*SEQ + s
  const int hg  = blockIdx.y;            // 0..7 (1024 channels each)
  const int tid = threadIdx.x;           // 0..127
  const int c0 = hg * 1024 + tid * 8;
  const int s = row & (SEQ - 1);
  float4 w4[8];
  #pragma unroll
  for (int e = 0; e < 8; e++) w4[e] = *(const float4*)(conv_w + (size_t)(c0 + e) * 4);
  float acc[8] = {0.f,0.f,0.f,0.f,0.f,0.f,0.f,0.f};
  #pragma unroll
  for (int j = 0; j < 4; j++) {
    int sj = s - 3 + j;
    if (sj >= 0) {
      bf16x8 x = *(const bf16x8*)(g1out + (size_t)(row - 3 + j) * NPAD + c0);
      #pragma unroll
      for (int e = 0; e < 8; e++) {
        float wj = (j == 0) ? w4[e].x : (j == 1) ? w4[e].y : (j == 2) ? w4[e].z : w4[e].w;
        acc[e] += wj * b2f((unsigned short)x[e]);
      }
    }
  }
  float sv[8], ssq = 0.f;
  #pragma unroll
  for (int e = 0; e < 8; e++) {
    sv[e] = acc[e] / (1.f + __expf(-acc[e]));
    ssq += sv[e] * sv[e];
  }
  ssq += __shfl_xor(ssq, 1, 64);
  ssq += __shfl_xor(ssq, 2, 64);
  ssq += __shfl_xor(ssq, 4, 64);
  ssq += __shfl_xor(ssq, 8, 64);
  float scale = 1.f;
  if (hg < 4) {
    scale = rsqrtf(ssq + 1e-6f);
    if (hg < 2) scale *= 0.08838834764831845f;  // q: 1/sqrt(128)
  }
  bf16x8 o;
  #pragma unroll
  for (int e = 0; e < 8; e++) o[e] = (short)f2b(sv[e] * scale);
  *(bf16x8*)(qkv_act + (size_t)row * CONV_INNER + c0) = o;
}

// ---------------- conv_state output ----------------
__global__ void convstate_kernel(const unsigned short* __restrict__ g1out, float* __restrict__ out1)
{
  int idx = blockIdx.x * blockDim.x + threadIdx.x;
  int b = idx >> 15, rem = idx & 32767;
  int c = rem >> 2, j = rem & 3;
  out1[idx] = b2f(g1out[(size_t)(b * SEQ + SEQ - 4 + j) * NPAD + c]);
}

// ================= PASS 1: chunk-local W,U (UT transform) =================
__global__ __launch_bounds__(256, 2) void chunk_prep(
    const unsigned short* __restrict__ qact,
    const float* __restrict__ g_arr, const float* __restrict__ beta_arr,
    unsigned short* __restrict__ W_all, unsigned short* __restrict__ U_all)
{
  __shared__ __align__(16) char smem[73472];
  short* sKn = (short*)smem;                  // 64 x stride152; Vt (128x72) aliases
  short* sVt = (short*)smem;
  short* sKt = (short*)(smem + 19456);        // 128 x 72
  float* sA  = (float*)(smem + 37888);        // 64 x 68 fp32; Tb aliases
  short* sTb = (short*)(smem + 37888);        // 64 x 72 bf16
  float* sT  = (float*)(smem + 55296);        // 64 x 68 fp32
  float* sl  = (float*)(smem + 72704);
  float* sel = (float*)(smem + 72960);
  float* sbb = (float*)(smem + 73216);

  const int tid = threadIdx.x, lane = tid & 63, wid = tid >> 6;
  const int lane16 = lane & 15, quad = lane >> 4;
  const int cid = blockIdx.x;
  const int ch = cid & 31, h = (cid >> 5) & 31, b = cid >> 10;
  const int qh = h >> 1;
  const int row0 = b * SEQ + ch * 64;

  float gv = g_arr[(size_t)(row0 + lane) * 32 + h];
  float bb = beta_arr[(size_t)(row0 + lane) * 32 + h];
  float l = gv;
  #pragma unroll
  for (int off = 1; off < 64; off <<= 1) {
    float p = __shfl_up(l, off, 64);
    if (lane >= off) l += p;
  }
  float el = expf(l);
  if (wid == 0) { sl[lane] = l; sel[lane] = el; sbb[lane] = bb; }

  {
    int j = tid >> 2, kc = (tid & 3) * 32;
    const unsigned short* src = qact + (size_t)(row0 + j) * CONV_INNER + 2048 + qh * 128 + kc;
    #pragma unroll
    for (int u = 0; u < 4; u++) {
      bf16x8 r = *(const bf16x8*)(src + u * 8);
      *(bf16x8*)&sKn[j * 152 + kc + u * 8] = r;
    }
  }
  {
    const unsigned short* src = qact + (size_t)(row0 + lane) * CONV_INNER + 2048 + qh * 128 + wid * 32;
    float cj = bb * el;
    #pragma unroll
    for (int u = 0; u < 4; u++) {
      bf16x8 r = *(const bf16x8*)(src + u * 8);
      #pragma unroll
      for (int e = 0; e < 8; e++)
        sKt[(wid * 32 + u * 8 + e) * 72 + lane] = (short)f2b(b2f((unsigned short)r[e]) * cj);
    }
  }
  __syncthreads();

  {
    f32x4 accA[4];
    #pragma unroll
    for (int t = 0; t < 4; t++) accA[t] = f32x4{0.f, 0.f, 0.f, 0.f};
    #pragma unroll
    for (int ks = 0; ks < 4; ks++) {
      bf16x8 a = *(const bf16x8*)&sKn[(wid * 16 + lane16) * 152 + ks * 32 + quad * 8];
      #pragma unroll
      for (int jt = 0; jt < 4; jt++) {
        bf16x8 bfr = *(const bf16x8*)&sKn[(jt * 16 + lane16) * 152 + ks * 32 + quad * 8];
        accA[jt] = __builtin_amdgcn_mfma_f32_16x16x32_bf16(a, bfr, accA[jt], 0, 0, 0);
      }
    }
    #pragma unroll
    for (int jt = 0; jt < 4; jt++) {
      int j = jt * 16 + lane16;
      float lj = sl[j];
      #pragma unroll
      for (int r = 0; r < 4; r++) {
        int i = wid * 16 + quad * 4 + r;
        float v = (j < i) ? sbb[i] * expf(sl[i] - lj) * accA[jt][r] : 0.f;
        sA[i * 68 + j] = v;
      }
    }
  }
  __syncthreads();

  {
    const unsigned short* src = qact + (size_t)(row0 + lane) * CONV_INNER + 4096 + h * 128 + wid * 32;
    #pragma unroll
    for (int u = 0; u < 4; u++) {
      bf16x8 r = *(const bf16x8*)(src + u * 8);
      #pragma unroll
      for (int e = 0; e < 8; e++)
        sVt[(wid * 32 + u * 8 + e) * 72 + lane] = (short)f2b(b2f((unsigned short)r[e]) * bb);
    }
  }
  __syncthreads();

  if (wid == 0 && lane < 32) {
    int c = lane;
    float treg[32];
    treg[0] = (c == 0) ? 1.f : 0.f;
    #pragma unroll
    for (int i = 1; i < 32; i++) {
      float s = 0.f;
      #pragma unroll
      for (int j = 0; j < i; j++) s += sA[i * 68 + j] * treg[j];
      treg[i] = ((i == c) ? 1.f : 0.f) - s;
    }
    #pragma unroll
    for (int i = 0; i < 32; i++) sT[i * 68 + c] = treg[i];
  } else if (wid == 1 && lane < 32) {
    int c = lane;
    float treg[32];
    treg[0] = (c == 0) ? 1.f : 0.f;
    #pragma unroll
    for (int i = 1; i < 32; i++) {
      float s = 0.f;
      #pragma unroll
      for (int j = 0; j < i; j++) s += sA[(32 + i) * 68 + 32 + j] * treg[j];
      treg[i] = ((i == c) ? 1.f : 0.f) - s;
    }
    #pragma unroll
    for (int i = 0; i < 32; i++) sT[(32 + i) * 68 + 32 + c] = treg[i];
  } else if (wid == 2) {
    for (int e = lane; e < 1024; e += 64) sT[(e >> 5) * 68 + 32 + (e & 31)] = 0.f;
  }
  __syncthreads();

  {
    int i = tid & 31, c0 = (tid >> 5) * 4;
    float x[4] = {0.f, 0.f, 0.f, 0.f};
    #pragma unroll
    for (int j = 0; j < 32; j++) {
      float a = sA[(32 + i) * 68 + j];
      #pragma unroll
      for (int cc = 0; cc < 4; cc++) x[cc] += a * sT[j * 68 + c0 + cc];
    }
    #pragma unroll
    for (int cc = 0; cc < 4; cc++) sA[i * 68 + c0 + cc] = x[cc];
  }
  __syncthreads();
  {
    int i = tid & 31, c0 = (tid >> 5) * 4;
    float x[4] = {0.f, 0.f, 0.f, 0.f};
    #pragma unroll
    for (int j = 0; j < 32; j++) {
      float t2 = sT[(32 + i) * 68 + 32 + j];
      #pragma unroll
      for (int cc = 0; cc < 4; cc++) x[cc] += t2 * sA[j * 68 + c0 + cc];
    }
    #pragma unroll
    for (int cc = 0; cc < 4; cc++) sT[(32 + i) * 68 + c0 + cc] = -x[cc];
  }
  __syncthreads();
  #pragma unroll
  for (int ii = 0; ii < 16; ii++) {
    int e = tid + 256 * ii;
    int r = e >> 6, cc = e & 63;
    sTb[r * 72 + cc] = (short)f2b(sT[r * 68 + cc]);
  }
  __syncthreads();

  {
    f32x4 accW[8], accU[8];
    #pragma unroll
    for (int nt = 0; nt < 8; nt++) { accW[nt] = f32x4{0.f,0.f,0.f,0.f}; accU[nt] = f32x4{0.f,0.f,0.f,0.f}; }
    bf16x8 ta[2];
    #pragma unroll
    for (int ks = 0; ks < 2; ks++)
      ta[ks] = *(const bf16x8*)&sTb[(wid * 16 + lane16) * 72 + ks * 32 + quad * 8];
    #pragma unroll
    for (int nt = 0; nt < 8; nt++) {
      #pragma unroll
      for (int ks = 0; ks < 2; ks++) {
        bf16x8 bk = *(const bf16x8*)&sKt[(nt * 16 + lane16) * 72 + ks * 32 + quad * 8];
        accW[nt] = __builtin_amdgcn_mfma_f32_16x16x32_bf16(ta[ks], bk, accW[nt], 0, 0, 0);
        bf16x8 bv = *(const bf16x8*)&sVt[(nt * 16 + lane16) * 72 + ks * 32 + quad * 8];
        accU[nt] = __builtin_amdgcn_mfma_f32_16x16x32_bf16(ta[ks], bv, accU[nt], 0, 0, 0);
      }
    }
    unsigned short* Wg = W_all + (size_t)cid * 8192;
    unsigned short* Ug = U_all + (size_t)cid * 8192;
    #pragma unroll
    for (int nt = 0; nt < 8; nt++)
      #pragma unroll
      for (int r = 0; r < 4; r++) {
        int i = wid * 16 + quad * 4 + r, k = nt * 16 + lane16;
        Wg[i * 128 + k] = f2b(accW[nt][r]);
        Ug[i * 128 + k] = f2b(accU[nt][r]);
      }
  }
}

// ================= PASS 2a: sequential state recurrence only =================
__global__ __launch_bounds__(512) void state_scan(
    unsigned short* qact, unsigned short* g1out,
    const float* __restrict__ g_arr,
    const unsigned short* __restrict__ W_all, const unsigned short* __restrict__ U_all,
    float* __restrict__ state_out)
{
  __shared__ __align__(16) short sS[64 * 136];    // S half-tile [64v][128k] bf16
  __shared__ __align__(16) short sDt[64 * 72];    // Dt [64v][64t] bf16
  __shared__ __align__(16) short sK2[128 * 72];   // K2^T [128k'][64t] bf16
  const int tid = threadIdx.x, lane = tid & 63, w = tid >> 6;
  const int lane16 = lane & 15, quad = lane >> 4;
  const int bid = blockIdx.x;
  const int bh = bid >> 1, vs = bid & 1;
  const int h = bh & 31, b = bh >> 5, qh = h >> 1;
  const int V0 = vs * 64;
  const int tt = w >> 1, vhl = (w & 1) * 32;      // aD work split
  const int avt = w & 3, kt0 = (w >> 2) * 4;      // aS work split

  for (int e = tid; e < 64 * 136 / 2; e += 512) ((unsigned int*)sS)[e] = 0u;
  float Sreg[4][4];
  #pragma unroll
  for (int n = 0; n < 4; n++)
    #pragma unroll
    for (int r = 0; r < 4; r++) Sreg[n][r] = 0.f;

  // ---- prefetch chunk 0 ----
  float gvn;
  bf16x8 kn[2], wn[4];
  unsigned short un[8];
  {
    const int r0_ = b * SEQ, cid_ = bh << 5;
    gvn = g_arr[(size_t)(r0_ + lane) * 32 + h];
    const unsigned short* ks_ = qact + (size_t)(r0_ + lane) * 8192 + 2048 + qh * 128 + w * 16;
    kn[0] = *(const bf16x8*)ks_; kn[1] = *(const bf16x8*)(ks_ + 8);
    const unsigned short* ws_ = W_all + (size_t)cid_ * 8192 + (tt * 16 + lane16) * 128 + quad * 8;
    #pragma unroll
    for (int ks = 0; ks < 4; ks++) wn[ks] = *(const bf16x8*)(ws_ + ks * 32);
    const unsigned short* us_ = U_all + (size_t)cid_ * 8192 + (tt * 16 + quad * 4) * 128 + V0 + vhl + lane16;
    #pragma unroll
    for (int vt = 0; vt < 2; vt++)
      #pragma unroll
      for (int r = 0; r < 4; r++) un[vt * 4 + r] = us_[r * 128 + vt * 16];
  }

  for (int ch = 0; ch < 32; ch++) {
    const int cid = (bh << 5) + ch;
    float l = gvn;
    #pragma unroll
    for (int off = 1; off < 64; off <<= 1) {
      float p = __shfl_up(l, off, 64);
      if (lane >= off) l += p;
    }
    float lC = __shfl(l, 63, 64);
    float elC = expf(lC);
    float s2 = expf(lC - l);
    #pragma unroll
    for (int e = 0; e < 8; e++)
      sK2[(w * 16 + e) * 72 + lane] = (short)f2b(b2f((unsigned short)kn[0][e]) * s2);
    #pragma unroll
    for (int e = 0; e < 8; e++)
      sK2[(w * 16 + 8 + e) * 72 + lane] = (short)f2b(b2f((unsigned short)kn[1][e]) * s2);
    bf16x8 wc[4];
    #pragma unroll
    for (int ks = 0; ks < 4; ks++) wc[ks] = wn[ks];
    unsigned short uc[8];
    #pragma unroll
    for (int i = 0; i < 8; i++) uc[i] = un[i];

    if (ch < 31) {
      const int r0_ = b * SEQ + (ch + 1) * 64, cid_ = cid + 1;
      gvn = g_arr[(size_t)(r0_ + lane) * 32 + h];
      const unsigned short* ks_ = qact + (size_t)(r0_ + lane) * 8192 + 2048 + qh * 128 + w * 16;
      kn[0] = *(const bf16x8*)ks_; kn[1] = *(const bf16x8*)(ks_ + 8);
      const unsigned short* ws_ = W_all + (size_t)cid_ * 8192 + (tt * 16 + lane16) * 128 + quad * 8;
      #pragma unroll
      for (int ks = 0; ks < 4; ks++) wn[ks] = *(const bf16x8*)(ws_ + ks * 32);
      const unsigned short* us_ = U_all + (size_t)cid_ * 8192 + (tt * 16 + quad * 4) * 128 + V0 + vhl + lane16;
      #pragma unroll
      for (int vt = 0; vt < 2; vt++)
        #pragma unroll
        for (int r = 0; r < 4; r++) un[vt * 4 + r] = us_[r * 128 + vt * 16];
    }
    asm volatile("s_waitcnt lgkmcnt(0)" ::: "memory");
    __builtin_amdgcn_s_barrier();      // bar1: sS(entering) + sK2 ready

    // Dt = U - W.S^T  -> out[t][v]
    f32x4 aD[2];
    aD[0] = f32x4{0.f,0.f,0.f,0.f}; aD[1] = f32x4{0.f,0.f,0.f,0.f};
    #pragma unroll
    for (int ks = 0; ks < 4; ks++)
      #pragma unroll
      for (int vt = 0; vt < 2; vt++) {
        bf16x8 bfr = *(const bf16x8*)&sS[(vhl + vt * 16 + lane16) * 136 + ks * 32 + quad * 8];
        aD[vt] = __builtin_amdgcn_mfma_f32_16x16x32_bf16(wc[ks], bfr, aD[vt], 0, 0, 0);
      }
    #pragma unroll
    for (int vt = 0; vt < 2; vt++)
      #pragma unroll
      for (int r = 0; r < 4; r++)
        sDt[(vhl + vt * 16 + lane16) * 72 + tt * 16 + quad * 4 + r] =
            (short)f2b(b2f(uc[vt * 4 + r]) - aD[vt][r]);
    asm volatile("s_waitcnt lgkmcnt(0)" ::: "memory");
    __builtin_amdgcn_s_barrier();      // bar2: sDt ready

    // S <- elC*S + Dt.K2
    bf16x8 a2[2];
    #pragma unroll
    for (int ks2 = 0; ks2 < 2; ks2++)
      a2[ks2] = *(const bf16x8*)&sDt[(avt * 16 + lane16) * 72 + ks2 * 32 + quad * 8];
    f32x4 aS[4];
    #pragma unroll
    for (int n = 0; n < 4; n++) aS[n] = f32x4{0.f,0.f,0.f,0.f};
    #pragma unroll
    for (int n = 0; n < 4; n++)
      #pragma unroll
      for (int ks2 = 0; ks2 < 2; ks2++) {
        bf16x8 bfr = *(const bf16x8*)&sK2[((kt0 + n) * 16 + lane16) * 72 + ks2 * 32 + quad * 8];
        aS[n] = __builtin_amdgcn_mfma_f32_16x16x32_bf16(a2[ks2], bfr, aS[n], 0, 0, 0);
      }
    #pragma unroll
    for (int r = 0; r < 4; r++) {
      int vg = V0 + avt * 16 + quad * 4 + r;
      unsigned short* sp = nullptr;
      if (ch < 31) sp = sall_ptr(qact, g1out, cid + 1, vg);
      #pragma unroll
      for (int n = 0; n < 4; n++) {
        float v = elC * Sreg[n][r] + aS[n][r];
        Sreg[n][r] = v;
        unsigned short bv = f2b(v);
        sS[(avt * 16 + quad * 4 + r) * 136 + (kt0 + n) * 16 + lane16] = (short)bv;
        if (ch < 31) sp[(kt0 + n) * 16 + lane16] = bv;
      }
    }
    asm volatile("s_waitcnt lgkmcnt(0)" ::: "memory");
    __builtin_amdgcn_s_barrier();      // bar3: sS(new) written; sDt/sK2 reads done
  }

  float* so = state_out + (size_t)bh * 16384;
  #pragma unroll
  for (int r = 0; r < 4; r++)
    #pragma unroll
    for (int n = 0; n < 4; n++)
      so[(size_t)(V0 + avt * 16 + quad * 4 + r) * 128 + (kt0 + n) * 16 + lane16] = Sreg[n][r];
}

// ================= PASS 2b: per-chunk output (fully parallel) =================
__global__ __launch_bounds__(256) void chunk_out(
    unsigned short* qact, unsigned short* g1out,
    const float* __restrict__ g_arr, const float* __restrict__ norm_w,
    const unsigned short* __restrict__ W_all, const unsigned short* __restrict__ U_all)
{
  __shared__ __align__(16) short sS[128 * 136];   // 34816 B
  __shared__ __align__(16) short sKn[64 * 136];   // 17408 B ; sM aliases
  __shared__ __align__(16) short sDt[128 * 72];   // 18432 B
  __shared__ float sl[64];
  __shared__ float sel[64];
  __shared__ float snw[128];
  short* sM = sKn;
  const int tid = threadIdx.x, lane = tid & 63, wid = tid >> 6;
  const int lane16 = lane & 15, quad = lane >> 4;
  const int cid = blockIdx.x;
  const int ch = cid & 31, h = (cid >> 5) & 31, b = cid >> 10, qh = h >> 1;
  const int row0 = b * SEQ + ch * 64;

  float l = g_arr[(size_t)(row0 + lane) * 32 + h];
  #pragma unroll
  for (int off = 1; off < 64; off <<= 1) {
    float p = __shfl_up(l, off, 64);
    if (lane >= off) l += p;
  }
  if (wid == 0) { sl[lane] = l; sel[lane] = expf(l); }
  if (tid < 128) snw[tid] = norm_w[tid];

  {
    int j4 = tid >> 2, kc = (tid & 3) * 32;
    const unsigned short* sk = qact + (size_t)(row0 + j4) * 8192 + 2048 + qh * 128 + kc;
    #pragma unroll
    for (int u = 0; u < 4; u++)
      *(bf16x8*)&sKn[j4 * 136 + kc + u * 8] = *(const bf16x8*)(sk + u * 8);
  }
  if (ch == 0) {
    for (int e = tid; e < 128 * 136 / 2; e += 256) ((unsigned int*)sS)[e] = 0u;
  } else {
    int vr = tid >> 1, hf = (tid & 1) * 64;
    const unsigned short* sp = sall_ptr(qact, g1out, cid, vr) + hf;
    #pragma unroll
    for (int u = 0; u < 8; u++)
      *(bf16x8*)&sS[vr * 136 + hf + u * 8] = *(const bf16x8*)(sp + u * 8);
  }
  bf16x8 qf[4], wf[4];
  {
    const unsigned short* qsrc = qact + (size_t)(row0 + wid * 16 + lane16) * 8192 + qh * 128 + quad * 8;
    #pragma unroll
    for (int ks = 0; ks < 4; ks++) qf[ks] = *(const bf16x8*)(qsrc + ks * 32);
    const unsigned short* wsrc = W_all + (size_t)cid * 8192 + (wid * 16 + lane16) * 128 + quad * 8;
    #pragma unroll
    for (int ks = 0; ks < 4; ks++) wf[ks] = *(const bf16x8*)(wsrc + ks * 32);
  }
  unsigned short uvr[8][4], zr[8][4];
  {
    const unsigned short* usrc = U_all + (size_t)cid * 8192 + (wid * 16 + quad * 4) * 128 + lane16;
    const unsigned short* zsrc = g1out + (size_t)(row0 + wid * 16 + quad * 4) * NPAD + 8192 + h * 128 + lane16;
    #pragma unroll
    for (int nt = 0; nt < 8; nt++)
      #pragma unroll
      for (int r = 0; r < 4; r++) {
        uvr[nt][r] = usrc[r * 128 + nt * 16];
        zr[nt][r]  = zsrc[(size_t)r * NPAD + nt * 16];
      }
  }
  __syncthreads();   // B1

  {
    f32x4 aD[8];
    #pragma unroll
    for (int nt = 0; nt < 8; nt++) aD[nt] = f32x4{0.f,0.f,0.f,0.f};
    #pragma unroll
    for (int ks = 0; ks < 4; ks++)
      #pragma unroll
      for (int nt = 0; nt < 8; nt++) {
        bf16x8 bfr = *(const bf16x8*)&sS[(nt * 16 + lane16) * 136 + ks * 32 + quad * 8];
        aD[nt] = __builtin_amdgcn_mfma_f32_16x16x32_bf16(wf[ks], bfr, aD[nt], 0, 0, 0);
      }
    #pragma unroll
    for (int nt = 0; nt < 8; nt++)
      #pragma unroll
      for (int r = 0; r < 4; r++)
        sDt[(nt * 16 + lane16) * 72 + wid * 16 + quad * 4 + r] =
            (short)f2b(b2f(uvr[nt][r]) - aD[nt][r]);
  }
  f32x4 aM[4];
  #pragma unroll
  for (int jt = 0; jt < 4; jt++) aM[jt] = f32x4{0.f,0.f,0.f,0.f};
  #pragma unroll
  for (int ks = 0; ks < 4; ks++)
    #pragma unroll
    for (int jt = 0; jt < 4; jt++) {
      bf16x8 bfr = *(const bf16x8*)&sKn[(jt * 16 + lane16) * 136 + ks * 32 + quad * 8];
      aM[jt] = __builtin_amdgcn_mfma_f32_16x16x32_bf16(qf[ks], bfr, aM[jt], 0, 0, 0);
    }
  __syncthreads();   // B2

  #pragma unroll
  for (int jt = 0; jt < 4; jt++) {
    int j = jt * 16 + lane16;
    float lj = sl[j];
    #pragma unroll
    for (int r = 0; r < 4; r++) {
      int i = wid * 16 + quad * 4 + r;
      float m = (j <= i) ? expf(sl[i] - lj) * aM[jt][r] : 0.f;
      sM[i * 72 + j] = (short)f2b(m);
    }
  }
  f32x4 aO[8];
  #pragma unroll
  for (int nt = 0; nt < 8; nt++) aO[nt] = f32x4{0.f,0.f,0.f,0.f};
  #pragma unroll
  for (int ks = 0; ks < 4; ks++)
    #pragma unroll
    for (int nt = 0; nt < 8; nt++) {
      bf16x8 bfr = *(const bf16x8*)&sS[(nt * 16 + lane16) * 136 + ks * 32 + quad * 8];
      aO[nt] = __builtin_amdgcn_mfma_f32_16x16x32_bf16(qf[ks], bfr, aO[nt], 0, 0, 0);
    }
  #pragma unroll
  for (int r = 0; r < 4; r++) {
    float eli = sel[wid * 16 + quad * 4 + r];
    #pragma unroll
    for (int nt = 0; nt < 8; nt++) aO[nt][r] *= eli;
  }
  __syncthreads();   // B3

  {
    bf16x8 a2[2];
    #pragma unroll
    for (int ks2 = 0; ks2 < 2; ks2++)
      a2[ks2] = *(const bf16x8*)&sM[(wid * 16 + lane16) * 72 + ks2 * 32 + quad * 8];
    #pragma unroll
    for (int ks2 = 0; ks2 < 2; ks2++)
      #pragma unroll
      for (int nt = 0; nt < 8; nt++) {
        bf16x8 bfr = *(const bf16x8*)&sDt[(nt * 16 + lane16) * 72 + ks2 * 32 + quad * 8];
        aO[nt] = __builtin_amdgcn_mfma_f32_16x16x32_bf16(a2[ks2], bfr, aO[nt], 0, 0, 0);
      }
  }
  #pragma unroll
  for (int r = 0; r < 4; r++) {
    float ss = 0.f;
    #pragma unroll
    for (int nt = 0; nt < 8; nt++) ss += aO[nt][r] * aO[nt][r];
    ss += __shfl_xor(ss, 1, 64);
    ss += __shfl_xor(ss, 2, 64);
    ss += __shfl_xor(ss, 4, 64);
    ss += __shfl_xor(ss, 8, 64);
    float rinv = rsqrtf(ss * (1.f / 128.f) + 1e-6f);
    int i = wid * 16 + quad * 4 + r;
    size_t grow = (size_t)(row0 + i) * NPAD + h * 128;
    #pragma unroll
    for (int nt = 0; nt < 8; nt++) {
      int v = nt * 16 + lane16;
      float zv = b2f(zr[nt][r]);
      float zg = zv / (1.f + __expf(-zv));
      float y = snw[v] * (aO[nt][r] * rinv) * zg;
      g1out[grow + v] = f2b(y);
    }
  }
}

extern "C" void kernel_launch(void* const* d_in, const int* in_sizes, int n_in,
                              void* d_out, int out_size, void* d_ws, size_t ws_size,
                              hipStream_t stream)
{
  const float* hidden  = (const float*)d_in[0];
  const float* W_qkv   = (const float*)d_in[1];
  const float* W_z     = (const float*)d_in[2];
  const float* W_a     = (const float*)d_in[3];
  const float* W_b     = (const float*)d_in[4];
  const float* conv_w  = (const float*)d_in[5];
  const float* A_log   = (const float*)d_in[6];
  const float* dt_bias = (const float*)d_in[7];
  const float* norm_w  = (const float*)d_in[8];
  const float* W_out   = (const float*)d_in[9];

  char* ws = (char*)d_ws;
  unsigned short* hbf   = (unsigned short*)(ws);                 // [4096][2048] bf16
  unsigned short* Wcat  = (unsigned short*)(ws + 16777216ull);   // [12416][2048] bf16
  unsigned short* Woutb = (unsigned short*)(ws + 67633152ull);   // [2048][4096] bf16
  unsigned short* g1out = (unsigned short*)(ws + 84410368ull);   // [4096][12416] bf16
  unsigned short* qact  = (unsigned short*)(ws + 186122240ull);  // [4096][8192] bf16
  float* g_arr          = (float*)(ws + 253231104ull);           // [4096][32]
  float* beta           = (float*)(ws + 253755392ull);           // [4096][32]
  unsigned short* W_all = (unsigned short*)(ws);                 // aliases hbf (dead after GEMM1)
  unsigned short* U_all = (unsigned short*)(ws + 33554432ull);   // aliases Wcat tail
  float* gate_part      = (float*)qact;   // [8][4096][64] fp32, 8MB; dead before conv writes qact

  float* out0 = (float*)d_out;          // (2,2048,2048) fp32
  float* out1 = out0 + 8388608;         // conv_state (2,8192,4)
  float* out2 = out0 + 8454144;         // state (2,32,128,128)

  cast_kernel<<<8192,  256, 0, stream>>>(hidden, hbf, 2097152);
  cast_kernel<<<16384, 256, 0, stream>>>(W_qkv, Wcat, 4194304);
  cast_kernel<<<8192,  256, 0, stream>>>(W_z,   Wcat + 8192ull  * 2048, 2097152);
  cast_kernel<<<64,    256, 0, stream>>>(W_a,   Wcat + 12288ull * 2048, 16384);
  cast_kernel<<<64,    256, 0, stream>>>(W_b,   Wcat + 12320ull * 2048, 16384);
  cast_kernel<<<8192,  256, 0, stream>>>(W_out, Woutb, 2097152);

  // a/b gate columns via split-K (8 x 256-K segments, full-chip 256 blocks)
  gemm_ab<<<dim3(8, 32), 256, 0, stream>>>(hbf, Wcat + 12288ull * 2048, gate_part);
  // GEMM1: 256^2 8-phase over q,k,v,z; 16 m-tiles (fast) x 48 n-tiles = 768 = 3x256
  gemm1_256<<<768, 512, 0, stream>>>(hbf, Wcat, g1out, 2048, 2048, 2048,
                                     NPAD, 12288, NPAD - 1, 16);
  gebeta_kernel<<<512, 256, 0, stream>>>(gate_part, A_log, dt_bias, g_arr, beta);
  conv_kernel<<<dim3(4096, 8), 128, 0, stream>>>(g1out, conv_w, qact);
  convstate_kernel<<<256, 256, 0, stream>>>(g1out, out1);

  chunk_prep<<<2048, 256, 0, stream>>>(qact, g_arr, beta, W_all, U_all);
  state_scan<<<128, 512, 0, stream>>>(qact, g1out, g_arr, W_all, U_all, out2);
  chunk_out<<<2048, 256, 0, stream>>>(qact, g1out, g_arr, norm_w, W_all, U_all);

  gemm_bt<false><<<dim3(16, 32), 256, 0, stream>>>(g1out, Woutb, out0, 4096, NPAD, 4096, 2048, 2048);
}

// Round 5
// 823.328 us; speedup vs baseline: 1.3279x; 1.0191x over previous
//
#include <hip/hip_runtime.h>
#include <hip/hip_bf16.h>
#include <cstdint>

#define SEQ 2048
#define NPAD 12416      // 97*128, padded N for GEMM1 output rows
#define NTOT 12352      // qkv(8192) + z(4096) + a(32) + b(32)
#define CONV_INNER 8192

typedef __attribute__((ext_vector_type(8))) short bf16x8;
typedef __attribute__((ext_vector_type(4))) float f32x4;

__device__ __forceinline__ float b2f(unsigned short u) {
  union { unsigned int i; float f; } x; x.i = ((unsigned int)u) << 16; return x.f;
}
__device__ __forceinline__ unsigned short f2b(float f) {
  __hip_bfloat16 h = __float2bfloat16(f);
  return *reinterpret_cast<unsigned short*>(&h);
}
__device__ __forceinline__ void load_lds16(const short* g, short* l) {
  __builtin_amdgcn_global_load_lds(
      (__attribute__((address_space(1))) void*)(g),
      (__attribute__((address_space(3))) void*)(l), 16, 0, 0);
}

// S_all staging: state ENTERING chunk ch of (b,h), bf16 [128 v][128 k].
// Lives in dead workspace columns: qact cols 4096..8191 (v-region, dead after
// chunk_prep) for b=0 cids; g1out cols 4096..8191 (qkv_raw, dead after conv)
// for b=1 cids. One cid = 4 row-slots of 32 v-rows each.
__device__ __forceinline__ unsigned short* sall_ptr(
    unsigned short* qact, unsigned short* g1out, int cid, int vrow) {
  int slot = ((cid & 1023) << 2) + (vrow >> 5);
  if (cid < 1024) return qact + (size_t)slot * 8192 + 4096 + (vrow & 31) * 128;
  return g1out + (size_t)slot * (size_t)NPAD + 4096 + (vrow & 31) * 128;
}

// ---------------- fp32 -> bf16 cast ----------------
__global__ void cast_kernel(const float* __restrict__ in, unsigned short* __restrict__ out, int n4) {
  int i = blockIdx.x * blockDim.x + threadIdx.x;
  if (i >= n4) return;
  float4 v = ((const float4*)in)[i];
  ushort4 o;
  o.x = f2b(v.x); o.y = f2b(v.y); o.z = f2b(v.z); o.w = f2b(v.w);
  ((ushort4*)out)[i] = o;
}

// ---------------- bf16 MFMA GEMM (128^2, 2-barrier): C[m][n] = sum_k A[m][k]*B[n][k] ----
template<bool OUT_BF16>
__global__ __launch_bounds__(256) void gemm_bt(
    const unsigned short* __restrict__ A,   // [M][lda] bf16
    const unsigned short* __restrict__ Bm,  // [Nrows][ldb] bf16
    void* __restrict__ Cout, int K, int lda, int ldb, int ldc, int nmax)
{
  __shared__ __align__(16) short lA[2][128 * 32];
  __shared__ __align__(16) short lB[2][128 * 32];
  const int tid = threadIdx.x;
  const int lane = tid & 63, wid = tid >> 6;
  const int lane16 = lane & 15, quad = lane >> 4;
  const int wm = (wid & 1) * 64, wn = (wid >> 1) * 64;
  const int m0 = blockIdx.y * 128, n0 = blockIdx.x * 128;
  const int srow = wid * 16 + (lane >> 2);                  // staged tile row
  const int scol = (((lane & 3) ^ ((lane >> 3) & 3))) * 8;  // swizzled source chunk
  const int rchunk = (quad ^ ((lane16 >> 1) & 3)) * 8;      // swizzled fragment chunk

  f32x4 acc[4][4];
  #pragma unroll
  for (int i = 0; i < 4; i++)
    #pragma unroll
    for (int j = 0; j < 4; j++)
      acc[i][j] = f32x4{0.f, 0.f, 0.f, 0.f};

  const short* As = (const short*)A;
  const short* Bs = (const short*)Bm;
  short* lA0s[2] = { &lA[0][(wid * 16) * 32], &lA[1][(wid * 16) * 32] };
  short* lA1s[2] = { &lA[0][(64 + wid * 16) * 32], &lA[1][(64 + wid * 16) * 32] };
  short* lB0s[2] = { &lB[0][(wid * 16) * 32], &lB[1][(wid * 16) * 32] };
  short* lB1s[2] = { &lB[0][(64 + wid * 16) * 32], &lB[1][(64 + wid * 16) * 32] };
  const short* ga0 = As + (size_t)(m0 + srow) * lda + scol;
  const short* ga1 = As + (size_t)(m0 + 64 + srow) * lda + scol;
  const short* gb0 = Bs + (size_t)(n0 + srow) * ldb + scol;
  const short* gb1 = Bs + (size_t)(n0 + 64 + srow) * ldb + scol;

  for (int kb = 0; kb < K; kb += 64) {
    #pragma unroll
    for (int st = 0; st < 2; st++) {
      int ko = kb + st * 32;
      load_lds16(ga0 + ko, lA0s[st]);
      load_lds16(ga1 + ko, lA1s[st]);
      load_lds16(gb0 + ko, lB0s[st]);
      load_lds16(gb1 + ko, lB1s[st]);
    }
    __syncthreads();   // drains vmcnt -> both stages complete
    #pragma unroll
    for (int st = 0; st < 2; st++) {
      bf16x8 af[4], bfr[4];
      #pragma unroll
      for (int t = 0; t < 4; t++) af[t]  = *(const bf16x8*)&lA[st][(wm + t * 16 + lane16) * 32 + rchunk];
      #pragma unroll
      for (int t = 0; t < 4; t++) bfr[t] = *(const bf16x8*)&lB[st][(wn + t * 16 + lane16) * 32 + rchunk];
      #pragma unroll
      for (int i = 0; i < 4; i++)
        #pragma unroll
        for (int j = 0; j < 4; j++)
          acc[i][j] = __builtin_amdgcn_mfma_f32_16x16x32_bf16(af[i], bfr[j], acc[i][j], 0, 0, 0);
    }
    __syncthreads();   // all reads done before next overwrite
  }

  #pragma unroll
  for (int i = 0; i < 4; i++) {
    #pragma unroll
    for (int j = 0; j < 4; j++) {
      int n = n0 + wn + j * 16 + lane16;
      if (n >= nmax) continue;
      #pragma unroll
      for (int r = 0; r < 4; r++) {
        int m = m0 + wm + i * 16 + quad * 4 + r;
        float v = acc[i][j][r];
        if (OUT_BF16) ((unsigned short*)Cout)[(size_t)m * ldc + n] = f2b(v);
        else          ((float*)Cout)[(size_t)m * ldc + n] = v;
      }
    }
  }
}

// ---------- split-K a/b gate GEMM: P[ks][m][64] = A[m][k0:k0+256] . Bab[n][k0:k0+256]^T ----------
// 256 blocks = 8 K-segments x 32 m-tiles; full-chip; fp32 partials.
__global__ __launch_bounds__(256) void gemm_ab(
    const unsigned short* __restrict__ A,     // hbf [4096][2048]
    const unsigned short* __restrict__ Bm,    // Wcat rows 12288.. (64 rows: a then b)
    float* __restrict__ Pout)                 // [8][4096][64] fp32
{
  __shared__ __align__(16) short lA[2][128 * 32];
  __shared__ __align__(16) short lB[2][128 * 32];
  const int tid = threadIdx.x;
  const int lane = tid & 63, wid = tid >> 6;
  const int lane16 = lane & 15, quad = lane >> 4;
  const int wm = (wid & 1) * 64, wn = (wid >> 1) * 64;
  const int m0 = blockIdx.y * 128;
  const int k0 = blockIdx.x * 256;
  const int srow = wid * 16 + (lane >> 2);
  const int scol = (((lane & 3) ^ ((lane >> 3) & 3))) * 8;
  const int rchunk = (quad ^ ((lane16 >> 1) & 3)) * 8;

  f32x4 acc[4][4];
  #pragma unroll
  for (int i = 0; i < 4; i++)
    #pragma unroll
    for (int j = 0; j < 4; j++)
      acc[i][j] = f32x4{0.f, 0.f, 0.f, 0.f};

  const short* As = (const short*)A;
  const short* Bs = (const short*)Bm;
  short* lA0s[2] = { &lA[0][(wid * 16) * 32], &lA[1][(wid * 16) * 32] };
  short* lA1s[2] = { &lA[0][(64 + wid * 16) * 32], &lA[1][(64 + wid * 16) * 32] };
  short* lB0s[2] = { &lB[0][(wid * 16) * 32], &lB[1][(wid * 16) * 32] };
  short* lB1s[2] = { &lB[0][(64 + wid * 16) * 32], &lB[1][(64 + wid * 16) * 32] };
  const short* ga0 = As + (size_t)(m0 + srow) * 2048 + k0 + scol;
  const short* ga1 = As + (size_t)(m0 + 64 + srow) * 2048 + k0 + scol;
  int br0 = srow > 63 ? 63 : srow;                 // only 64 B rows exist
  const short* gb0 = Bs + (size_t)br0 * 2048 + k0 + scol;
  const short* gb1 = Bs + (size_t)63  * 2048 + k0 + scol;   // rows 64.. all clamp

  for (int kb = 0; kb < 256; kb += 64) {
    #pragma unroll
    for (int st = 0; st < 2; st++) {
      int ko = kb + st * 32;
      load_lds16(ga0 + ko, lA0s[st]);
      load_lds16(ga1 + ko, lA1s[st]);
      load_lds16(gb0 + ko, lB0s[st]);
      load_lds16(gb1 + ko, lB1s[st]);
    }
    __syncthreads();
    #pragma unroll
    for (int st = 0; st < 2; st++) {
      bf16x8 af[4], bfr[4];
      #pragma unroll
      for (int t = 0; t < 4; t++) af[t]  = *(const bf16x8*)&lA[st][(wm + t * 16 + lane16) * 32 + rchunk];
      #pragma unroll
      for (int t = 0; t < 4; t++) bfr[t] = *(const bf16x8*)&lB[st][(wn + t * 16 + lane16) * 32 + rchunk];
      #pragma unroll
      for (int i = 0; i < 4; i++)
        #pragma unroll
        for (int j = 0; j < 4; j++)
          acc[i][j] = __builtin_amdgcn_mfma_f32_16x16x32_bf16(af[i], bfr[j], acc[i][j], 0, 0, 0);
    }
    __syncthreads();
  }

  #pragma unroll
  for (int i = 0; i < 4; i++) {
    #pragma unroll
    for (int j = 0; j < 4; j++) {
      int n = wn + j * 16 + lane16;
      if (n >= 64) continue;
      #pragma unroll
      for (int r = 0; r < 4; r++) {
        int m = m0 + wm + i * 16 + quad * 4 + r;
        Pout[((size_t)blockIdx.x * 4096 + m) * 64 + n] = acc[i][j][r];
      }
    }
  }
}

// ======== 256x256 4-phase GEMM (merged 8-phase; T2+T4+T5), bf16 out ========
// 512 threads = 8 waves (2M x 4N); BK=64 double-buffered; per-wave C = 128x64.
// Each phase: {4 bfr + 8 af ds_read_b128 || 2 stage units || 32 MFMA}.
// Uniform vmcnt(8) at each phase end retires exactly one phase's 4-load stage;
// producer->consumer slack = 3 phases. Drain iter: P1 vm4, P2 vm0.
// Tile map m-fastest: each XCD's resident blocks share B-panels (L2-resident).
__global__ __launch_bounds__(512, 2) void gemm1_256(
    const unsigned short* __restrict__ A,
    const unsigned short* __restrict__ Bm,
    unsigned short* __restrict__ Cout,
    int K, int lda, int ldb, int ldc, int nmax, int brmax, int tmc)
{
  __shared__ __align__(16) short lA[2][16384];
  __shared__ __align__(16) short lB[2][16384];
  const int tid = threadIdx.x;
  const int lane = tid & 63, wid = tid >> 6;
  const int lane16 = lane & 15, quad = lane >> 4;
  const int wm = (wid >> 2) * 128, wn = (wid & 3) * 64;
  const int cpx = gridDim.x >> 3;                 // grid % 8 == 0 (bijective)
  const int swz = ((int)blockIdx.x & 7) * cpx + ((int)blockIdx.x >> 3);
  const int tm = swz % tmc, tn = swz / tmc;       // m-fastest
  const int m0 = tm * 256, n0 = tn * 256;
  const int srow = tid >> 2;                                // 0..127
  const int scol = ((tid & 3) ^ ((tid >> 3) & 3)) * 8;      // swizzled src chunk
  const int rchunk = (quad ^ ((lane16 >> 1) & 3)) * 8;      // swizzled read chunk
  const int NK = K >> 6;

  const short* As = (const short*)A;
  const short* Bs = (const short*)Bm;
  const size_t arow0 = (size_t)(m0 + srow) * lda;
  const size_t arow1 = (size_t)(m0 + 128 + srow) * lda;
  int br0i = n0 + srow;       if (br0i > brmax) br0i = brmax;
  int br1i = n0 + 128 + srow; if (br1i > brmax) br1i = brmax;
  const size_t brow0 = (size_t)br0i * ldb;
  const size_t brow1 = (size_t)br1i * ldb;
  short* dA[2] = { &lA[0][wid * 512], &lA[1][wid * 512] };
  short* dB[2] = { &lB[0][wid * 512], &lB[1][wid * 512] };

  f32x4 acc[8][4];
  #pragma unroll
  for (int i = 0; i < 8; i++)
    #pragma unroll
    for (int j = 0; j < 4; j++) acc[i][j] = f32x4{0.f, 0.f, 0.f, 0.f};

  auto stgA = [&](int buf, int hk, int kt) {
    int co = kt * 64 + hk * 32 + scol;
    load_lds16(As + arow0 + co, dA[buf] + hk * 8192);
    load_lds16(As + arow1 + co, dA[buf] + hk * 8192 + 4096);
  };
  auto stgB = [&](int buf, int hk, int kt) {
    int co = kt * 64 + hk * 32 + scol;
    load_lds16(Bs + brow0 + co, dB[buf] + hk * 8192);
    load_lds16(Bs + brow1 + co, dB[buf] + hk * 8192 + 4096);
  };

#define G1_VM8()   asm volatile("s_waitcnt vmcnt(8)" ::: "memory")
#define G1_VM4()   asm volatile("s_waitcnt vmcnt(4)" ::: "memory")
#define G1_VM0()   asm volatile("s_waitcnt vmcnt(0)" ::: "memory")
// merged phase: reads (4 bfr + 8 af) || 2 stage units || barrier || 32 MFMA || gate || barrier
#define G1_PHASE(bufi, hofs, STG1, STG2, GATE) \
  { bf16x8 af[4], af2[4], bfr[4]; \
    _Pragma("unroll") \
    for (int jt = 0; jt < 4; jt++) \
      bfr[jt] = *(const bf16x8*)&lB[bufi][(hofs) + (wn + jt * 16 + lane16) * 32 + rchunk]; \
    _Pragma("unroll") \
    for (int mt = 0; mt < 4; mt++) \
      af[mt] = *(const bf16x8*)&lA[bufi][(hofs) + (wm + mt * 16 + lane16) * 32 + rchunk]; \
    STG1; \
    _Pragma("unroll") \
    for (int mt = 0; mt < 4; mt++) \
      af2[mt] = *(const bf16x8*)&lA[bufi][(hofs) + (wm + 64 + mt * 16 + lane16) * 32 + rchunk]; \
    STG2; \
    __builtin_amdgcn_s_barrier(); \
    asm volatile("s_waitcnt lgkmcnt(0)" ::: "memory"); \
    __builtin_amdgcn_s_setprio(1); \
    _Pragma("unroll") \
    for (int mt = 0; mt < 4; mt++) \
      _Pragma("unroll") \
      for (int jt = 0; jt < 4; jt++) \
        acc[mt][jt] = __builtin_amdgcn_mfma_f32_16x16x32_bf16( \
            af[mt], bfr[jt], acc[mt][jt], 0, 0, 0); \
    _Pragma("unroll") \
    for (int mt = 0; mt < 4; mt++) \
      _Pragma("unroll") \
      for (int jt = 0; jt < 4; jt++) \
        acc[4 + mt][jt] = __builtin_amdgcn_mfma_f32_16x16x32_bf16( \
            af2[mt], bfr[jt], acc[4 + mt][jt], 0, 0, 0); \
    __builtin_amdgcn_s_setprio(0); \
    GATE; \
    __builtin_amdgcn_s_barrier(); }

  // prologue: T0 (buf0) fully + T1.hk0 (buf1) = 6 units, 12 loads in order
  stgA(0, 0, 0); stgB(0, 0, 0); stgA(0, 1, 0); stgB(0, 1, 0);
  stgA(1, 0, 1); stgB(1, 0, 1);
  G1_VM8();          // first 4 loads (T0.hk0 A+B) landed
  __builtin_amdgcn_s_barrier();

  for (int it = 0; it < (NK >> 1); it++) {
    const int t0 = 2 * it, t1 = 2 * it + 1;
    const bool s2 = (t0 + 2) < NK;   // prefetch tile t0+2 -> buf0
    const bool s3 = (t1 + 2) < NK;   // prefetch tile t1+2 -> buf1

    // P0: consume buf0 hk0 (T0); stage T1.hk1 -> buf1
    G1_PHASE(0, 0,
             stgA(1, 1, t1), stgB(1, 1, t1),
             G1_VM8());
    // P1: consume buf0 hk1 (T0); stage T2.hk0 -> buf0
    G1_PHASE(0, 8192,
             if (s2) stgA(0, 0, t0 + 2), if (s2) stgB(0, 0, t0 + 2),
             if (s2) { G1_VM8(); } else { G1_VM4(); });
    // P2: consume buf1 hk0 (T1); stage T2.hk1 -> buf0
    G1_PHASE(1, 0,
             if (s2) stgA(0, 1, t0 + 2), if (s2) stgB(0, 1, t0 + 2),
             if (s2) { G1_VM8(); } else { G1_VM0(); });
    // P3: consume buf1 hk1 (T1); stage T3.hk0 -> buf1
    G1_PHASE(1, 8192,
             if (s3) stgA(1, 0, t1 + 2), if (s3) stgB(1, 0, t1 + 2),
             if (s3) { G1_VM8(); });
  }

  #pragma unroll
  for (int mt = 0; mt < 8; mt++)
    #pragma unroll
    for (int jt = 0; jt < 4; jt++) {
      int n = n0 + wn + jt * 16 + lane16;
      if (n >= nmax) continue;
      #pragma unroll
      for (int r = 0; r < 4; r++) {
        int m = m0 + wm + mt * 16 + quad * 4 + r;
        Cout[(size_t)m * ldc + n] = f2b(acc[mt][jt][r]);
      }
    }
#undef G1_VM8
#undef G1_VM4
#undef G1_VM0
#undef G1_PHASE
}

// ---------------- gates: g (log decay) and beta, from split-K fp32 partials ----------------
__global__ void gebeta_kernel(const float* __restrict__ P,   // [8][4096][64]
                              const float* __restrict__ A_log, const float* __restrict__ dt_bias,
                              float* __restrict__ g_out, float* __restrict__ beta)
{
  int idx = blockIdx.x * blockDim.x + threadIdx.x;  // 131072 = 4096*32
  int r = idx >> 5, n = idx & 31;
  float av = 0.f, bvv = 0.f;
  #pragma unroll
  for (int ks = 0; ks < 8; ks++) {
    const float* p = P + ((size_t)ks * 4096 + r) * 64;
    av  += p[n];
    bvv += p[32 + n];
  }
  float a = av + dt_bias[n];
  float sp = (a > 20.f) ? a : log1pf(expf(a));
  g_out[idx] = -expf(A_log[n]) * sp;
  beta[idx] = 1.f / (1.f + expf(-bvv));
}

// ---------------- conv(4) + silu + l2norm(q,k), 8 ch/thread ----------------
__global__ __launch_bounds__(128) void conv_kernel(
    const unsigned short* __restrict__ g1out, const float* __restrict__ conv_w,
    unsigned short* __restrict__ qkv_act)
{
  const int row = blockIdx.x;            // b*SEQ + s
  const int hg  = blockIdx.y;            // 0..7 (1024 channels each)
  const int tid = threadIdx.x;           // 0..127
  const int c0 = hg * 1024 + tid * 8;
  const int s = row & (SEQ - 1);
  float4 w4[8];
  #pragma unroll
  for (int e = 0; e < 8; e++) w4[e] = *(const float4*)(conv_w + (size_t)(c0 + e) * 4);
  float acc[8] = {0.f,0.f,0.f,0.f,0.f,0.f,0.f,0.f};
  #pragma unroll
  for (int j = 0; j < 4; j++) {
    int sj = s - 3 + j;
    if (sj >= 0) {
      bf16x8 x = *(const bf16x8*)(g1out + (size_t)(row - 3 + j) * NPAD + c0);
      #pragma unroll
      for (int e = 0; e < 8; e++) {
        float wj = (j == 0) ? w4[e].x : (j == 1) ? w4[e].y : (j == 2) ? w4[e].z : w4[e].w;
        acc[e] += wj * b2f((unsigned short)x[e]);
      }
    }
  }
  float sv[8], ssq = 0.f;
  #pragma unroll
  for (int e = 0; e < 8; e++) {
    sv[e] = acc[e] / (1.f + __expf(-acc[e]));
    ssq += sv[e] * sv[e];
  }
  ssq += __shfl_xor(ssq, 1, 64);
  ssq += __shfl_xor(ssq, 2, 64);
  ssq += __shfl_xor(ssq, 4, 64);
  ssq += __shfl_xor(ssq, 8, 64);
  float scale = 1.f;
  if (hg < 4) {
    scale = rsqrtf(ssq + 1e-6f);
    if (hg < 2) scale *= 0.08838834764831845f;  // q: 1/sqrt(128)
  }
  bf16x8 o;
  #pragma unroll
  for (int e = 0; e < 8; e++) o[e] = (short)f2b(sv[e] * scale);
  *(bf16x8*)(qkv_act + (size_t)row * CONV_INNER + c0) = o;
}

// ---------------- conv_state output ----------------
__global__ void convstate_kernel(const unsigned short* __restrict__ g1out, float* __restrict__ out1)
{
  int idx = blockIdx.x * blockDim.x + threadIdx.x;
  int b = idx >> 15, rem = idx & 32767;
  int c = rem >> 2, j = rem & 3;
  out1[idx] = b2f(g1out[(size_t)(b * SEQ + SEQ - 4 + j) * NPAD + c]);
}

// ================= PASS 1: chunk-local W,U (UT transform) =================
__global__ __launch_bounds__(256, 2) void chunk_prep(
    const unsigned short* __restrict__ qact,
    const float* __restrict__ g_arr, const float* __restrict__ beta_arr,
    unsigned short* __restrict__ W_all, unsigned short* __restrict__ U_all)
{
  __shared__ __align__(16) char smem[73472];
  short* sKn = (short*)smem;                  // 64 x stride152; Vt (128x72) aliases
  short* sVt = (short*)smem;
  short* sKt = (short*)(smem + 19456);        // 128 x 72
  float* sA  = (float*)(smem + 37888);        // 64 x 68 fp32; Tb aliases
  short* sTb = (short*)(smem + 37888);        // 64 x 72 bf16
  float* sT  = (float*)(smem + 55296);        // 64 x 68 fp32
  float* sl  = (float*)(smem + 72704);
  float* sel = (float*)(smem + 72960);
  float* sbb = (float*)(smem + 73216);

  const int tid = threadIdx.x, lane = tid & 63, wid = tid >> 6;
  const int lane16 = lane & 15, quad = lane >> 4;
  const int cid = blockIdx.x;
  const int ch = cid & 31, h = (cid >> 5) & 31, b = cid >> 10;
  const int qh = h >> 1;
  const int row0 = b * SEQ + ch * 64;

  float gv = g_arr[(size_t)(row0 + lane) * 32 + h];
  float bb = beta_arr[(size_t)(row0 + lane) * 32 + h];
  float l = gv;
  #pragma unroll
  for (int off = 1; off < 64; off <<= 1) {
    float p = __shfl_up(l, off, 64);
    if (lane >= off) l += p;
  }
  float el = expf(l);
  if (wid == 0) { sl[lane] = l; sel[lane] = el; sbb[lane] = bb; }

  {
    int j = tid >> 2, kc = (tid & 3) * 32;
    const unsigned short* src = qact + (size_t)(row0 + j) * CONV_INNER + 2048 + qh * 128 + kc;
    #pragma unroll
    for (int u = 0; u < 4; u++) {
      bf16x8 r = *(const bf16x8*)(src + u * 8);
      *(bf16x8*)&sKn[j * 152 + kc + u * 8] = r;
    }
  }
  {
    const unsigned short* src = qact + (size_t)(row0 + lane) * CONV_INNER + 2048 + qh * 128 + wid * 32;
    float cj = bb * el;
    #pragma unroll
    for (int u = 0; u < 4; u++) {
      bf16x8 r = *(const bf16x8*)(src + u * 8);
      #pragma unroll
      for (int e = 0; e < 8; e++)
        sKt[(wid * 32 + u * 8 + e) * 72 + lane] = (short)f2b(b2f((unsigned short)r[e]) * cj);
    }
  }
  __syncthreads();

  {
    f32x4 accA[4];
    #pragma unroll
    for (int t = 0; t < 4; t++) accA[t] = f32x4{0.f, 0.f, 0.f, 0.f};
    #pragma unroll
    for (int ks = 0; ks < 4; ks++) {
      bf16x8 a = *(const bf16x8*)&sKn[(wid * 16 + lane16) * 152 + ks * 32 + quad * 8];
      #pragma unroll
      for (int jt = 0; jt < 4; jt++) {
        bf16x8 bfr = *(const bf16x8*)&sKn[(jt * 16 + lane16) * 152 + ks * 32 + quad * 8];
        accA[jt] = __builtin_amdgcn_mfma_f32_16x16x32_bf16(a, bfr, accA[jt], 0, 0, 0);
      }
    }
    #pragma unroll
    for (int jt = 0; jt < 4; jt++) {
      int j = jt * 16 + lane16;
      float lj = sl[j];
      #pragma unroll
      for (int r = 0; r < 4; r++) {
        int i = wid * 16 + quad * 4 + r;
        float v = (j < i) ? sbb[i] * expf(sl[i] - lj) * accA[jt][r] : 0.f;
        sA[i * 68 + j] = v;
      }
    }
  }
  __syncthreads();

  {
    const unsigned short* src = qact + (size_t)(row0 + lane) * CONV_INNER + 4096 + h * 128 + wid * 32;
    #pragma unroll
    for (int u = 0; u < 4; u++) {
      bf16x8 r = *(const bf16x8*)(src + u * 8);
      #pragma unroll
      for (int e = 0; e < 8; e++)
        sVt[(wid * 32 + u * 8 + e) * 72 + lane] = (short)f2b(b2f((unsigned short)r[e]) * bb);
    }
  }
  __syncthreads();

  if (wid == 0 && lane < 32) {
    int c = lane;
    float treg[32];
    treg[0] = (c == 0) ? 1.f : 0.f;
    #pragma unroll
    for (int i = 1; i < 32; i++) {
      float s = 0.f;
      #pragma unroll
      for (int j = 0; j < i; j++) s += sA[i * 68 + j] * treg[j];
      treg[i] = ((i == c) ? 1.f : 0.f) - s;
    }
    #pragma unroll
    for (int i = 0; i < 32; i++) sT[i * 68 + c] = treg[i];
  } else if (wid == 1 && lane < 32) {
    int c = lane;
    float treg[32];
    treg[0] = (c == 0) ? 1.f : 0.f;
    #pragma unroll
    for (int i = 1; i < 32; i++) {
      float s = 0.f;
      #pragma unroll
      for (int j = 0; j < i; j++) s += sA[(32 + i) * 68 + 32 + j] * treg[j];
      treg[i] = ((i == c) ? 1.f : 0.f) - s;
    }
    #pragma unroll
    for (int i = 0; i < 32; i++) sT[(32 + i) * 68 + 32 + c] = treg[i];
  } else if (wid == 2) {
    for (int e = lane; e < 1024; e += 64) sT[(e >> 5) * 68 + 32 + (e & 31)] = 0.f;
  }
  __syncthreads();

  {
    int i = tid & 31, c0 = (tid >> 5) * 4;
    float x[4] = {0.f, 0.f, 0.f, 0.f};
    #pragma unroll
    for (int j = 0; j < 32; j++) {
      float a = sA[(32 + i) * 68 + j];
      #pragma unroll
      for (int cc = 0; cc < 4; cc++) x[cc] += a * sT[j * 68 + c0 + cc];
    }
    #pragma unroll
    for (int cc = 0; cc < 4; cc++) sA[i * 68 + c0 + cc] = x[cc];
  }
  __syncthreads();
  {
    int i = tid & 31, c0 = (tid >> 5) * 4;
    float x[4] = {0.f, 0.f, 0.f, 0.f};
    #pragma unroll
    for (int j = 0; j < 32; j++) {
      float t2 = sT[(32 + i) * 68 + 32 + j];
      #pragma unroll
      for (int cc = 0; cc < 4; cc++) x[cc] += t2 * sA[j * 68 + c0 + cc];
    }
    #pragma unroll
    for (int cc = 0; cc < 4; cc++) sT[(32 + i) * 68 + c0 + cc] = -x[cc];
  }
  __syncthreads();
  #pragma unroll
  for (int ii = 0; ii < 16; ii++) {
    int e = tid + 256 * ii;
    int r = e >> 6, cc = e & 63;
    sTb[r * 72 + cc] = (short)f2b(sT[r * 68 + cc]);
  }
  __syncthreads();

  {
    f32x4 accW[8], accU[8];
    #pragma unroll
    for (int nt = 0; nt < 8; nt++) { accW[nt] = f32x4{0.f,0.f,0.f,0.f}; accU[nt] = f32x4{0.f,0.f,0.f,0.f}; }
    bf16x8 ta[2];
    #pragma unroll
    for (int ks = 0; ks < 2; ks++)
      ta[ks] = *(const bf16x8*)&sTb[(wid * 16 + lane16) * 72 + ks * 32 + quad * 8];
    #pragma unroll
    for (int nt = 0; nt < 8; nt++) {
      #pragma unroll
      for (int ks = 0; ks < 2; ks++) {
        bf16x8 bk = *(const bf16x8*)&sKt[(nt * 16 + lane16) * 72 + ks * 32 + quad * 8];
        accW[nt] = __builtin_amdgcn_mfma_f32_16x16x32_bf16(ta[ks], bk, accW[nt], 0, 0, 0);
        bf16x8 bv = *(const bf16x8*)&sVt[(nt * 16 + lane16) * 72 + ks * 32 + quad * 8];
        accU[nt] = __builtin_amdgcn_mfma_f32_16x16x32_bf16(ta[ks], bv, accU[nt], 0, 0, 0);
      }
    }
    unsigned short* Wg = W_all + (size_t)cid * 8192;
    unsigned short* Ug = U_all + (size_t)cid * 8192;
    #pragma unroll
    for (int nt = 0; nt < 8; nt++)
      #pragma unroll
      for (int r = 0; r < 4; r++) {
        int i = wid * 16 + quad * 4 + r, k = nt * 16 + lane16;
        Wg[i * 128 + k] = f2b(accW[nt][r]);
        Ug[i * 128 + k] = f2b(accU[nt][r]);
      }
  }
}

// ================= PASS 2a: sequential state recurrence only =================
__global__ __launch_bounds__(512) void state_scan(
    unsigned short* qact, unsigned short* g1out,
    const float* __restrict__ g_arr,
    const unsigned short* __restrict__ W_all, const unsigned short* __restrict__ U_all,
    float* __restrict__ state_out)
{
  __shared__ __align__(16) short sS[64 * 136];    // S half-tile [64v][128k] bf16
  __shared__ __align__(16) short sDt[64 * 72];    // Dt [64v][64t] bf16
  __shared__ __align__(16) short sK2[128 * 72];   // K2^T [128k'][64t] bf16
  const int tid = threadIdx.x, lane = tid & 63, w = tid >> 6;
  const int lane16 = lane & 15, quad = lane >> 4;
  const int bid = blockIdx.x;
  const int bh = bid >> 1, vs = bid & 1;
  const int h = bh & 31, b = bh >> 5, qh = h >> 1;
  const int V0 = vs * 64;
  const int tt = w >> 1, vhl = (w & 1) * 32;      // aD work split
  const int avt = w & 3, kt0 = (w >> 2) * 4;      // aS work split

  for (int e = tid; e < 64 * 136 / 2; e += 512) ((unsigned int*)sS)[e] = 0u;
  float Sreg[4][4];
  #pragma unroll
  for (int n = 0; n < 4; n++)
    #pragma unroll
    for (int r = 0; r < 4; r++) Sreg[n][r] = 0.f;

  // ---- prefetch chunk 0 ----
  float gvn;
  bf16x8 kn[2], wn[4];
  unsigned short un[8];
  {
    const int r0_ = b * SEQ, cid_ = bh << 5;
    gvn = g_arr[(size_t)(r0_ + lane) * 32 + h];
    const unsigned short* ks_ = qact + (size_t)(r0_ + lane) * 8192 + 2048 + qh * 128 + w * 16;
    kn[0] = *(const bf16x8*)ks_; kn[1] = *(const bf16x8*)(ks_ + 8);
    const unsigned short* ws_ = W_all + (size_t)cid_ * 8192 + (tt * 16 + lane16) * 128 + quad * 8;
    #pragma unroll
    for (int ks = 0; ks < 4; ks++) wn[ks] = *(const bf16x8*)(ws_ + ks * 32);
    const unsigned short* us_ = U_all + (size_t)cid_ * 8192 + (tt * 16 + quad * 4) * 128 + V0 + vhl + lane16;
    #pragma unroll
    for (int vt = 0; vt < 2; vt++)
      #pragma unroll
      for (int r = 0; r < 4; r++) un[vt * 4 + r] = us_[r * 128 + vt * 16];
  }

  for (int ch = 0; ch < 32; ch++) {
    const int cid = (bh << 5) + ch;
    float l = gvn;
    #pragma unroll
    for (int off = 1; off < 64; off <<= 1) {
      float p = __shfl_up(l, off, 64);
      if (lane >= off) l += p;
    }
    float lC = __shfl(l, 63, 64);
    float elC = expf(lC);
    float s2 = expf(lC - l);
    #pragma unroll
    for (int e = 0; e < 8; e++)
      sK2[(w * 16 + e) * 72 + lane] = (short)f2b(b2f((unsigned short)kn[0][e]) * s2);
    #pragma unroll
    for (int e = 0; e < 8; e++)
      sK2[(w * 16 + 8 + e) * 72 + lane] = (short)f2b(b2f((unsigned short)kn[1][e]) * s2);
    bf16x8 wc[4];
    #pragma unroll
    for (int ks = 0; ks < 4; ks++) wc[ks] = wn[ks];
    unsigned short uc[8];
    #pragma unroll
    for (int i = 0; i < 8; i++) uc[i] = un[i];

    if (ch < 31) {
      const int r0_ = b * SEQ + (ch + 1) * 64, cid_ = cid + 1;
      gvn = g_arr[(size_t)(r0_ + lane) * 32 + h];
      const unsigned short* ks_ = qact + (size_t)(r0_ + lane) * 8192 + 2048 + qh * 128 + w * 16;
      kn[0] = *(const bf16x8*)ks_; kn[1] = *(const bf16x8*)(ks_ + 8);
      const unsigned short* ws_ = W_all + (size_t)cid_ * 8192 + (tt * 16 + lane16) * 128 + quad * 8;
      #pragma unroll
      for (int ks = 0; ks < 4; ks++) wn[ks] = *(const bf16x8*)(ws_ + ks * 32);
      const unsigned short* us_ = U_all + (size_t)cid_ * 8192 + (tt * 16 + quad * 4) * 128 + V0 + vhl + lane16;
      #pragma unroll
      for (int vt = 0; vt < 2; vt++)
        #pragma unroll
        for (int r = 0; r < 4; r++) un[vt * 4 + r] = us_[r * 128 + vt * 16];
    }
    asm volatile("s_waitcnt lgkmcnt(0)" ::: "memory");
    __builtin_amdgcn_s_barrier();      // bar1: sS(entering) + sK2 ready

    // Dt = U - W.S^T  -> out[t][v]
    f32x4 aD[2];
    aD[0] = f32x4{0.f,0.f,0.f,0.f}; aD[1] = f32x4{0.f,0.f,0.f,0.f};
    #pragma unroll
    for (int ks = 0; ks < 4; ks++)
      #pragma unroll
      for (int vt = 0; vt < 2; vt++) {
        bf16x8 bfr = *(const bf16x8*)&sS[(vhl + vt * 16 + lane16) * 136 + ks * 32 + quad * 8];
        aD[vt] = __builtin_amdgcn_mfma_f32_16x16x32_bf16(wc[ks], bfr, aD[vt], 0, 0, 0);
      }
    #pragma unroll
    for (int vt = 0; vt < 2; vt++)
      #pragma unroll
      for (int r = 0; r < 4; r++)
        sDt[(vhl + vt * 16 + lane16) * 72 + tt * 16 + quad * 4 + r] =
            (short)f2b(b2f(uc[vt * 4 + r]) - aD[vt][r]);
    asm volatile("s_waitcnt lgkmcnt(0)" ::: "memory");
    __builtin_amdgcn_s_barrier();      // bar2: sDt ready

    // S <- elC*S + Dt.K2
    bf16x8 a2[2];
    #pragma unroll
    for (int ks2 = 0; ks2 < 2; ks2++)
      a2[ks2] = *(const bf16x8*)&sDt[(avt * 16 + lane16) * 72 + ks2 * 32 + quad * 8];
    f32x4 aS[4];
    #pragma unroll
    for (int n = 0; n < 4; n++) aS[n] = f32x4{0.f,0.f,0.f,0.f};
    #pragma unroll
    for (int n = 0; n < 4; n++)
      #pragma unroll
      for (int ks2 = 0; ks2 < 2; ks2++) {
        bf16x8 bfr = *(const bf16x8*)&sK2[((kt0 + n) * 16 + lane16) * 72 + ks2 * 32 + quad * 8];
        aS[n] = __builtin_amdgcn_mfma_f32_16x16x32_bf16(a2[ks2], bfr, aS[n], 0, 0, 0);
      }
    #pragma unroll
    for (int r = 0; r < 4; r++) {
      int vg = V0 + avt * 16 + quad * 4 + r;
      unsigned short* sp = nullptr;
      if (ch < 31) sp = sall_ptr(qact, g1out, cid + 1, vg);
      #pragma unroll
      for (int n = 0; n < 4; n++) {
        float v = elC * Sreg[n][r] + aS[n][r];
        Sreg[n][r] = v;
        unsigned short bv = f2b(v);
        sS[(avt * 16 + quad * 4 + r) * 136 + (kt0 + n) * 16 + lane16] = (short)bv;
        if (ch < 31) sp[(kt0 + n) * 16 + lane16] = bv;
      }
    }
    asm volatile("s_waitcnt lgkmcnt(0)" ::: "memory");
    __builtin_amdgcn_s_barrier();      // bar3: sS(new) written; sDt/sK2 reads done
  }

  float* so = state_out + (size_t)bh * 16384;
  #pragma unroll
  for (int r = 0; r < 4; r++)
    #pragma unroll
    for (int n = 0; n < 4; n++)
      so[(size_t)(V0 + avt * 16 + quad * 4 + r) * 128 + (kt0 + n) * 16 + lane16] = Sreg[n][r];
}

// ================= PASS 2b: per-chunk output (fully parallel) =================
__global__ __launch_bounds__(256) void chunk_out(
    unsigned short* qact, unsigned short* g1out,
    const float* __restrict__ g_arr, const float* __restrict__ norm_w,
    const unsigned short* __restrict__ W_all, const unsigned short* __restrict__ U_all)
{
  __shared__ __align__(16) short sS[128 * 136];   // 34816 B
  __shared__ __align__(16) short sKn[64 * 136];   // 17408 B ; sM aliases
  __shared__ __align__(16) short sDt[128 * 72];   // 18432 B
  __shared__ float sl[64];
  __shared__ float sel[64];
  __shared__ float snw[128];
  short* sM = sKn;
  const int tid = threadIdx.x, lane = tid & 63, wid = tid >> 6;
  const int lane16 = lane & 15, quad = lane >> 4;
  const int cid = blockIdx.x;
  const int ch = cid & 31, h = (cid >> 5) & 31, b = cid >> 10, qh = h >> 1;
  const int row0 = b * SEQ + ch * 64;

  float l = g_arr[(size_t)(row0 + lane) * 32 + h];
  #pragma unroll
  for (int off = 1; off < 64; off <<= 1) {
    float p = __shfl_up(l, off, 64);
    if (lane >= off) l += p;
  }
  if (wid == 0) { sl[lane] = l; sel[lane] = expf(l); }
  if (tid < 128) snw[tid] = norm_w[tid];

  {
    int j4 = tid >> 2, kc = (tid & 3) * 32;
    const unsigned short* sk = qact + (size_t)(row0 + j4) * 8192 + 2048 + qh * 128 + kc;
    #pragma unroll
    for (int u = 0; u < 4; u++)
      *(bf16x8*)&sKn[j4 * 136 + kc + u * 8] = *(const bf16x8*)(sk + u * 8);
  }
  if (ch == 0) {
    for (int e = tid; e < 128 * 136 / 2; e += 256) ((unsigned int*)sS)[e] = 0u;
  } else {
    int vr = tid >> 1, hf = (tid & 1) * 64;
    const unsigned short* sp = sall_ptr(qact, g1out, cid, vr) + hf;
    #pragma unroll
    for (int u = 0; u < 8; u++)
      *(bf16x8*)&sS[vr * 136 + hf + u * 8] = *(const bf16x8*)(sp + u * 8);
  }
  bf16x8 qf[4], wf[4];
  {
    const unsigned short* qsrc = qact + (size_t)(row0 + wid * 16 + lane16) * 8192 + qh * 128 + quad * 8;
    #pragma unroll
    for (int ks = 0; ks < 4; ks++) qf[ks] = *(const bf16x8*)(qsrc + ks * 32);
    const unsigned short* wsrc = W_all + (size_t)cid * 8192 + (wid * 16 + lane16) * 128 + quad * 8;
    #pragma unroll
    for (int ks = 0; ks < 4; ks++) wf[ks] = *(const bf16x8*)(wsrc + ks * 32);
  }
  unsigned short uvr[8][4], zr[8][4];
  {
    const unsigned short* usrc = U_all + (size_t)cid * 8192 + (wid * 16 + quad * 4) * 128 + lane16;
    const unsigned short* zsrc = g1out + (size_t)(row0 + wid * 16 + quad * 4) * NPAD + 8192 + h * 128 + lane16;
    #pragma unroll
    for (int nt = 0; nt < 8; nt++)
      #pragma unroll
      for (int r = 0; r < 4; r++) {
        uvr[nt][r] = usrc[r * 128 + nt * 16];
        zr[nt][r]  = zsrc[(size_t)r * NPAD + nt * 16];
      }
  }
  __syncthreads();   // B1

  {
    f32x4 aD[8];
    #pragma unroll
    for (int nt = 0; nt < 8; nt++) aD[nt] = f32x4{0.f,0.f,0.f,0.f};
    #pragma unroll
    for (int ks = 0; ks < 4; ks++)
      #pragma unroll
      for (int nt = 0; nt < 8; nt++) {
        bf16x8 bfr = *(const bf16x8*)&sS[(nt * 16 + lane16) * 136 + ks * 32 + quad * 8];
        aD[nt] = __builtin_amdgcn_mfma_f32_16x16x32_bf16(wf[ks], bfr, aD[nt], 0, 0, 0);
      }
    #pragma unroll
    for (int nt = 0; nt < 8; nt++)
      #pragma unroll
      for (int r = 0; r < 4; r++)
        sDt[(nt * 16 + lane16) * 72 + wid * 16 + quad * 4 + r] =
            (short)f2b(b2f(uvr[nt][r]) - aD[nt][r]);
  }
  f32x4 aM[4];
  #pragma unroll
  for (int jt = 0; jt < 4; jt++) aM[jt] = f32x4{0.f,0.f,0.f,0.f};
  #pragma unroll
  for (int ks = 0; ks < 4; ks++)
    #pragma unroll
    for (int jt = 0; jt < 4; jt++) {
      bf16x8 bfr = *(const bf16x8*)&sKn[(jt * 16 + lane16) * 136 + ks * 32 + quad * 8];
      aM[jt] = __builtin_amdgcn_mfma_f32_16x16x32_bf16(qf[ks], bfr, aM[jt], 0, 0, 0);
    }
  __syncthreads();   // B2

  #pragma unroll
  for (int jt = 0; jt < 4; jt++) {
    int j = jt * 16 + lane16;
    float lj = sl[j];
    #pragma unroll
    for (int r = 0; r < 4; r++) {
      int i = wid * 16 + quad * 4 + r;
      float m = (j <= i) ? expf(sl[i] - lj) * aM[jt][r] : 0.f;
      sM[i * 72 + j] = (short)f2b(m);
    }
  }
  f32x4 aO[8];
  #pragma unroll
  for (int nt = 0; nt < 8; nt++) aO[nt] = f32x4{0.f,0.f,0.f,0.f};
  #pragma unroll
  for (int ks = 0; ks < 4; ks++)
    #pragma unroll
    for (int nt = 0; nt < 8; nt++) {
      bf16x8 bfr = *(const bf16x8*)&sS[(nt * 16 + lane16) * 136 + ks * 32 + quad * 8];
      aO[nt] = __builtin_amdgcn_mfma_f32_16x16x32_bf16(qf[ks], bfr, aO[nt], 0, 0, 0);
    }
  #pragma unroll
  for (int r = 0; r < 4; r++) {
    float eli = sel[wid * 16 + quad * 4 + r];
    #pragma unroll
    for (int nt = 0; nt < 8; nt++) aO[nt][r] *= eli;
  }
  __syncthreads();   // B3

  {
    bf16x8 a2[2];
    #pragma unroll
    for (int ks2 = 0; ks2 < 2; ks2++)
      a2[ks2] = *(const bf16x8*)&sM[(wid * 16 + lane16) * 72 + ks2 * 32 + quad * 8];
    #pragma unroll
    for (int ks2 = 0; ks2 < 2; ks2++)
      #pragma unroll
      for (int nt = 0; nt < 8; nt++) {
        bf16x8 bfr = *(const bf16x8*)&sDt[(nt * 16 + lane16) * 72 + ks2 * 32 + quad * 8];
        aO[nt] = __builtin_amdgcn_mfma_f32_16x16x32_bf16(a2[ks2], bfr, aO[nt], 0, 0, 0);
      }
  }
  #pragma unroll
  for (int r = 0; r < 4; r++) {
    float ss = 0.f;
    #pragma unroll
    for (int nt = 0; nt < 8; nt++) ss += aO[nt][r] * aO[nt][r];
    ss += __shfl_xor(ss, 1, 64);
    ss += __shfl_xor(ss, 2, 64);
    ss += __shfl_xor(ss, 4, 64);
    ss += __shfl_xor(ss, 8, 64);
    float rinv = rsqrtf(ss * (1.f / 128.f) + 1e-6f);
    int i = wid * 16 + quad * 4 + r;
    size_t grow = (size_t)(row0 + i) * NPAD + h * 128;
    #pragma unroll
    for (int nt = 0; nt < 8; nt++) {
      int v = nt * 16 + lane16;
      float zv = b2f(zr[nt][r]);
      float zg = zv / (1.f + __expf(-zv));
      float y = snw[v] * (aO[nt][r] * rinv) * zg;
      g1out[grow + v] = f2b(y);
    }
  }
}

extern "C" void kernel_launch(void* const* d_in, const int* in_sizes, int n_in,
                              void* d_out, int out_size, void* d_ws, size_t ws_size,
                              hipStream_t stream)
{
  const float* hidden  = (const float*)d_in[0];
  const float* W_qkv   = (const float*)d_in[1];
  const float* W_z     = (const float*)d_in[2];
  const float* W_a     = (const float*)d_in[3];
  const float* W_b     = (const float*)d_in[4];
  const float* conv_w  = (const float*)d_in[5];
  const float* A_log   = (const float*)d_in[6];
  const float* dt_bias = (const float*)d_in[7];
  const float* norm_w  = (const float*)d_in[8];
  const float* W_out   = (const float*)d_in[9];

  char* ws = (char*)d_ws;
  unsigned short* hbf   = (unsigned short*)(ws);                 // [4096][2048] bf16
  unsigned short* Wcat  = (unsigned short*)(ws + 16777216ull);   // [12416][2048] bf16
  unsigned short* Woutb = (unsigned short*)(ws + 67633152ull);   // [2048][4096] bf16
  unsigned short* g1out = (unsigned short*)(ws + 84410368ull);   // [4096][12416] bf16
  unsigned short* qact  = (unsigned short*)(ws + 186122240ull);  // [4096][8192] bf16
  float* g_arr          = (float*)(ws + 253231104ull);           // [4096][32]
  float* beta           = (float*)(ws + 253755392ull);           // [4096][32]
  unsigned short* W_all = (unsigned short*)(ws);                 // aliases hbf (dead after GEMM1)
  unsigned short* U_all = (unsigned short*)(ws + 33554432ull);   // aliases Wcat tail
  float* gate_part      = (float*)qact;   // [8][4096][64] fp32, 8MB; dead before conv writes qact

  float* out0 = (float*)d_out;          // (2,2048,2048) fp32
  float* out1 = out0 + 8388608;         // conv_state (2,8192,4)
  float* out2 = out0 + 8454144;         // state (2,32,128,128)

  cast_kernel<<<8192,  256, 0, stream>>>(hidden, hbf, 2097152);
  cast_kernel<<<16384, 256, 0, stream>>>(W_qkv, Wcat, 4194304);
  cast_kernel<<<8192,  256, 0, stream>>>(W_z,   Wcat + 8192ull  * 2048, 2097152);
  cast_kernel<<<64,    256, 0, stream>>>(W_a,   Wcat + 12288ull * 2048, 16384);
  cast_kernel<<<64,    256, 0, stream>>>(W_b,   Wcat + 12320ull * 2048, 16384);
  cast_kernel<<<8192,  256, 0, stream>>>(W_out, Woutb, 2097152);

  // a/b gate columns via split-K (8 x 256-K segments, full-chip 256 blocks)
  gemm_ab<<<dim3(8, 32), 256, 0, stream>>>(hbf, Wcat + 12288ull * 2048, gate_part);
  // GEMM1: 256^2 4-phase over q,k,v,z; 16 m-tiles (fast) x 48 n-tiles = 768 = 3x256
  gemm1_256<<<768, 512, 0, stream>>>(hbf, Wcat, g1out, 2048, 2048, 2048,
                                     NPAD, 12288, NPAD - 1, 16);
  gebeta_kernel<<<512, 256, 0, stream>>>(gate_part, A_log, dt_bias, g_arr, beta);
  conv_kernel<<<dim3(4096, 8), 128, 0, stream>>>(g1out, conv_w, qact);
  convstate_kernel<<<256, 256, 0, stream>>>(g1out, out1);

  chunk_prep<<<2048, 256, 0, stream>>>(qact, g_arr, beta, W_all, U_all);
  state_scan<<<128, 512, 0, stream>>>(qact, g1out, g_arr, W_all, U_all, out2);
  chunk_out<<<2048, 256, 0, stream>>>(qact, g1out, g_arr, norm_w, W_all, U_all);

  gemm_bt<false><<<dim3(16, 32), 256, 0, stream>>>(g1out, Woutb, out0, 4096, NPAD, 4096, 2048, 2048);
}